// Round 1
// baseline (5939.355 us; speedup 1.0000x reference)
//
#include <hip/hip_runtime.h>

#define EPS_BN 1e-5f

// ---------------- normalization ----------------
__global__ void k_init_deg(float* deg, int n) {
    int i = blockIdx.x * blockDim.x + threadIdx.x;
    if (i < n) deg[i] = 1.0f;   // self-loop weight
}

__global__ void k_accum_deg(const int* __restrict__ dst, const float* __restrict__ w,
                            float* __restrict__ deg, int e) {
    int i = blockIdx.x * blockDim.x + threadIdx.x;
    if (i < e) atomicAdd(&deg[dst[i]], w[i]);
}

__global__ void k_finalize_dinv(float* d, int n) {
    int i = blockIdx.x * blockDim.x + threadIdx.x;
    if (i < n) {
        float v = d[i];
        d[i] = v > 0.0f ? rsqrtf(v) : 0.0f;
    }
}

__global__ void k_norm(const int* __restrict__ src, const int* __restrict__ dst,
                       const float* __restrict__ w, const float* __restrict__ dinv,
                       float* __restrict__ norm, int e) {
    int i = blockIdx.x * blockDim.x + threadIdx.x;
    if (i < e) norm[i] = dinv[src[i]] * w[i] * dinv[dst[i]];
}

// ---------------- GEMMs ----------------
// x(N,16) @ W(16,128) -> out(N,128). 128 threads/block, 8 nodes/block.
__global__ void k_gemm_in(const float* __restrict__ x, const float* __restrict__ W,
                          float* __restrict__ out, int n) {
    __shared__ float Ws[16 * 128];
    __shared__ float xs[8 * 16];
    int f = threadIdx.x;
    #pragma unroll
    for (int k = 0; k < 16; ++k) Ws[k * 128 + f] = W[k * 128 + f];
    int node0 = blockIdx.x * 8;
    int nrows = n - node0; if (nrows > 8) nrows = 8;
    if (f < nrows * 16) xs[f] = x[node0 * 16 + f];
    __syncthreads();
    for (int nl = 0; nl < nrows; ++nl) {
        float acc = 0.f;
        #pragma unroll
        for (int k = 0; k < 16; ++k) acc += xs[nl * 16 + k] * Ws[k * 128 + f];
        out[(size_t)(node0 + nl) * 128 + f] = acc;
    }
}

// h(N,128) @ W(128,128) -> out(N,128). 256 threads/block, 16 nodes/block.
__global__ void k_gemm_hid(const float* __restrict__ h, const float* __restrict__ W,
                           float* __restrict__ out, int n) {
    __shared__ float hs[16 * 128];
    int tid = threadIdx.x;
    int f = tid & 127;
    int half = tid >> 7;           // 0..1
    int node0 = blockIdx.x * 16;
    int nrows = n - node0; if (nrows > 16) nrows = 16;
    const float4* h4 = (const float4*)(h + (size_t)node0 * 128);
    float4* hs4 = (float4*)hs;
    for (int i = tid; i < nrows * 32; i += 256) hs4[i] = h4[i];
    __syncthreads();
    float acc[8] = {0.f, 0.f, 0.f, 0.f, 0.f, 0.f, 0.f, 0.f};
    for (int k4 = 0; k4 < 32; ++k4) {
        float w0 = W[(k4 * 4 + 0) * 128 + f];
        float w1 = W[(k4 * 4 + 1) * 128 + f];
        float w2 = W[(k4 * 4 + 2) * 128 + f];
        float w3 = W[(k4 * 4 + 3) * 128 + f];
        #pragma unroll
        for (int i = 0; i < 8; ++i) {
            float4 hv = hs4[(half + 2 * i) * 32 + k4];
            acc[i] += hv.x * w0 + hv.y * w1 + hv.z * w2 + hv.w * w3;
        }
    }
    #pragma unroll
    for (int i = 0; i < 8; ++i) {
        int nl = half + 2 * i;
        if (nl < nrows) out[(size_t)(node0 + nl) * 128 + f] = acc[i];
    }
}

// h(N,128) @ W(128,12) -> out(N,12). 192 threads/block = 16 nodes x 12 feats.
__global__ void k_gemm_out(const float* __restrict__ h, const float* __restrict__ W,
                           float* __restrict__ out, int n) {
    __shared__ float hs[16 * 129];
    __shared__ float Ws[128 * 12];
    int tid = threadIdx.x;
    int node0 = blockIdx.x * 16;
    int nrows = n - node0; if (nrows > 16) nrows = 16;
    for (int i = tid; i < 128 * 12; i += 192) Ws[i] = W[i];
    for (int i = tid; i < nrows * 128; i += 192)
        hs[(i >> 7) * 129 + (i & 127)] = h[(size_t)node0 * 128 + i];
    __syncthreads();
    int nl = tid / 12, f = tid - nl * 12;
    if (nl < nrows) {
        float acc = 0.f;
        for (int k = 0; k < 128; ++k) acc += hs[nl * 129 + k] * Ws[k * 12 + f];
        out[(size_t)(node0 + nl) * 12 + f] = acc;
    }
}

// ---------------- scatter (segment_sum) ----------------
// one thread per (edge, 4-feature group); 32 groups per edge
__global__ void k_scatter128(const float* __restrict__ hsrc, const int* __restrict__ src,
                             const int* __restrict__ dst, const float* __restrict__ norm,
                             float* __restrict__ agg, int e) {
    int t = blockIdx.x * blockDim.x + threadIdx.x;
    int eidx = t >> 5;
    if (eidx >= e) return;
    int q = t & 31;
    int s = src[eidx], d = dst[eidx];
    float nm = norm[eidx];
    float4 v = *(const float4*)(hsrc + (size_t)s * 128 + q * 4);
    float* o = agg + (size_t)d * 128 + q * 4;
    atomicAdd(o + 0, v.x * nm);
    atomicAdd(o + 1, v.y * nm);
    atomicAdd(o + 2, v.z * nm);
    atomicAdd(o + 3, v.w * nm);
}

// agg += h_trans * dinv^2 (self loop) + bias
__global__ void k_self_bias(const float* __restrict__ ht, const float* __restrict__ dinv,
                            const float* __restrict__ bias, float* __restrict__ agg, int n) {
    int t = blockIdx.x * blockDim.x + threadIdx.x;
    if (t < n * 128) {
        int i = t >> 7, f = t & 127;
        float di = dinv[i];
        agg[t] += ht[t] * di * di + bias[f];
    }
}

// ---------------- batch norm ----------------
__global__ void k_bn_stats(const float* __restrict__ h, float* __restrict__ sums,
                           float* __restrict__ sumsq, int n) {
    int f = threadIdx.x;             // 128
    int i0 = blockIdx.x * 256;
    int i1 = i0 + 256; if (i1 > n) i1 = n;
    float s = 0.f, ss = 0.f;
    for (int i = i0; i < i1; ++i) {
        float v = h[(size_t)i * 128 + f];
        s += v; ss += v * v;
    }
    atomicAdd(&sums[f], s);
    atomicAdd(&sumsq[f], ss);
}

__global__ void k_bn_apply(float* __restrict__ h, const float* __restrict__ sums,
                           const float* __restrict__ sumsq, const float* __restrict__ g,
                           const float* __restrict__ b, int n, float invn) {
    int t = blockIdx.x * blockDim.x + threadIdx.x;
    if (t < n * 128) {
        int f = t & 127;
        float m = sums[f] * invn;
        float v = sumsq[f] * invn - m * m;
        float x = (h[t] - m) * rsqrtf(v + EPS_BN) * g[f] + b[f];
        h[t] = x > 0.f ? x : 0.f;
    }
}

// ---------------- output layer helpers ----------------
__global__ void k_out_init(const float* __restrict__ ht, const float* __restrict__ dinv,
                           const float* __restrict__ b2, float* __restrict__ out, int n) {
    int t = blockIdx.x * blockDim.x + threadIdx.x;
    if (t < n * 12) {
        int i = t / 12, f = t - i * 12;
        float di = dinv[i];
        out[t] = ht[t] * di * di + b2[f];
    }
}

__global__ void k_scatter12(const float* __restrict__ ht, const int* __restrict__ src,
                            const int* __restrict__ dst, const float* __restrict__ norm,
                            float* __restrict__ out, int e) {
    int t = blockIdx.x * blockDim.x + threadIdx.x;
    if (t < e * 12) {
        int eidx = t / 12, f = t - eidx * 12;
        atomicAdd(&out[(size_t)dst[eidx] * 12 + f],
                  ht[(size_t)src[eidx] * 12 + f] * norm[eidx]);
    }
}

extern "C" void kernel_launch(void* const* d_in, const int* in_sizes, int n_in,
                              void* d_out, int out_size, void* d_ws, size_t ws_size,
                              hipStream_t stream) {
    const float* x   = (const float*)d_in[0];
    const int*   ei  = (const int*)d_in[1];     // (2, E) int32
    const float* ew  = (const float*)d_in[2];
    const float* W0  = (const float*)d_in[3];
    const float* b0  = (const float*)d_in[4];
    const float* W1  = (const float*)d_in[5];
    const float* b1  = (const float*)d_in[6];
    const float* W2  = (const float*)d_in[7];
    const float* b2  = (const float*)d_in[8];
    const float* g0  = (const float*)d_in[9];
    const float* be0 = (const float*)d_in[10];
    const float* g1  = (const float*)d_in[11];
    const float* be1 = (const float*)d_in[12];
    float* out = (float*)d_out;

    const int n = in_sizes[0] / 16;   // 100000
    const int e = in_sizes[2];        // 1600000
    const int* src = ei;
    const int* dst = ei + e;

    // workspace layout (floats): dinv[n] | norm[e] | A[n*128] | B[n*128] | sums[128] | sumsq[128]
    float* wsf  = (float*)d_ws;
    float* dinv = wsf;
    float* norm = dinv + n;
    float* A    = norm + e;
    float* B    = A + (size_t)n * 128;
    float* sums = B + (size_t)n * 128;
    float* sumsq = sums + 128;

    const float invn = 1.0f / (float)n;
    const int scatter_blocks = (int)(((size_t)e * 32 + 255) / 256);

    // ---- normalization ----
    k_init_deg<<<(n + 255) / 256, 256, 0, stream>>>(dinv, n);
    k_accum_deg<<<(e + 255) / 256, 256, 0, stream>>>(dst, ew, dinv, e);
    k_finalize_dinv<<<(n + 255) / 256, 256, 0, stream>>>(dinv, n);
    k_norm<<<(e + 255) / 256, 256, 0, stream>>>(src, dst, ew, dinv, norm, e);

    // ---- layer 0: 16 -> 128, BN+ReLU ----
    k_gemm_in<<<(n + 7) / 8, 128, 0, stream>>>(x, W0, A, n);
    hipMemsetAsync(B, 0, (size_t)n * 128 * sizeof(float), stream);
    k_scatter128<<<scatter_blocks, 256, 0, stream>>>(A, src, dst, norm, B, e);
    k_self_bias<<<(n * 128 + 255) / 256, 256, 0, stream>>>(A, dinv, b0, B, n);
    hipMemsetAsync(sums, 0, 256 * sizeof(float), stream);
    k_bn_stats<<<(n + 255) / 256, 128, 0, stream>>>(B, sums, sumsq, n);
    k_bn_apply<<<(n * 128 + 255) / 256, 256, 0, stream>>>(B, sums, sumsq, g0, be0, n, invn);

    // ---- layer 1: 128 -> 128, BN+ReLU ----
    k_gemm_hid<<<(n + 15) / 16, 256, 0, stream>>>(B, W1, A, n);
    hipMemsetAsync(B, 0, (size_t)n * 128 * sizeof(float), stream);
    k_scatter128<<<scatter_blocks, 256, 0, stream>>>(A, src, dst, norm, B, e);
    k_self_bias<<<(n * 128 + 255) / 256, 256, 0, stream>>>(A, dinv, b1, B, n);
    hipMemsetAsync(sums, 0, 256 * sizeof(float), stream);
    k_bn_stats<<<(n + 255) / 256, 128, 0, stream>>>(B, sums, sumsq, n);
    k_bn_apply<<<(n * 128 + 255) / 256, 256, 0, stream>>>(B, sums, sumsq, g1, be1, n, invn);

    // ---- layer 2: 128 -> 12, no BN ----
    k_gemm_out<<<(n + 15) / 16, 192, 0, stream>>>(B, W2, A, n);   // A reused as N x 12
    k_out_init<<<(n * 12 + 255) / 256, 256, 0, stream>>>(A, dinv, b2, out, n);
    k_scatter12<<<(e * 12 + 255) / 256, 256, 0, stream>>>(A, src, dst, norm, out, e);
}

// Round 2
// 889.537 us; speedup vs baseline: 6.6769x; 6.6769x over previous
//
#include <hip/hip_runtime.h>

#define EPS_BN 1e-5f

// ================= degree + histogram =================
__global__ void k_init_deg(float* deg, int n) {
    int i = blockIdx.x * blockDim.x + threadIdx.x;
    if (i < n) deg[i] = 1.0f;   // self-loop weight
}

__global__ void k_deg_hist(const int* __restrict__ dst, const float* __restrict__ w,
                           float* __restrict__ deg, int* __restrict__ hist, int e) {
    int i = blockIdx.x * blockDim.x + threadIdx.x;
    if (i < e) {
        int d = dst[i];
        atomicAdd(&deg[d], w[i]);
        atomicAdd(&hist[d], 1);
    }
}

__global__ void k_finalize_dinv(float* d, int n) {
    int i = blockIdx.x * blockDim.x + threadIdx.x;
    if (i < n) {
        float v = d[i];
        d[i] = v > 0.0f ? rsqrtf(v) : 0.0f;
    }
}

// ================= exclusive scan (3-kernel) =================
// chunk = 1024 elements per block (256 threads x 4)
__global__ void k_scan_local(int* __restrict__ R, int* __restrict__ bsum, int n) {
    __shared__ int s[256];
    int t = threadIdx.x;
    int base = blockIdx.x * 1024 + t * 4;
    int v0 = (base + 0 < n) ? R[base + 0] : 0;
    int v1 = (base + 1 < n) ? R[base + 1] : 0;
    int v2 = (base + 2 < n) ? R[base + 2] : 0;
    int v3 = (base + 3 < n) ? R[base + 3] : 0;
    int sum = v0 + v1 + v2 + v3;
    s[t] = sum;
    __syncthreads();
    for (int off = 1; off < 256; off <<= 1) {
        int u = (t >= off) ? s[t - off] : 0;
        __syncthreads();
        s[t] += u;
        __syncthreads();
    }
    if (t == 255) bsum[blockIdx.x] = s[255];
    int run = s[t] - sum;   // exclusive prefix of this thread's chunk
    if (base + 0 < n) R[base + 0] = run;  run += v0;
    if (base + 1 < n) R[base + 1] = run;  run += v1;
    if (base + 2 < n) R[base + 2] = run;  run += v2;
    if (base + 3 < n) R[base + 3] = run;
}

__global__ void k_scan_bsum(int* __restrict__ bsum, int nb) {
    __shared__ int s[128];
    int t = threadIdx.x;
    int v = (t < nb) ? bsum[t] : 0;
    s[t] = v;
    __syncthreads();
    for (int off = 1; off < 128; off <<= 1) {
        int u = (t >= off) ? s[t - off] : 0;
        __syncthreads();
        s[t] += u;
        __syncthreads();
    }
    if (t < nb) bsum[t] = s[t] - v;   // exclusive
}

__global__ void k_scan_add(int* __restrict__ R, const int* __restrict__ bsum, int n) {
    int add = bsum[blockIdx.x];
    int base = blockIdx.x * 1024 + threadIdx.x * 4;
    if (base + 3 < n) {
        R[base + 0] += add; R[base + 1] += add;
        R[base + 2] += add; R[base + 3] += add;
    } else {
        for (int k = 0; k < 4; ++k)
            if (base + k < n) R[base + k] += add;
    }
}

// ================= CSR placement =================
// After this, R[i] == original R[i+1] (row end), since each atomicAdd bumps R[d] by 1 per edge.
__global__ void k_place(const int* __restrict__ src, const int* __restrict__ dst,
                        const float* __restrict__ w, const float* __restrict__ dinv,
                        int* __restrict__ R, int* __restrict__ esrc,
                        float* __restrict__ enorm, int e) {
    int i = blockIdx.x * blockDim.x + threadIdx.x;
    if (i < e) {
        int s = src[i], d = dst[i];
        float nm = dinv[s] * w[i] * dinv[d];
        int pos = atomicAdd(&R[d], 1);
        esrc[pos] = s;
        enorm[pos] = nm;
    }
}

// ================= aggregations (CSR, no atomics) =================
// 16-feature aggregation of raw x (layer 0, aggregate-before-transform).
// 16 threads per node, 256/block -> 16 nodes/block.
__global__ void k_agg_x(const float* __restrict__ x, const int* __restrict__ esrc,
                        const float* __restrict__ enorm, const int* __restrict__ Rpost,
                        const float* __restrict__ dinv, float* __restrict__ xagg, int n) {
    int t = blockIdx.x * blockDim.x + threadIdx.x;
    int node = t >> 4, f = t & 15;
    if (node >= n) return;
    int start = node ? Rpost[node - 1] : 0;
    int end = Rpost[node];
    float acc = 0.f;
    for (int j = start; j < end; ++j)
        acc += enorm[j] * x[(size_t)esrc[j] * 16 + f];
    float di = dinv[node];
    xagg[(size_t)node * 16 + f] = acc + x[(size_t)node * 16 + f] * di * di;
}

// 128-feature aggregation: one wave per node, float2 per lane.
// Epilogue fuses self-loop + bias.
__global__ void k_aggregate128(const float* __restrict__ A, const int* __restrict__ esrc,
                               const float* __restrict__ enorm, const int* __restrict__ Rpost,
                               const float* __restrict__ dinv, const float* __restrict__ bias,
                               float* __restrict__ B, int n) {
    int gid = blockIdx.x * blockDim.x + threadIdx.x;
    int node = gid >> 6;
    int lane = threadIdx.x & 63;
    if (node >= n) return;
    int start = node ? Rpost[node - 1] : 0;
    int end = Rpost[node];
    const float2* A2 = (const float2*)A;
    float ax = 0.f, ay = 0.f;
    int j = start;
    for (; j + 1 < end; j += 2) {
        int s0 = esrc[j], s1 = esrc[j + 1];
        float n0 = enorm[j], n1 = enorm[j + 1];
        float2 v0 = A2[(size_t)s0 * 64 + lane];
        float2 v1 = A2[(size_t)s1 * 64 + lane];
        ax += v0.x * n0 + v1.x * n1;
        ay += v0.y * n0 + v1.y * n1;
    }
    if (j < end) {
        int s0 = esrc[j];
        float n0 = enorm[j];
        float2 v0 = A2[(size_t)s0 * 64 + lane];
        ax += v0.x * n0;
        ay += v0.y * n0;
    }
    float di = dinv[node];
    float2 vs = A2[(size_t)node * 64 + lane];
    ax += vs.x * di * di + bias[2 * lane];
    ay += vs.y * di * di + bias[2 * lane + 1];
    float2 r; r.x = ax; r.y = ay;
    ((float2*)B)[(size_t)node * 64 + lane] = r;
}

// 12-feature output aggregation (input stride 16, output stride 12), fuses self-loop + b2.
__global__ void k_agg_out(const float* __restrict__ A16, const int* __restrict__ esrc,
                          const float* __restrict__ enorm, const int* __restrict__ Rpost,
                          const float* __restrict__ dinv, const float* __restrict__ b2,
                          float* __restrict__ out, int n) {
    int t = blockIdx.x * blockDim.x + threadIdx.x;
    int node = t >> 4, f = t & 15;
    if (node >= n || f >= 12) return;
    int start = node ? Rpost[node - 1] : 0;
    int end = Rpost[node];
    float acc = 0.f;
    for (int j = start; j < end; ++j)
        acc += enorm[j] * A16[(size_t)esrc[j] * 16 + f];
    float di = dinv[node];
    out[(size_t)node * 12 + f] = acc + A16[(size_t)node * 16 + f] * di * di + b2[f];
}

// ================= GEMMs =================
// xagg(N,16) @ W(16,128) + b -> out(N,128). 128 threads/block, 8 nodes/block.
__global__ void k_gemm_in(const float* __restrict__ x, const float* __restrict__ W,
                          const float* __restrict__ b, float* __restrict__ out, int n) {
    __shared__ float Ws[16 * 128];
    __shared__ float xs[8 * 16];
    int f = threadIdx.x;
    #pragma unroll
    for (int k = 0; k < 16; ++k) Ws[k * 128 + f] = W[k * 128 + f];
    int node0 = blockIdx.x * 8;
    int nrows = n - node0; if (nrows > 8) nrows = 8;
    if (f < nrows * 16) xs[f] = x[(size_t)node0 * 16 + f];
    __syncthreads();
    float bf = b[f];
    for (int nl = 0; nl < nrows; ++nl) {
        float acc = bf;
        #pragma unroll
        for (int k = 0; k < 16; ++k) acc += xs[nl * 16 + k] * Ws[k * 128 + f];
        out[(size_t)(node0 + nl) * 128 + f] = acc;
    }
}

// h(N,128) @ W(128,128) -> out(N,128). 256 threads/block, 16 nodes/block. (no bias)
__global__ void k_gemm_hid(const float* __restrict__ h, const float* __restrict__ W,
                           float* __restrict__ out, int n) {
    __shared__ float hs[16 * 128];
    int tid = threadIdx.x;
    int f = tid & 127;
    int half = tid >> 7;           // 0..1
    int node0 = blockIdx.x * 16;
    int nrows = n - node0; if (nrows > 16) nrows = 16;
    const float4* h4 = (const float4*)(h + (size_t)node0 * 128);
    float4* hs4 = (float4*)hs;
    for (int i = tid; i < nrows * 32; i += 256) hs4[i] = h4[i];
    __syncthreads();
    float acc[8] = {0.f, 0.f, 0.f, 0.f, 0.f, 0.f, 0.f, 0.f};
    for (int k4 = 0; k4 < 32; ++k4) {
        float w0 = W[(k4 * 4 + 0) * 128 + f];
        float w1 = W[(k4 * 4 + 1) * 128 + f];
        float w2 = W[(k4 * 4 + 2) * 128 + f];
        float w3 = W[(k4 * 4 + 3) * 128 + f];
        #pragma unroll
        for (int i = 0; i < 8; ++i) {
            float4 hv = hs4[(half + 2 * i) * 32 + k4];
            acc[i] += hv.x * w0 + hv.y * w1 + hv.z * w2 + hv.w * w3;
        }
    }
    #pragma unroll
    for (int i = 0; i < 8; ++i) {
        int nl = half + 2 * i;
        if (nl < nrows) out[(size_t)(node0 + nl) * 128 + f] = acc[i];
    }
}

// h(N,128) @ W(128,12) -> out(N,16) stride-16, cols 12..15 zeroed. 192 thr/block.
__global__ void k_gemm_out16(const float* __restrict__ h, const float* __restrict__ W,
                             float* __restrict__ out, int n) {
    __shared__ float hs[16 * 129];
    __shared__ float Ws[128 * 12];
    int tid = threadIdx.x;
    int node0 = blockIdx.x * 16;
    int nrows = n - node0; if (nrows > 16) nrows = 16;
    for (int i = tid; i < 128 * 12; i += 192) Ws[i] = W[i];
    for (int i = tid; i < nrows * 128; i += 192)
        hs[(i >> 7) * 129 + (i & 127)] = h[(size_t)node0 * 128 + i];
    __syncthreads();
    int nl = tid / 12, f = tid - nl * 12;
    if (nl < nrows) {
        float acc = 0.f;
        for (int k = 0; k < 128; ++k) acc += hs[nl * 129 + k] * Ws[k * 12 + f];
        out[(size_t)(node0 + nl) * 16 + f] = acc;
    }
    // zero the 4 pad columns: 16 nodes x 4 cols = 64 entries
    if (tid < 64) {
        int nn = tid >> 2, pf = 12 + (tid & 3);
        if (nn < nrows) out[(size_t)(node0 + nn) * 16 + pf] = 0.f;
    }
}

// ================= batch norm =================
__global__ void k_bn_stats(const float* __restrict__ h, float* __restrict__ sums,
                           float* __restrict__ sumsq, int n) {
    int f = threadIdx.x;             // 128
    int i0 = blockIdx.x * 256;
    int i1 = i0 + 256; if (i1 > n) i1 = n;
    float s = 0.f, ss = 0.f;
    for (int i = i0; i < i1; ++i) {
        float v = h[(size_t)i * 128 + f];
        s += v; ss += v * v;
    }
    atomicAdd(&sums[f], s);
    atomicAdd(&sumsq[f], ss);
}

__global__ void k_bn_apply(float* __restrict__ h, const float* __restrict__ sums,
                           const float* __restrict__ sumsq, const float* __restrict__ g,
                           const float* __restrict__ b, int n, float invn) {
    int t = blockIdx.x * blockDim.x + threadIdx.x;
    if (t < n * 128) {
        int f = t & 127;
        float m = sums[f] * invn;
        float v = sumsq[f] * invn - m * m;
        float x = (h[t] - m) * rsqrtf(v + EPS_BN) * g[f] + b[f];
        h[t] = x > 0.f ? x : 0.f;
    }
}

// ================= launch =================
extern "C" void kernel_launch(void* const* d_in, const int* in_sizes, int n_in,
                              void* d_out, int out_size, void* d_ws, size_t ws_size,
                              hipStream_t stream) {
    const float* x   = (const float*)d_in[0];
    const int*   ei  = (const int*)d_in[1];
    const float* ew  = (const float*)d_in[2];
    const float* W0  = (const float*)d_in[3];
    const float* b0  = (const float*)d_in[4];
    const float* W1  = (const float*)d_in[5];
    const float* b1  = (const float*)d_in[6];
    const float* W2  = (const float*)d_in[7];
    const float* b2  = (const float*)d_in[8];
    const float* g0  = (const float*)d_in[9];
    const float* be0 = (const float*)d_in[10];
    const float* g1  = (const float*)d_in[11];
    const float* be1 = (const float*)d_in[12];
    float* out = (float*)d_out;

    const int n = in_sizes[0] / 16;   // 100000
    const int e = in_sizes[2];        // 1600000
    const int* src = ei;
    const int* dst = ei + e;

    // workspace layout (4B elements, regions padded to 16B)
    float* wsf   = (float*)d_ws;
    float* dinv  = wsf;                              // n
    int*   R     = (int*)(wsf + n);                  // n+4 (hist -> scan -> row-ends)
    int*   bsum  = R + (n + 4);                      // 128
    int*   esrc  = bsum + 128;                       // e
    float* enorm = (float*)(esrc + e);               // e
    float* A     = enorm + e;                        // n*128
    float* B     = A + (size_t)n * 128;              // n*128
    float* sums  = B + (size_t)n * 128;              // 128
    float* sumsq = sums + 128;                       // 128

    const float invn = 1.0f / (float)n;
    const int nb_scan = (n + 1023) / 1024;           // 98

    // ---- degree + CSR build ----
    k_init_deg<<<(n + 255) / 256, 256, 0, stream>>>(dinv, n);
    hipMemsetAsync(R, 0, (size_t)(n + 4) * sizeof(int), stream);
    k_deg_hist<<<(e + 255) / 256, 256, 0, stream>>>(dst, ew, dinv, R, e);
    k_finalize_dinv<<<(n + 255) / 256, 256, 0, stream>>>(dinv, n);
    k_scan_local<<<nb_scan, 256, 0, stream>>>(R, bsum, n);
    k_scan_bsum<<<1, 128, 0, stream>>>(bsum, nb_scan);
    k_scan_add<<<nb_scan, 256, 0, stream>>>(R, bsum, n);
    k_place<<<(e + 255) / 256, 256, 0, stream>>>(src, dst, ew, dinv, R, esrc, enorm, e);
    // now R[i] == row_end(i); row_start(i) = (i ? R[i-1] : 0)

    // ---- layer 0: aggregate x (16 feats), then 16->128 GEMM + bias, BN+ReLU ----
    k_agg_x<<<(n * 16 + 255) / 256, 256, 0, stream>>>(x, esrc, enorm, R, dinv, A, n);
    k_gemm_in<<<(n + 7) / 8, 128, 0, stream>>>(A, W0, b0, B, n);
    hipMemsetAsync(sums, 0, 256 * sizeof(float), stream);
    k_bn_stats<<<(n + 255) / 256, 128, 0, stream>>>(B, sums, sumsq, n);
    k_bn_apply<<<(n * 128 + 255) / 256, 256, 0, stream>>>(B, sums, sumsq, g0, be0, n, invn);

    // ---- layer 1: 128->128 GEMM, aggregate (fused self-loop+bias), BN+ReLU ----
    k_gemm_hid<<<(n + 15) / 16, 256, 0, stream>>>(B, W1, A, n);
    k_aggregate128<<<(n * 64 + 255) / 256, 256, 0, stream>>>(A, esrc, enorm, R, dinv, b1, B, n);
    hipMemsetAsync(sums, 0, 256 * sizeof(float), stream);
    k_bn_stats<<<(n + 255) / 256, 128, 0, stream>>>(B, sums, sumsq, n);
    k_bn_apply<<<(n * 128 + 255) / 256, 256, 0, stream>>>(B, sums, sumsq, g1, be1, n, invn);

    // ---- layer 2: 128->12 GEMM (stride-16 padded), aggregate to out ----
    k_gemm_out16<<<(n + 15) / 16, 192, 0, stream>>>(B, W2, A, n);   // A used as N x 16
    k_agg_out<<<(n * 16 + 255) / 256, 256, 0, stream>>>(A, esrc, enorm, R, dinv, b2, out, n);
}

// Round 3
// 788.813 us; speedup vs baseline: 7.5295x; 1.1277x over previous
//
#include <hip/hip_runtime.h>

#define EPS_BN 1e-5f

__device__ inline unsigned short f2bf(float f) {
    unsigned int u = __float_as_uint(f);
    unsigned int r = (u + 0x7fffu + ((u >> 16) & 1u)) >> 16;
    return (unsigned short)r;
}
__device__ inline unsigned int packbf(float lo, float hi) {
    return (unsigned int)f2bf(lo) | ((unsigned int)f2bf(hi) << 16);
}
__device__ inline float bflo(unsigned int p) { return __uint_as_float(p << 16); }
__device__ inline float bfhi(unsigned int p) { return __uint_as_float(p & 0xffff0000u); }

// ================= degree + histogram =================
__global__ void k_init_deg(float* deg, int n) {
    int i = blockIdx.x * blockDim.x + threadIdx.x;
    if (i < n) deg[i] = 1.0f;   // self-loop weight
}

__global__ void k_deg_hist(const int* __restrict__ dst, const float* __restrict__ w,
                           float* __restrict__ deg, int* __restrict__ hist, int e) {
    int i = blockIdx.x * blockDim.x + threadIdx.x;
    if (i < e) {
        int d = dst[i];
        atomicAdd(&deg[d], w[i]);
        atomicAdd(&hist[d], 1);
    }
}

__global__ void k_finalize_dinv(float* d, int n) {
    int i = blockIdx.x * blockDim.x + threadIdx.x;
    if (i < n) {
        float v = d[i];
        d[i] = v > 0.0f ? rsqrtf(v) : 0.0f;
    }
}

// ================= exclusive scan (3-kernel) =================
__global__ void k_scan_local(int* __restrict__ R, int* __restrict__ bsum, int n) {
    __shared__ int s[256];
    int t = threadIdx.x;
    int base = blockIdx.x * 1024 + t * 4;
    int v0 = (base + 0 < n) ? R[base + 0] : 0;
    int v1 = (base + 1 < n) ? R[base + 1] : 0;
    int v2 = (base + 2 < n) ? R[base + 2] : 0;
    int v3 = (base + 3 < n) ? R[base + 3] : 0;
    int sum = v0 + v1 + v2 + v3;
    s[t] = sum;
    __syncthreads();
    for (int off = 1; off < 256; off <<= 1) {
        int u = (t >= off) ? s[t - off] : 0;
        __syncthreads();
        s[t] += u;
        __syncthreads();
    }
    if (t == 255) bsum[blockIdx.x] = s[255];
    int run = s[t] - sum;
    if (base + 0 < n) R[base + 0] = run;  run += v0;
    if (base + 1 < n) R[base + 1] = run;  run += v1;
    if (base + 2 < n) R[base + 2] = run;  run += v2;
    if (base + 3 < n) R[base + 3] = run;
}

__global__ void k_scan_bsum(int* __restrict__ bsum, int nb) {
    __shared__ int s[128];
    int t = threadIdx.x;
    int v = (t < nb) ? bsum[t] : 0;
    s[t] = v;
    __syncthreads();
    for (int off = 1; off < 128; off <<= 1) {
        int u = (t >= off) ? s[t - off] : 0;
        __syncthreads();
        s[t] += u;
        __syncthreads();
    }
    if (t < nb) bsum[t] = s[t] - v;
}

__global__ void k_scan_add(int* __restrict__ R, const int* __restrict__ bsum, int n) {
    int add = bsum[blockIdx.x];
    int base = blockIdx.x * 1024 + threadIdx.x * 4;
    for (int k = 0; k < 4; ++k)
        if (base + k < n) R[base + k] += add;
}

// ================= CSR placement =================
__global__ void k_place(const int* __restrict__ src, const int* __restrict__ dst,
                        const float* __restrict__ w, const float* __restrict__ dinv,
                        int* __restrict__ R, int* __restrict__ esrc,
                        float* __restrict__ enorm, int e) {
    int i = blockIdx.x * blockDim.x + threadIdx.x;
    if (i < e) {
        int s = src[i], d = dst[i];
        float nm = dinv[s] * w[i] * dinv[d];
        int pos = atomicAdd(&R[d], 1);
        esrc[pos] = s;
        enorm[pos] = nm;
    }
}

// ================= x -> bf16 =================
__global__ void k_xcast(const float* __restrict__ x, unsigned int* __restrict__ xbf, int n8) {
    int t = blockIdx.x * blockDim.x + threadIdx.x;
    if (t < n8) {
        float2 v = ((const float2*)x)[t];
        xbf[t] = packbf(v.x, v.y);
    }
}

// ================= aggregations (CSR, no atomics) =================
// layer-0: aggregate bf16 x (16 feats = 8 uints/row). 8 lanes/node.
__global__ void k_agg_x(const unsigned int* __restrict__ xbf, const int* __restrict__ esrc,
                        const float* __restrict__ enorm, const int* __restrict__ Rpost,
                        const float* __restrict__ dinv, float* __restrict__ xagg, int n) {
    int t = blockIdx.x * blockDim.x + threadIdx.x;
    int node = t >> 3, u = t & 7;
    if (node >= n) return;
    int start = node ? Rpost[node - 1] : 0;
    int end = Rpost[node];
    float ax = 0.f, ay = 0.f;
    for (int j = start; j < end; ++j) {
        int s = esrc[j];
        float nm = enorm[j];
        unsigned int p = xbf[(size_t)s * 8 + u];
        ax += bflo(p) * nm;
        ay += bfhi(p) * nm;
    }
    float di = dinv[node];
    unsigned int ps = xbf[(size_t)node * 8 + u];
    ax += bflo(ps) * di * di;
    ay += bfhi(ps) * di * di;
    ((float2*)xagg)[(size_t)node * 8 + u] = make_float2(ax, ay);
}

// layer-1: 128-feature bf16 aggregation. one wave/node, 1 uint (2 feats)/lane.
__global__ void k_aggregate128(const unsigned int* __restrict__ Abf, const int* __restrict__ esrc,
                               const float* __restrict__ enorm, const int* __restrict__ Rpost,
                               const float* __restrict__ dinv, const float* __restrict__ bias,
                               float* __restrict__ B, int n) {
    int gid = blockIdx.x * blockDim.x + threadIdx.x;
    int node = gid >> 6;
    int lane = threadIdx.x & 63;
    if (node >= n) return;
    int start = node ? Rpost[node - 1] : 0;
    int end = Rpost[node];
    float ax = 0.f, ay = 0.f;
    for (int base = start; base < end; base += 64) {
        int m = end - base; if (m > 64) m = 64;
        int myS = 0; float myN = 0.f;
        if (lane < m) { myS = esrc[base + lane]; myN = enorm[base + lane]; }
        for (int j = 0; j < m; ++j) {
            int s = __shfl(myS, j);
            float nm = __shfl(myN, j);
            unsigned int p = Abf[(size_t)s * 64 + lane];
            ax += bflo(p) * nm;
            ay += bfhi(p) * nm;
        }
    }
    float di = dinv[node];
    unsigned int ps = Abf[(size_t)node * 64 + lane];
    ax += bflo(ps) * di * di + bias[2 * lane];
    ay += bfhi(ps) * di * di + bias[2 * lane + 1];
    ((float2*)B)[(size_t)node * 64 + lane] = make_float2(ax, ay);
}

// layer-2: 12-feature aggregation over bf16 stride-16 rows (8 uints). 8 lanes/node, 6 active.
__global__ void k_agg_out(const unsigned int* __restrict__ A16bf, const int* __restrict__ esrc,
                          const float* __restrict__ enorm, const int* __restrict__ Rpost,
                          const float* __restrict__ dinv, const float* __restrict__ b2,
                          float* __restrict__ out, int n) {
    int t = blockIdx.x * blockDim.x + threadIdx.x;
    int node = t >> 3, u = t & 7;
    if (node >= n || u >= 6) return;
    int start = node ? Rpost[node - 1] : 0;
    int end = Rpost[node];
    float ax = 0.f, ay = 0.f;
    for (int j = start; j < end; ++j) {
        int s = esrc[j];
        float nm = enorm[j];
        unsigned int p = A16bf[(size_t)s * 8 + u];
        ax += bflo(p) * nm;
        ay += bfhi(p) * nm;
    }
    float di = dinv[node];
    unsigned int ps = A16bf[(size_t)node * 8 + u];
    ax += bflo(ps) * di * di + b2[2 * u];
    ay += bfhi(ps) * di * di + b2[2 * u + 1];
    ((float2*)(out + (size_t)node * 12))[u] = make_float2(ax, ay);
}

// ================= GEMMs =================
// xagg(N,16) @ W0(16,128) + b0 -> B(N,128) fp32
__global__ void k_gemm_in(const float* __restrict__ x, const float* __restrict__ W,
                          const float* __restrict__ b, float* __restrict__ out, int n) {
    __shared__ float Ws[16 * 128];
    __shared__ float xs[8 * 16];
    int f = threadIdx.x;
    #pragma unroll
    for (int k = 0; k < 16; ++k) Ws[k * 128 + f] = W[k * 128 + f];
    int node0 = blockIdx.x * 8;
    int nrows = n - node0; if (nrows > 8) nrows = 8;
    if (f < nrows * 16) xs[f] = x[(size_t)node0 * 16 + f];
    __syncthreads();
    float bf = b[f];
    for (int nl = 0; nl < nrows; ++nl) {
        float acc = bf;
        #pragma unroll
        for (int k = 0; k < 16; ++k) acc += xs[nl * 16 + k] * Ws[k * 128 + f];
        out[(size_t)(node0 + nl) * 128 + f] = acc;
    }
}

// BN0+ReLU fused on load; (N,128)@W1(128,128) -> Abf bf16 packed (64 uints/row)
__global__ void k_gemm_hid_bn(const float* __restrict__ Bin, const float* __restrict__ sums,
                              const float* __restrict__ sumsq, const float* __restrict__ g,
                              const float* __restrict__ be, const float* __restrict__ W,
                              unsigned int* __restrict__ Abf, int n, float invn) {
    __shared__ float hs[16 * 128];
    __shared__ float sc[128], sh[128];
    int tid = threadIdx.x;
    if (tid < 128) {
        float m = sums[tid] * invn;
        float v = sumsq[tid] * invn - m * m;
        float scale = rsqrtf(v + EPS_BN) * g[tid];
        sc[tid] = scale;
        sh[tid] = be[tid] - m * scale;
    }
    __syncthreads();
    int f = tid & 127;
    int half = tid >> 7;
    int node0 = blockIdx.x * 16;
    int nrows = n - node0; if (nrows > 16) nrows = 16;
    const float4* B4 = (const float4*)(Bin + (size_t)node0 * 128);
    float4* hs4 = (float4*)hs;
    for (int i = tid; i < nrows * 32; i += 256) {
        float4 v = B4[i];
        int fb = (i & 31) * 4;
        v.x = fmaxf(v.x * sc[fb + 0] + sh[fb + 0], 0.f);
        v.y = fmaxf(v.y * sc[fb + 1] + sh[fb + 1], 0.f);
        v.z = fmaxf(v.z * sc[fb + 2] + sh[fb + 2], 0.f);
        v.w = fmaxf(v.w * sc[fb + 3] + sh[fb + 3], 0.f);
        hs4[i] = v;
    }
    __syncthreads();
    float acc[8] = {0.f, 0.f, 0.f, 0.f, 0.f, 0.f, 0.f, 0.f};
    for (int k4 = 0; k4 < 32; ++k4) {
        float w0 = W[(k4 * 4 + 0) * 128 + f];
        float w1 = W[(k4 * 4 + 1) * 128 + f];
        float w2 = W[(k4 * 4 + 2) * 128 + f];
        float w3 = W[(k4 * 4 + 3) * 128 + f];
        #pragma unroll
        for (int i = 0; i < 8; ++i) {
            float4 hv = hs4[(half + 2 * i) * 32 + k4];
            acc[i] += hv.x * w0 + hv.y * w1 + hv.z * w2 + hv.w * w3;
        }
    }
    __syncthreads();   // all reads of hs done
    #pragma unroll
    for (int i = 0; i < 8; ++i) {
        int nl = half + 2 * i;
        if (nl < nrows) hs[nl * 128 + f] = acc[i];
    }
    __syncthreads();
    unsigned int* A0 = Abf + (size_t)node0 * 64;
    for (int i = tid; i < nrows * 64; i += 256) {
        int nl = i >> 6, fp = i & 63;
        A0[i] = packbf(hs[nl * 128 + 2 * fp], hs[nl * 128 + 2 * fp + 1]);
    }
}

// BN1+ReLU fused on load; (N,128)@W2(128,12) -> A16bf bf16 stride-16 (8 uints/row, pads 0)
__global__ void k_gemm_out_bn(const float* __restrict__ Bin, const float* __restrict__ sums,
                              const float* __restrict__ sumsq, const float* __restrict__ g,
                              const float* __restrict__ be, const float* __restrict__ W,
                              unsigned int* __restrict__ A16bf, int n, float invn) {
    __shared__ float hs[16 * 129];
    __shared__ float Ws[128 * 12];
    __shared__ float sc[128], sh[128];
    __shared__ float outv[16 * 12];
    int tid = threadIdx.x;   // 192
    if (tid < 128) {
        float m = sums[tid] * invn;
        float v = sumsq[tid] * invn - m * m;
        float scale = rsqrtf(v + EPS_BN) * g[tid];
        sc[tid] = scale;
        sh[tid] = be[tid] - m * scale;
    }
    for (int i = tid; i < 128 * 12; i += 192) Ws[i] = W[i];
    int node0 = blockIdx.x * 16;
    int nrows = n - node0; if (nrows > 16) nrows = 16;
    __syncthreads();
    for (int i = tid; i < nrows * 128; i += 192) {
        int f = i & 127;
        float v = Bin[(size_t)node0 * 128 + i];
        hs[(i >> 7) * 129 + f] = fmaxf(v * sc[f] + sh[f], 0.f);
    }
    __syncthreads();
    int nl = tid / 12, f = tid - nl * 12;
    if (nl < 16 && nl < nrows) {
        float acc = 0.f;
        for (int k = 0; k < 128; ++k) acc += hs[nl * 129 + k] * Ws[k * 12 + f];
        outv[nl * 12 + f] = acc;
    }
    __syncthreads();
    for (int i = tid; i < nrows * 8; i += 192) {
        int nn = i >> 3, u = i & 7;
        float lo = (2 * u < 12)     ? outv[nn * 12 + 2 * u]     : 0.f;
        float hi = (2 * u + 1 < 12) ? outv[nn * 12 + 2 * u + 1] : 0.f;
        A16bf[(size_t)(node0 + nn) * 8 + u] = packbf(lo, hi);
    }
}

// ================= batch norm stats =================
__global__ void k_bn_stats(const float* __restrict__ h, float* __restrict__ sums,
                           float* __restrict__ sumsq, int n) {
    int f = threadIdx.x;             // 128
    int i0 = blockIdx.x * 256;
    int i1 = i0 + 256; if (i1 > n) i1 = n;
    float s = 0.f, ss = 0.f;
    for (int i = i0; i < i1; ++i) {
        float v = h[(size_t)i * 128 + f];
        s += v; ss += v * v;
    }
    atomicAdd(&sums[f], s);
    atomicAdd(&sumsq[f], ss);
}

// ================= launch =================
extern "C" void kernel_launch(void* const* d_in, const int* in_sizes, int n_in,
                              void* d_out, int out_size, void* d_ws, size_t ws_size,
                              hipStream_t stream) {
    const float* x   = (const float*)d_in[0];
    const int*   ei  = (const int*)d_in[1];
    const float* ew  = (const float*)d_in[2];
    const float* W0  = (const float*)d_in[3];
    const float* b0  = (const float*)d_in[4];
    const float* W1  = (const float*)d_in[5];
    const float* b1  = (const float*)d_in[6];
    const float* W2  = (const float*)d_in[7];
    const float* b2  = (const float*)d_in[8];
    const float* g0  = (const float*)d_in[9];
    const float* be0 = (const float*)d_in[10];
    const float* g1  = (const float*)d_in[11];
    const float* be1 = (const float*)d_in[12];
    float* out = (float*)d_out;

    const int n = in_sizes[0] / 16;   // 100000
    const int e = in_sizes[2];        // 1600000
    const int* src = ei;
    const int* dst = ei + e;

    // workspace layout (4B elems)
    float*        wsf   = (float*)d_ws;
    float*        dinv  = wsf;                               // n
    int*          R     = (int*)(wsf + n);                   // n+4
    int*          bsum  = R + (n + 4);                       // 128
    int*          esrc  = bsum + 128;                        // e
    float*        enorm = (float*)(esrc + e);                // e
    float*        B     = enorm + e;                         // n*128 fp32
    unsigned int* Abf   = (unsigned int*)(B + (size_t)n * 128);  // n*64
    unsigned int* xbf   = Abf + (size_t)n * 64;              // n*8
    float*        xagg  = (float*)(xbf + (size_t)n * 8);     // n*16
    unsigned int* A16bf = (unsigned int*)(xagg + (size_t)n * 16); // n*8
    float*        sums  = (float*)(A16bf + (size_t)n * 8);   // 128
    float*        sumsq = sums + 128;                        // 128

    const float invn = 1.0f / (float)n;
    const int nb_scan = (n + 1023) / 1024;

    // ---- degree + CSR build ----
    k_init_deg<<<(n + 255) / 256, 256, 0, stream>>>(dinv, n);
    hipMemsetAsync(R, 0, (size_t)(n + 4) * sizeof(int), stream);
    k_deg_hist<<<(e + 255) / 256, 256, 0, stream>>>(dst, ew, dinv, R, e);
    k_finalize_dinv<<<(n + 255) / 256, 256, 0, stream>>>(dinv, n);
    k_scan_local<<<nb_scan, 256, 0, stream>>>(R, bsum, n);
    k_scan_bsum<<<1, 128, 0, stream>>>(bsum, nb_scan);
    k_scan_add<<<nb_scan, 256, 0, stream>>>(R, bsum, n);
    k_place<<<(e + 255) / 256, 256, 0, stream>>>(src, dst, ew, dinv, R, esrc, enorm, e);

    // ---- layer 0 ----
    k_xcast<<<(n * 8 + 255) / 256, 256, 0, stream>>>(x, xbf, n * 8);
    k_agg_x<<<(n * 8 + 255) / 256, 256, 0, stream>>>(xbf, esrc, enorm, R, dinv, xagg, n);
    k_gemm_in<<<(n + 7) / 8, 128, 0, stream>>>(xagg, W0, b0, B, n);
    hipMemsetAsync(sums, 0, 256 * sizeof(float), stream);
    k_bn_stats<<<(n + 255) / 256, 128, 0, stream>>>(B, sums, sumsq, n);

    // ---- layer 1 ----
    k_gemm_hid_bn<<<(n + 15) / 16, 256, 0, stream>>>(B, sums, sumsq, g0, be0, W1, Abf, n, invn);
    k_aggregate128<<<(n * 64 + 255) / 256, 256, 0, stream>>>(Abf, esrc, enorm, R, dinv, b1, B, n);
    hipMemsetAsync(sums, 0, 256 * sizeof(float), stream);
    k_bn_stats<<<(n + 255) / 256, 128, 0, stream>>>(B, sums, sumsq, n);

    // ---- layer 2 ----
    k_gemm_out_bn<<<(n + 15) / 16, 192, 0, stream>>>(B, sums, sumsq, g1, be1, W2, A16bf, n, invn);
    k_agg_out<<<(n * 8 + 255) / 256, 256, 0, stream>>>(A16bf, esrc, enorm, R, dinv, b2, out, n);
}

// Round 4
// 661.709 us; speedup vs baseline: 8.9758x; 1.1921x over previous
//
#include <hip/hip_runtime.h>

#define EPS_BN 1e-5f

__device__ inline unsigned short f2bf(float f) {
    unsigned int u = __float_as_uint(f);
    unsigned int r = (u + 0x7fffu + ((u >> 16) & 1u)) >> 16;
    return (unsigned short)r;
}
__device__ inline unsigned int packbf(float lo, float hi) {
    return (unsigned int)f2bf(lo) | ((unsigned int)f2bf(hi) << 16);
}
__device__ inline float bflo(unsigned int p) { return __uint_as_float(p << 16); }
__device__ inline float bfhi(unsigned int p) { return __uint_as_float(p & 0xffff0000u); }

// ================= CSR build: 1 atomic per edge =================
// rank[i] = old count of dst[i]; after this, R[d] = degree(d)
__global__ void k_hist_rank(const int* __restrict__ dst, int* __restrict__ R,
                            int* __restrict__ rank, int e) {
    int i = blockIdx.x * blockDim.x + threadIdx.x;
    if (i < e) rank[i] = atomicAdd(&R[dst[i]], 1);
}

// ================= exclusive scan (3-kernel) =================
__global__ void k_scan_local(int* __restrict__ R, int* __restrict__ bsum, int n) {
    __shared__ int s[256];
    int t = threadIdx.x;
    int base = blockIdx.x * 1024 + t * 4;
    int v0 = (base + 0 < n) ? R[base + 0] : 0;
    int v1 = (base + 1 < n) ? R[base + 1] : 0;
    int v2 = (base + 2 < n) ? R[base + 2] : 0;
    int v3 = (base + 3 < n) ? R[base + 3] : 0;
    int sum = v0 + v1 + v2 + v3;
    s[t] = sum;
    __syncthreads();
    for (int off = 1; off < 256; off <<= 1) {
        int u = (t >= off) ? s[t - off] : 0;
        __syncthreads();
        s[t] += u;
        __syncthreads();
    }
    if (t == 255) bsum[blockIdx.x] = s[255];
    int run = s[t] - sum;
    if (base + 0 < n) R[base + 0] = run;  run += v0;
    if (base + 1 < n) R[base + 1] = run;  run += v1;
    if (base + 2 < n) R[base + 2] = run;  run += v2;
    if (base + 3 < n) R[base + 3] = run;
}

__global__ void k_scan_bsum(int* __restrict__ bsum, int nb) {
    __shared__ int s[128];
    int t = threadIdx.x;
    int v = (t < nb) ? bsum[t] : 0;
    s[t] = v;
    __syncthreads();
    for (int off = 1; off < 128; off <<= 1) {
        int u = (t >= off) ? s[t - off] : 0;
        __syncthreads();
        s[t] += u;
        __syncthreads();
    }
    if (t < nb) bsum[t] = s[t] - v;
}

__global__ void k_scan_add(int* __restrict__ R, const int* __restrict__ bsum, int n) {
    int add = bsum[blockIdx.x];
    int base = blockIdx.x * 1024 + threadIdx.x * 4;
    for (int k = 0; k < 4; ++k)
        if (base + k < n) R[base + k] += add;
}

// atomic-free placement: epair[start[d]+rank] = {src, w-bits}
__global__ void k_place(const int* __restrict__ src, const int* __restrict__ dst,
                        const float* __restrict__ w, const int* __restrict__ rank,
                        const int* __restrict__ R, uint2* __restrict__ epair, int e) {
    int i = blockIdx.x * blockDim.x + threadIdx.x;
    if (i < e) {
        int d = dst[i];
        int pos = R[d] + rank[i];
        epair[pos] = make_uint2((unsigned int)src[i], __float_as_uint(w[i]));
    }
}

// contiguous per-row sum of w -> dinv
__global__ void k_deg_dinv(const uint2* __restrict__ epair, const int* __restrict__ R,
                           float* __restrict__ dinv, int n, int e) {
    int node = blockIdx.x * blockDim.x + threadIdx.x;
    if (node >= n) return;
    int start = R[node];
    int end = (node + 1 < n) ? R[node + 1] : e;
    float sum = 1.0f;   // self-loop
    for (int j = start; j < end; ++j) sum += __uint_as_float(epair[j].y);
    dinv[node] = rsqrtf(sum);
}

// rewrite pair.y: w -> dinv[src]*w*dinv[node]
__global__ void k_enorm(uint2* __restrict__ epair, const int* __restrict__ R,
                        const float* __restrict__ dinv, int n, int e) {
    int node = blockIdx.x * blockDim.x + threadIdx.x;
    if (node >= n) return;
    int start = R[node];
    int end = (node + 1 < n) ? R[node + 1] : e;
    float di = dinv[node];
    for (int j = start; j < end; ++j) {
        uint2 p = epair[j];
        float w = __uint_as_float(p.y);
        p.y = __float_as_uint(dinv[p.x] * w * di);
        epair[j] = p;
    }
}

// ================= x -> bf16 =================
__global__ void k_xcast(const float* __restrict__ x, unsigned int* __restrict__ xbf, int n8) {
    int t = blockIdx.x * blockDim.x + threadIdx.x;
    if (t < n8) {
        float2 v = ((const float2*)x)[t];
        xbf[t] = packbf(v.x, v.y);
    }
}

// ================= aggregations (CSR, no atomics) =================
// layer-0: aggregate bf16 x (16 feats = 8 uints/row). 8 lanes/node.
__global__ void k_agg_x(const unsigned int* __restrict__ xbf, const uint2* __restrict__ epair,
                        const int* __restrict__ R, const float* __restrict__ dinv,
                        float* __restrict__ xagg, int n, int e) {
    int t = blockIdx.x * blockDim.x + threadIdx.x;
    int node = t >> 3, u = t & 7;
    if (node >= n) return;
    int start = R[node];
    int end = (node + 1 < n) ? R[node + 1] : e;
    float ax = 0.f, ay = 0.f;
    for (int j = start; j < end; ++j) {
        uint2 pr = epair[j];
        float nm = __uint_as_float(pr.y);
        unsigned int p = xbf[(size_t)pr.x * 8 + u];
        ax += bflo(p) * nm;
        ay += bfhi(p) * nm;
    }
    float di = dinv[node];
    unsigned int ps = xbf[(size_t)node * 8 + u];
    ax += bflo(ps) * di * di;
    ay += bfhi(ps) * di * di;
    ((float2*)xagg)[(size_t)node * 8 + u] = make_float2(ax, ay);
}

// layer-1: 128-feature bf16 aggregation. one wave/node, 1 uint (2 feats)/lane.
__global__ void k_aggregate128(const unsigned int* __restrict__ Abf, const uint2* __restrict__ epair,
                               const int* __restrict__ R, const float* __restrict__ dinv,
                               const float* __restrict__ bias, float* __restrict__ B, int n, int e) {
    int gid = blockIdx.x * blockDim.x + threadIdx.x;
    int node = gid >> 6;
    int lane = threadIdx.x & 63;
    if (node >= n) return;
    int start = R[node];
    int end = (node + 1 < n) ? R[node + 1] : e;
    float ax = 0.f, ay = 0.f;
    for (int base = start; base < end; base += 64) {
        int m = end - base; if (m > 64) m = 64;
        int myS = 0; float myN = 0.f;
        if (lane < m) {
            uint2 pr = epair[base + lane];
            myS = (int)pr.x;
            myN = __uint_as_float(pr.y);
        }
        for (int j = 0; j < m; ++j) {
            int s = __shfl(myS, j);
            float nm = __shfl(myN, j);
            unsigned int p = Abf[(size_t)s * 64 + lane];
            ax += bflo(p) * nm;
            ay += bfhi(p) * nm;
        }
    }
    float di = dinv[node];
    unsigned int ps = Abf[(size_t)node * 64 + lane];
    ax += bflo(ps) * di * di + bias[2 * lane];
    ay += bfhi(ps) * di * di + bias[2 * lane + 1];
    ((float2*)B)[(size_t)node * 64 + lane] = make_float2(ax, ay);
}

// layer-2: 12-feature aggregation over bf16 stride-16 rows. 8 lanes/node, 6 active.
__global__ void k_agg_out(const unsigned int* __restrict__ A16bf, const uint2* __restrict__ epair,
                          const int* __restrict__ R, const float* __restrict__ dinv,
                          const float* __restrict__ b2, float* __restrict__ out, int n, int e) {
    int t = blockIdx.x * blockDim.x + threadIdx.x;
    int node = t >> 3, u = t & 7;
    if (node >= n || u >= 6) return;
    int start = R[node];
    int end = (node + 1 < n) ? R[node + 1] : e;
    float ax = 0.f, ay = 0.f;
    for (int j = start; j < end; ++j) {
        uint2 pr = epair[j];
        float nm = __uint_as_float(pr.y);
        unsigned int p = A16bf[(size_t)pr.x * 8 + u];
        ax += bflo(p) * nm;
        ay += bfhi(p) * nm;
    }
    float di = dinv[node];
    unsigned int ps = A16bf[(size_t)node * 8 + u];
    ax += bflo(ps) * di * di + b2[2 * u];
    ay += bfhi(ps) * di * di + b2[2 * u + 1];
    ((float2*)(out + (size_t)node * 12))[u] = make_float2(ax, ay);
}

// ================= GEMMs =================
__global__ void k_gemm_in(const float* __restrict__ x, const float* __restrict__ W,
                          const float* __restrict__ b, float* __restrict__ out, int n) {
    __shared__ float Ws[16 * 128];
    __shared__ float xs[8 * 16];
    int f = threadIdx.x;
    #pragma unroll
    for (int k = 0; k < 16; ++k) Ws[k * 128 + f] = W[k * 128 + f];
    int node0 = blockIdx.x * 8;
    int nrows = n - node0; if (nrows > 8) nrows = 8;
    if (f < nrows * 16) xs[f] = x[(size_t)node0 * 16 + f];
    __syncthreads();
    float bf = b[f];
    for (int nl = 0; nl < nrows; ++nl) {
        float acc = bf;
        #pragma unroll
        for (int k = 0; k < 16; ++k) acc += xs[nl * 16 + k] * Ws[k * 128 + f];
        out[(size_t)(node0 + nl) * 128 + f] = acc;
    }
}

// BN0+ReLU fused on load; (N,128)@W1(128,128) -> Abf bf16 packed (64 uints/row)
__global__ void k_gemm_hid_bn(const float* __restrict__ Bin, const float* __restrict__ sums,
                              const float* __restrict__ sumsq, const float* __restrict__ g,
                              const float* __restrict__ be, const float* __restrict__ W,
                              unsigned int* __restrict__ Abf, int n, float invn) {
    __shared__ float hs[16 * 128];
    __shared__ float sc[128], sh[128];
    int tid = threadIdx.x;
    if (tid < 128) {
        float m = sums[tid] * invn;
        float v = sumsq[tid] * invn - m * m;
        float scale = rsqrtf(v + EPS_BN) * g[tid];
        sc[tid] = scale;
        sh[tid] = be[tid] - m * scale;
    }
    __syncthreads();
    int f = tid & 127;
    int half = tid >> 7;
    int node0 = blockIdx.x * 16;
    int nrows = n - node0; if (nrows > 16) nrows = 16;
    const float4* B4 = (const float4*)(Bin + (size_t)node0 * 128);
    float4* hs4 = (float4*)hs;
    for (int i = tid; i < nrows * 32; i += 256) {
        float4 v = B4[i];
        int fb = (i & 31) * 4;
        v.x = fmaxf(v.x * sc[fb + 0] + sh[fb + 0], 0.f);
        v.y = fmaxf(v.y * sc[fb + 1] + sh[fb + 1], 0.f);
        v.z = fmaxf(v.z * sc[fb + 2] + sh[fb + 2], 0.f);
        v.w = fmaxf(v.w * sc[fb + 3] + sh[fb + 3], 0.f);
        hs4[i] = v;
    }
    __syncthreads();
    float acc[8] = {0.f, 0.f, 0.f, 0.f, 0.f, 0.f, 0.f, 0.f};
    for (int k4 = 0; k4 < 32; ++k4) {
        float w0 = W[(k4 * 4 + 0) * 128 + f];
        float w1 = W[(k4 * 4 + 1) * 128 + f];
        float w2 = W[(k4 * 4 + 2) * 128 + f];
        float w3 = W[(k4 * 4 + 3) * 128 + f];
        #pragma unroll
        for (int i = 0; i < 8; ++i) {
            float4 hv = hs4[(half + 2 * i) * 32 + k4];
            acc[i] += hv.x * w0 + hv.y * w1 + hv.z * w2 + hv.w * w3;
        }
    }
    __syncthreads();
    #pragma unroll
    for (int i = 0; i < 8; ++i) {
        int nl = half + 2 * i;
        if (nl < nrows) hs[nl * 128 + f] = acc[i];
    }
    __syncthreads();
    unsigned int* A0 = Abf + (size_t)node0 * 64;
    for (int i = tid; i < nrows * 64; i += 256) {
        int nl = i >> 6, fp = i & 63;
        A0[i] = packbf(hs[nl * 128 + 2 * fp], hs[nl * 128 + 2 * fp + 1]);
    }
}

// BN1+ReLU fused on load; (N,128)@W2(128,12) -> A16bf bf16 stride-16
__global__ void k_gemm_out_bn(const float* __restrict__ Bin, const float* __restrict__ sums,
                              const float* __restrict__ sumsq, const float* __restrict__ g,
                              const float* __restrict__ be, const float* __restrict__ W,
                              unsigned int* __restrict__ A16bf, int n, float invn) {
    __shared__ float hs[16 * 129];
    __shared__ float Ws[128 * 12];
    __shared__ float sc[128], sh[128];
    __shared__ float outv[16 * 12];
    int tid = threadIdx.x;   // 192
    if (tid < 128) {
        float m = sums[tid] * invn;
        float v = sumsq[tid] * invn - m * m;
        float scale = rsqrtf(v + EPS_BN) * g[tid];
        sc[tid] = scale;
        sh[tid] = be[tid] - m * scale;
    }
    for (int i = tid; i < 128 * 12; i += 192) Ws[i] = W[i];
    int node0 = blockIdx.x * 16;
    int nrows = n - node0; if (nrows > 16) nrows = 16;
    __syncthreads();
    for (int i = tid; i < nrows * 128; i += 192) {
        int f = i & 127;
        float v = Bin[(size_t)node0 * 128 + i];
        hs[(i >> 7) * 129 + f] = fmaxf(v * sc[f] + sh[f], 0.f);
    }
    __syncthreads();
    int nl = tid / 12, f = tid - nl * 12;
    if (nl < 16 && nl < nrows) {
        float acc = 0.f;
        for (int k = 0; k < 128; ++k) acc += hs[nl * 129 + k] * Ws[k * 12 + f];
        outv[nl * 12 + f] = acc;
    }
    __syncthreads();
    for (int i = tid; i < nrows * 8; i += 192) {
        int nn = i >> 3, u = i & 7;
        float lo = (2 * u < 12)     ? outv[nn * 12 + 2 * u]     : 0.f;
        float hi = (2 * u + 1 < 12) ? outv[nn * 12 + 2 * u + 1] : 0.f;
        A16bf[(size_t)(node0 + nn) * 8 + u] = packbf(lo, hi);
    }
}

// ================= batch norm stats =================
__global__ void k_bn_stats(const float* __restrict__ h, float* __restrict__ sums,
                           float* __restrict__ sumsq, int n) {
    int f = threadIdx.x;             // 128
    int i0 = blockIdx.x * 256;
    int i1 = i0 + 256; if (i1 > n) i1 = n;
    float s = 0.f, ss = 0.f;
    for (int i = i0; i < i1; ++i) {
        float v = h[(size_t)i * 128 + f];
        s += v; ss += v * v;
    }
    atomicAdd(&sums[f], s);
    atomicAdd(&sumsq[f], ss);
}

// ================= launch =================
extern "C" void kernel_launch(void* const* d_in, const int* in_sizes, int n_in,
                              void* d_out, int out_size, void* d_ws, size_t ws_size,
                              hipStream_t stream) {
    const float* x   = (const float*)d_in[0];
    const int*   ei  = (const int*)d_in[1];
    const float* ew  = (const float*)d_in[2];
    const float* W0  = (const float*)d_in[3];
    const float* b0  = (const float*)d_in[4];
    const float* W1  = (const float*)d_in[5];
    const float* b1  = (const float*)d_in[6];
    const float* W2  = (const float*)d_in[7];
    const float* b2  = (const float*)d_in[8];
    const float* g0  = (const float*)d_in[9];
    const float* be0 = (const float*)d_in[10];
    const float* g1  = (const float*)d_in[11];
    const float* be1 = (const float*)d_in[12];
    float* out = (float*)d_out;

    const int n = in_sizes[0] / 16;   // 100000
    const int e = in_sizes[2];        // 1600000
    const int* src = ei;
    const int* dst = ei + e;

    // workspace layout (4B elems); rank[] aliases B (dead after k_place, B written later)
    float*        wsf   = (float*)d_ws;
    float*        dinv  = wsf;                                    // n
    int*          R     = (int*)(wsf + n);                        // n+4
    int*          bsum  = R + (n + 4);                            // 128
    uint2*        epair = (uint2*)(bsum + 128);                   // e pairs (2e words, 8B-aligned)
    float*        B     = (float*)(bsum + 128 + 2 * (size_t)e);   // n*128 fp32
    int*          rank  = (int*)B;                                // e ints, aliases B
    unsigned int* Abf   = (unsigned int*)(B + (size_t)n * 128);   // n*64
    unsigned int* xbf   = Abf + (size_t)n * 64;                   // n*8
    float*        xagg  = (float*)(xbf + (size_t)n * 8);          // n*16
    unsigned int* A16bf = (unsigned int*)(xagg + (size_t)n * 16); // n*8
    float*        sums  = (float*)(A16bf + (size_t)n * 8);        // 128
    float*        sumsq = sums + 128;                             // 128

    const float invn = 1.0f / (float)n;
    const int nb_scan = (n + 1023) / 1024;

    // ---- CSR build (single atomic pass) ----
    hipMemsetAsync(R, 0, (size_t)(n + 4) * sizeof(int), stream);
    k_xcast<<<(n * 8 + 255) / 256, 256, 0, stream>>>(x, xbf, n * 8);
    k_hist_rank<<<(e + 255) / 256, 256, 0, stream>>>(dst, R, rank, e);
    k_scan_local<<<nb_scan, 256, 0, stream>>>(R, bsum, n);
    k_scan_bsum<<<1, 128, 0, stream>>>(bsum, nb_scan);
    k_scan_add<<<nb_scan, 256, 0, stream>>>(R, bsum, n);
    k_place<<<(e + 255) / 256, 256, 0, stream>>>(src, dst, ew, rank, R, epair, e);
    k_deg_dinv<<<(n + 255) / 256, 256, 0, stream>>>(epair, R, dinv, n, e);
    k_enorm<<<(n + 255) / 256, 256, 0, stream>>>(epair, R, dinv, n, e);

    // ---- layer 0 ----
    k_agg_x<<<(n * 8 + 255) / 256, 256, 0, stream>>>(xbf, epair, R, dinv, xagg, n, e);
    k_gemm_in<<<(n + 7) / 8, 128, 0, stream>>>(xagg, W0, b0, B, n);
    hipMemsetAsync(sums, 0, 256 * sizeof(float), stream);
    k_bn_stats<<<(n + 255) / 256, 128, 0, stream>>>(B, sums, sumsq, n);

    // ---- layer 1 ----
    k_gemm_hid_bn<<<(n + 15) / 16, 256, 0, stream>>>(B, sums, sumsq, g0, be0, W1, Abf, n, invn);
    k_aggregate128<<<(n * 64 + 255) / 256, 256, 0, stream>>>(Abf, epair, R, dinv, b1, B, n, e);
    hipMemsetAsync(sums, 0, 256 * sizeof(float), stream);
    k_bn_stats<<<(n + 255) / 256, 128, 0, stream>>>(B, sums, sumsq, n);

    // ---- layer 2 ----
    k_gemm_out_bn<<<(n + 15) / 16, 192, 0, stream>>>(B, sums, sumsq, g1, be1, W2, A16bf, n, invn);
    k_agg_out<<<(n * 8 + 255) / 256, 256, 0, stream>>>(A16bf, epair, R, dinv, b2, out, n, e);
}

// Round 5
// 626.035 us; speedup vs baseline: 9.4873x; 1.0570x over previous
//
#include <hip/hip_runtime.h>

#define EPS_BN 1e-5f

__device__ inline unsigned short f2bf(float f) {
    unsigned int u = __float_as_uint(f);
    unsigned int r = (u + 0x7fffu + ((u >> 16) & 1u)) >> 16;
    return (unsigned short)r;
}
__device__ inline unsigned int packbf(float lo, float hi) {
    return (unsigned int)f2bf(lo) | ((unsigned int)f2bf(hi) << 16);
}
__device__ inline float bflo(unsigned int p) { return __uint_as_float(p << 16); }
__device__ inline float bfhi(unsigned int p) { return __uint_as_float(p & 0xffff0000u); }

// ================= CSR build: 1 atomic per edge =================
__global__ void k_hist_rank(const int* __restrict__ dst, int* __restrict__ R,
                            int* __restrict__ rank, int e) {
    int i = blockIdx.x * blockDim.x + threadIdx.x;
    if (i < e) rank[i] = atomicAdd(&R[dst[i]], 1);
}

// ================= exclusive scan (3-kernel) =================
__global__ void k_scan_local(int* __restrict__ R, int* __restrict__ bsum, int n) {
    __shared__ int s[256];
    int t = threadIdx.x;
    int base = blockIdx.x * 1024 + t * 4;
    int v0 = (base + 0 < n) ? R[base + 0] : 0;
    int v1 = (base + 1 < n) ? R[base + 1] : 0;
    int v2 = (base + 2 < n) ? R[base + 2] : 0;
    int v3 = (base + 3 < n) ? R[base + 3] : 0;
    int sum = v0 + v1 + v2 + v3;
    s[t] = sum;
    __syncthreads();
    for (int off = 1; off < 256; off <<= 1) {
        int u = (t >= off) ? s[t - off] : 0;
        __syncthreads();
        s[t] += u;
        __syncthreads();
    }
    if (t == 255) bsum[blockIdx.x] = s[255];
    int run = s[t] - sum;
    if (base + 0 < n) R[base + 0] = run;  run += v0;
    if (base + 1 < n) R[base + 1] = run;  run += v1;
    if (base + 2 < n) R[base + 2] = run;  run += v2;
    if (base + 3 < n) R[base + 3] = run;
}

__global__ void k_scan_bsum(int* __restrict__ bsum, int nb) {
    __shared__ int s[128];
    int t = threadIdx.x;
    int v = (t < nb) ? bsum[t] : 0;
    s[t] = v;
    __syncthreads();
    for (int off = 1; off < 128; off <<= 1) {
        int u = (t >= off) ? s[t - off] : 0;
        __syncthreads();
        s[t] += u;
        __syncthreads();
    }
    if (t < nb) bsum[t] = s[t] - v;
}

__global__ void k_scan_add(int* __restrict__ R, const int* __restrict__ bsum, int n) {
    int add = bsum[blockIdx.x];
    int base = blockIdx.x * 1024 + threadIdx.x * 4;
    for (int k = 0; k < 4; ++k)
        if (base + k < n) R[base + k] += add;
}

// atomic-free placement: epair[start[d]+rank] = {src, w-bits}
__global__ void k_place(const int* __restrict__ src, const int* __restrict__ dst,
                        const float* __restrict__ w, const int* __restrict__ rank,
                        const int* __restrict__ R, uint2* __restrict__ epair, int e) {
    int i = blockIdx.x * blockDim.x + threadIdx.x;
    if (i < e) {
        int d = dst[i];
        int pos = R[d] + rank[i];
        epair[pos] = make_uint2((unsigned int)src[i], __float_as_uint(w[i]));
    }
}

// contiguous per-row sum of w -> dinv
__global__ void k_deg_dinv(const uint2* __restrict__ epair, const int* __restrict__ R,
                           float* __restrict__ dinv, int n, int e) {
    int node = blockIdx.x * blockDim.x + threadIdx.x;
    if (node >= n) return;
    int start = R[node];
    int end = (node + 1 < n) ? R[node + 1] : e;
    float sum = 1.0f;   // self-loop
    for (int j = start; j < end; ++j) sum += __uint_as_float(epair[j].y);
    dinv[node] = rsqrtf(sum);
}

// ================= x -> bf16 =================
__global__ void k_xcast(const float* __restrict__ x, unsigned int* __restrict__ xbf, int n8) {
    int t = blockIdx.x * blockDim.x + threadIdx.x;
    if (t < n8) {
        float2 v = ((const float2*)x)[t];
        xbf[t] = packbf(v.x, v.y);
    }
}

// ================= aggregations (CSR, no atomics) =================
// layer-0: aggregate bf16 x (16 feats = 8 uints/row). 8 lanes/node, unroll 2.
// norm folded: acc = di * sum(dinv[s]*w * row_s) + di^2 * self
__global__ void k_agg_x(const unsigned int* __restrict__ xbf, const uint2* __restrict__ epair,
                        const int* __restrict__ R, const float* __restrict__ dinv,
                        float* __restrict__ xagg, int n, int e) {
    int t = blockIdx.x * blockDim.x + threadIdx.x;
    int node = t >> 3, u = t & 7;
    if (node >= n) return;
    int start = R[node];
    int end = (node + 1 < n) ? R[node + 1] : e;
    float ax = 0.f, ay = 0.f;
    int j = start;
    for (; j + 1 < end; j += 2) {
        uint2 p0 = epair[j], p1 = epair[j + 1];
        float w0 = dinv[p0.x] * __uint_as_float(p0.y);
        float w1 = dinv[p1.x] * __uint_as_float(p1.y);
        unsigned int q0 = xbf[(size_t)p0.x * 8 + u];
        unsigned int q1 = xbf[(size_t)p1.x * 8 + u];
        ax += bflo(q0) * w0 + bflo(q1) * w1;
        ay += bfhi(q0) * w0 + bfhi(q1) * w1;
    }
    if (j < end) {
        uint2 p0 = epair[j];
        float w0 = dinv[p0.x] * __uint_as_float(p0.y);
        unsigned int q0 = xbf[(size_t)p0.x * 8 + u];
        ax += bflo(q0) * w0;
        ay += bfhi(q0) * w0;
    }
    float di = dinv[node];
    unsigned int ps = xbf[(size_t)node * 8 + u];
    ax = ax * di + bflo(ps) * di * di;
    ay = ay * di + bfhi(ps) * di * di;
    ((float2*)xagg)[(size_t)node * 8 + u] = make_float2(ax, ay);
}

// layer-1: 128-feature bf16 aggregation. one wave/node, two 32-lane groups,
// uint2 (4 feats) per lane, 4 edges per loop trip, partials combined via shfl_xor.
__global__ void k_aggregate128(const uint2* __restrict__ Abf2, const uint2* __restrict__ epair,
                               const int* __restrict__ R, const float* __restrict__ dinv,
                               const float4* __restrict__ bias4, float4* __restrict__ B4,
                               int n, int e) {
    int gid = blockIdx.x * blockDim.x + threadIdx.x;
    int node = gid >> 6;
    if (node >= n) return;
    int lane = threadIdx.x & 63;
    int g = lane >> 5, sub = lane & 31;
    int start = R[node];
    int end = (node + 1 < n) ? R[node + 1] : e;
    float a0 = 0.f, a1 = 0.f, a2 = 0.f, a3 = 0.f;
    for (int base = start; base < end; base += 64) {
        int m = end - base; if (m > 64) m = 64;
        int myS = 0; float myW = 0.f;
        if (lane < m) {
            uint2 pr = epair[base + lane];
            myS = (int)pr.x;
            myW = dinv[pr.x] * __uint_as_float(pr.y);
        }
        for (int t = 0; t < m; t += 4) {
            int j0 = t + g;
            int j1 = t + 2 + g;
            int s0 = __shfl(myS, j0); float w0 = __shfl(myW, j0);
            int s1 = __shfl(myS, j1); float w1 = __shfl(myW, j1);
            if (j0 < m) {
                uint2 p = Abf2[(size_t)s0 * 32 + sub];
                a0 += bflo(p.x) * w0; a1 += bfhi(p.x) * w0;
                a2 += bflo(p.y) * w0; a3 += bfhi(p.y) * w0;
            }
            if (j1 < m) {
                uint2 p = Abf2[(size_t)s1 * 32 + sub];
                a0 += bflo(p.x) * w1; a1 += bfhi(p.x) * w1;
                a2 += bflo(p.y) * w1; a3 += bfhi(p.y) * w1;
            }
        }
    }
    a0 += __shfl_xor(a0, 32);
    a1 += __shfl_xor(a1, 32);
    a2 += __shfl_xor(a2, 32);
    a3 += __shfl_xor(a3, 32);
    if (g == 0) {
        float di = dinv[node];
        uint2 ps = Abf2[(size_t)node * 32 + sub];
        float4 bv = bias4[sub];
        float4 r;
        r.x = a0 * di + bflo(ps.x) * di * di + bv.x;
        r.y = a1 * di + bfhi(ps.x) * di * di + bv.y;
        r.z = a2 * di + bflo(ps.y) * di * di + bv.z;
        r.w = a3 * di + bfhi(ps.y) * di * di + bv.w;
        B4[(size_t)node * 32 + sub] = r;
    }
}

// layer-2: 12-feature aggregation over bf16 stride-16 rows. 8 lanes/node, 6 active, unroll 2.
__global__ void k_agg_out(const unsigned int* __restrict__ A16bf, const uint2* __restrict__ epair,
                          const int* __restrict__ R, const float* __restrict__ dinv,
                          const float* __restrict__ b2, float* __restrict__ out, int n, int e) {
    int t = blockIdx.x * blockDim.x + threadIdx.x;
    int node = t >> 3, u = t & 7;
    if (node >= n || u >= 6) return;
    int start = R[node];
    int end = (node + 1 < n) ? R[node + 1] : e;
    float ax = 0.f, ay = 0.f;
    int j = start;
    for (; j + 1 < end; j += 2) {
        uint2 p0 = epair[j], p1 = epair[j + 1];
        float w0 = dinv[p0.x] * __uint_as_float(p0.y);
        float w1 = dinv[p1.x] * __uint_as_float(p1.y);
        unsigned int q0 = A16bf[(size_t)p0.x * 8 + u];
        unsigned int q1 = A16bf[(size_t)p1.x * 8 + u];
        ax += bflo(q0) * w0 + bflo(q1) * w1;
        ay += bfhi(q0) * w0 + bfhi(q1) * w1;
    }
    if (j < end) {
        uint2 p0 = epair[j];
        float w0 = dinv[p0.x] * __uint_as_float(p0.y);
        unsigned int q0 = A16bf[(size_t)p0.x * 8 + u];
        ax += bflo(q0) * w0;
        ay += bfhi(q0) * w0;
    }
    float di = dinv[node];
    unsigned int ps = A16bf[(size_t)node * 8 + u];
    ax = ax * di + bflo(ps) * di * di + b2[2 * u];
    ay = ay * di + bfhi(ps) * di * di + b2[2 * u + 1];
    ((float2*)(out + (size_t)node * 12))[u] = make_float2(ax, ay);
}

// ================= GEMMs =================
__global__ void k_gemm_in(const float* __restrict__ x, const float* __restrict__ W,
                          const float* __restrict__ b, float* __restrict__ out, int n) {
    __shared__ float Ws[16 * 128];
    __shared__ float xs[8 * 16];
    int f = threadIdx.x;
    #pragma unroll
    for (int k = 0; k < 16; ++k) Ws[k * 128 + f] = W[k * 128 + f];
    int node0 = blockIdx.x * 8;
    int nrows = n - node0; if (nrows > 8) nrows = 8;
    if (f < nrows * 16) xs[f] = x[(size_t)node0 * 16 + f];
    __syncthreads();
    float bf = b[f];
    for (int nl = 0; nl < nrows; ++nl) {
        float acc = bf;
        #pragma unroll
        for (int k = 0; k < 16; ++k) acc += xs[nl * 16 + k] * Ws[k * 128 + f];
        out[(size_t)(node0 + nl) * 128 + f] = acc;
    }
}

// BN0+ReLU fused on load; (N,128)@W1(128,128) -> Abf bf16 packed (64 uints/row)
__global__ void k_gemm_hid_bn(const float* __restrict__ Bin, const float* __restrict__ sums,
                              const float* __restrict__ sumsq, const float* __restrict__ g,
                              const float* __restrict__ be, const float* __restrict__ W,
                              unsigned int* __restrict__ Abf, int n, float invn) {
    __shared__ float hs[16 * 128];
    __shared__ float sc[128], sh[128];
    int tid = threadIdx.x;
    if (tid < 128) {
        float m = sums[tid] * invn;
        float v = sumsq[tid] * invn - m * m;
        float scale = rsqrtf(v + EPS_BN) * g[tid];
        sc[tid] = scale;
        sh[tid] = be[tid] - m * scale;
    }
    __syncthreads();
    int f = tid & 127;
    int half = tid >> 7;
    int node0 = blockIdx.x * 16;
    int nrows = n - node0; if (nrows > 16) nrows = 16;
    const float4* B4 = (const float4*)(Bin + (size_t)node0 * 128);
    float4* hs4 = (float4*)hs;
    for (int i = tid; i < nrows * 32; i += 256) {
        float4 v = B4[i];
        int fb = (i & 31) * 4;
        v.x = fmaxf(v.x * sc[fb + 0] + sh[fb + 0], 0.f);
        v.y = fmaxf(v.y * sc[fb + 1] + sh[fb + 1], 0.f);
        v.z = fmaxf(v.z * sc[fb + 2] + sh[fb + 2], 0.f);
        v.w = fmaxf(v.w * sc[fb + 3] + sh[fb + 3], 0.f);
        hs4[i] = v;
    }
    __syncthreads();
    float acc[8] = {0.f, 0.f, 0.f, 0.f, 0.f, 0.f, 0.f, 0.f};
    for (int k4 = 0; k4 < 32; ++k4) {
        float w0 = W[(k4 * 4 + 0) * 128 + f];
        float w1 = W[(k4 * 4 + 1) * 128 + f];
        float w2 = W[(k4 * 4 + 2) * 128 + f];
        float w3 = W[(k4 * 4 + 3) * 128 + f];
        #pragma unroll
        for (int i = 0; i < 8; ++i) {
            float4 hv = hs4[(half + 2 * i) * 32 + k4];
            acc[i] += hv.x * w0 + hv.y * w1 + hv.z * w2 + hv.w * w3;
        }
    }
    __syncthreads();
    #pragma unroll
    for (int i = 0; i < 8; ++i) {
        int nl = half + 2 * i;
        if (nl < nrows) hs[nl * 128 + f] = acc[i];
    }
    __syncthreads();
    unsigned int* A0 = Abf + (size_t)node0 * 64;
    for (int i = tid; i < nrows * 64; i += 256) {
        int nl = i >> 6, fp = i & 63;
        A0[i] = packbf(hs[nl * 128 + 2 * fp], hs[nl * 128 + 2 * fp + 1]);
    }
}

// BN1+ReLU fused on load; (N,128)@W2(128,12) -> A16bf bf16 stride-16
__global__ void k_gemm_out_bn(const float* __restrict__ Bin, const float* __restrict__ sums,
                              const float* __restrict__ sumsq, const float* __restrict__ g,
                              const float* __restrict__ be, const float* __restrict__ W,
                              unsigned int* __restrict__ A16bf, int n, float invn) {
    __shared__ float hs[16 * 129];
    __shared__ float Ws[128 * 12];
    __shared__ float sc[128], sh[128];
    __shared__ float outv[16 * 12];
    int tid = threadIdx.x;   // 192
    if (tid < 128) {
        float m = sums[tid] * invn;
        float v = sumsq[tid] * invn - m * m;
        float scale = rsqrtf(v + EPS_BN) * g[tid];
        sc[tid] = scale;
        sh[tid] = be[tid] - m * scale;
    }
    for (int i = tid; i < 128 * 12; i += 192) Ws[i] = W[i];
    int node0 = blockIdx.x * 16;
    int nrows = n - node0; if (nrows > 16) nrows = 16;
    __syncthreads();
    for (int i = tid; i < nrows * 128; i += 192) {
        int f = i & 127;
        float v = Bin[(size_t)node0 * 128 + i];
        hs[(i >> 7) * 129 + f] = fmaxf(v * sc[f] + sh[f], 0.f);
    }
    __syncthreads();
    int nl = tid / 12, f = tid - nl * 12;
    if (nl < 16 && nl < nrows) {
        float acc = 0.f;
        for (int k = 0; k < 128; ++k) acc += hs[nl * 129 + k] * Ws[k * 12 + f];
        outv[nl * 12 + f] = acc;
    }
    __syncthreads();
    for (int i = tid; i < nrows * 8; i += 192) {
        int nn = i >> 3, u = i & 7;
        float lo = (2 * u < 12)     ? outv[nn * 12 + 2 * u]     : 0.f;
        float hi = (2 * u + 1 < 12) ? outv[nn * 12 + 2 * u + 1] : 0.f;
        A16bf[(size_t)(node0 + nn) * 8 + u] = packbf(lo, hi);
    }
}

// ================= batch norm stats =================
__global__ void k_bn_stats(const float* __restrict__ h, float* __restrict__ sums,
                           float* __restrict__ sumsq, int n) {
    int f = threadIdx.x;             // 128
    int i0 = blockIdx.x * 256;
    int i1 = i0 + 256; if (i1 > n) i1 = n;
    float s = 0.f, ss = 0.f;
    for (int i = i0; i < i1; ++i) {
        float v = h[(size_t)i * 128 + f];
        s += v; ss += v * v;
    }
    atomicAdd(&sums[f], s);
    atomicAdd(&sumsq[f], ss);
}

// ================= launch =================
extern "C" void kernel_launch(void* const* d_in, const int* in_sizes, int n_in,
                              void* d_out, int out_size, void* d_ws, size_t ws_size,
                              hipStream_t stream) {
    const float* x   = (const float*)d_in[0];
    const int*   ei  = (const int*)d_in[1];
    const float* ew  = (const float*)d_in[2];
    const float* W0  = (const float*)d_in[3];
    const float* b0  = (const float*)d_in[4];
    const float* W1  = (const float*)d_in[5];
    const float* b1  = (const float*)d_in[6];
    const float* W2  = (const float*)d_in[7];
    const float* b2  = (const float*)d_in[8];
    const float* g0  = (const float*)d_in[9];
    const float* be0 = (const float*)d_in[10];
    const float* g1  = (const float*)d_in[11];
    const float* be1 = (const float*)d_in[12];
    float* out = (float*)d_out;

    const int n = in_sizes[0] / 16;   // 100000
    const int e = in_sizes[2];        // 1600000
    const int* src = ei;
    const int* dst = ei + e;

    // workspace layout (4B elems); rank[] aliases B (dead after k_place)
    float*        wsf   = (float*)d_ws;
    float*        dinv  = wsf;                                    // n
    int*          R     = (int*)(wsf + n);                        // n+4
    int*          bsum  = R + (n + 4);                            // 128
    uint2*        epair = (uint2*)(bsum + 128);                   // e pairs
    float*        B     = (float*)(bsum + 128 + 2 * (size_t)e);   // n*128 fp32
    int*          rank  = (int*)B;                                // e ints, aliases B
    unsigned int* Abf   = (unsigned int*)(B + (size_t)n * 128);   // n*64
    unsigned int* xbf   = Abf + (size_t)n * 64;                   // n*8
    float*        xagg  = (float*)(xbf + (size_t)n * 8);          // n*16
    unsigned int* A16bf = (unsigned int*)(xagg + (size_t)n * 16); // n*8
    float*        sums  = (float*)(A16bf + (size_t)n * 8);        // 128
    float*        sumsq = sums + 128;                             // 128

    const float invn = 1.0f / (float)n;
    const int nb_scan = (n + 1023) / 1024;

    // ---- CSR build (single atomic pass; norm folded into aggregation) ----
    hipMemsetAsync(R, 0, (size_t)(n + 4) * sizeof(int), stream);
    k_xcast<<<(n * 8 + 255) / 256, 256, 0, stream>>>(x, xbf, n * 8);
    k_hist_rank<<<(e + 255) / 256, 256, 0, stream>>>(dst, R, rank, e);
    k_scan_local<<<nb_scan, 256, 0, stream>>>(R, bsum, n);
    k_scan_bsum<<<1, 128, 0, stream>>>(bsum, nb_scan);
    k_scan_add<<<nb_scan, 256, 0, stream>>>(R, bsum, n);
    k_place<<<(e + 255) / 256, 256, 0, stream>>>(src, dst, ew, rank, R, epair, e);
    k_deg_dinv<<<(n + 255) / 256, 256, 0, stream>>>(epair, R, dinv, n, e);

    // ---- layer 0 ----
    k_agg_x<<<(n * 8 + 255) / 256, 256, 0, stream>>>(xbf, epair, R, dinv, xagg, n, e);
    k_gemm_in<<<(n + 7) / 8, 128, 0, stream>>>(xagg, W0, b0, B, n);
    hipMemsetAsync(sums, 0, 256 * sizeof(float), stream);
    k_bn_stats<<<(n + 255) / 256, 128, 0, stream>>>(B, sums, sumsq, n);

    // ---- layer 1 ----
    k_gemm_hid_bn<<<(n + 15) / 16, 256, 0, stream>>>(B, sums, sumsq, g0, be0, W1, Abf, n, invn);
    k_aggregate128<<<(n * 64 + 255) / 256, 256, 0, stream>>>((const uint2*)Abf, epair, R, dinv,
                                                             (const float4*)b1, (float4*)B, n, e);
    hipMemsetAsync(sums, 0, 256 * sizeof(float), stream);
    k_bn_stats<<<(n + 255) / 256, 128, 0, stream>>>(B, sums, sumsq, n);

    // ---- layer 2 ----
    k_gemm_out_bn<<<(n + 15) / 16, 192, 0, stream>>>(B, sums, sumsq, g1, be1, W2, A16bf, n, invn);
    k_agg_out<<<(n * 8 + 255) / 256, 256, 0, stream>>>(A16bf, epair, R, dinv, b2, out, n, e);
}

// Round 6
// 575.916 us; speedup vs baseline: 10.3129x; 1.0870x over previous
//
#include <hip/hip_runtime.h>

#define EPS_BN 1e-5f
#define HSTRIDE 68   // 64 dwords + 4 pad: breaks 16-way LDS bank aliasing on b128 reads

typedef __attribute__((ext_vector_type(4))) float f32x4;
typedef __attribute__((ext_vector_type(8))) short s16x8;

__device__ inline unsigned short f2bf(float f) {
    unsigned int u = __float_as_uint(f);
    unsigned int r = (u + 0x7fffu + ((u >> 16) & 1u)) >> 16;
    return (unsigned short)r;
}
__device__ inline unsigned int packbf(float lo, float hi) {
    return (unsigned int)f2bf(lo) | ((unsigned int)f2bf(hi) << 16);
}
__device__ inline float bflo(unsigned int p) { return __uint_as_float(p << 16); }
__device__ inline float bfhi(unsigned int p) { return __uint_as_float(p & 0xffff0000u); }

// ================= CSR build: 1 atomic per edge =================
__global__ void k_hist_rank(const int* __restrict__ dst, int* __restrict__ R,
                            int* __restrict__ rank, int e) {
    int i = blockIdx.x * blockDim.x + threadIdx.x;
    if (i < e) rank[i] = atomicAdd(&R[dst[i]], 1);
}

// ================= exclusive scan (3-kernel) =================
__global__ void k_scan_local(int* __restrict__ R, int* __restrict__ bsum, int n) {
    __shared__ int s[256];
    int t = threadIdx.x;
    int base = blockIdx.x * 1024 + t * 4;
    int v0 = (base + 0 < n) ? R[base + 0] : 0;
    int v1 = (base + 1 < n) ? R[base + 1] : 0;
    int v2 = (base + 2 < n) ? R[base + 2] : 0;
    int v3 = (base + 3 < n) ? R[base + 3] : 0;
    int sum = v0 + v1 + v2 + v3;
    s[t] = sum;
    __syncthreads();
    for (int off = 1; off < 256; off <<= 1) {
        int u = (t >= off) ? s[t - off] : 0;
        __syncthreads();
        s[t] += u;
        __syncthreads();
    }
    if (t == 255) bsum[blockIdx.x] = s[255];
    int run = s[t] - sum;
    if (base + 0 < n) R[base + 0] = run;  run += v0;
    if (base + 1 < n) R[base + 1] = run;  run += v1;
    if (base + 2 < n) R[base + 2] = run;  run += v2;
    if (base + 3 < n) R[base + 3] = run;
}

__global__ void k_scan_bsum(int* __restrict__ bsum, int nb) {
    __shared__ int s[128];
    int t = threadIdx.x;
    int v = (t < nb) ? bsum[t] : 0;
    s[t] = v;
    __syncthreads();
    for (int off = 1; off < 128; off <<= 1) {
        int u = (t >= off) ? s[t - off] : 0;
        __syncthreads();
        s[t] += u;
        __syncthreads();
    }
    if (t < nb) bsum[t] = s[t] - v;
}

__global__ void k_scan_add(int* __restrict__ R, const int* __restrict__ bsum, int n) {
    int add = bsum[blockIdx.x];
    int base = blockIdx.x * 1024 + threadIdx.x * 4;
    for (int k = 0; k < 4; ++k)
        if (base + k < n) R[base + k] += add;
}

// atomic-free placement
__global__ void k_place(const int* __restrict__ src, const int* __restrict__ dst,
                        const float* __restrict__ w, const int* __restrict__ rank,
                        const int* __restrict__ R, uint2* __restrict__ epair, int e) {
    int i = blockIdx.x * blockDim.x + threadIdx.x;
    if (i < e) {
        int d = dst[i];
        int pos = R[d] + rank[i];
        epair[pos] = make_uint2((unsigned int)src[i], __float_as_uint(w[i]));
    }
}

// contiguous per-row sum of w -> dinv
__global__ void k_deg_dinv(const uint2* __restrict__ epair, const int* __restrict__ R,
                           float* __restrict__ dinv, int n, int e) {
    int node = blockIdx.x * blockDim.x + threadIdx.x;
    if (node >= n) return;
    int start = R[node];
    int end = (node + 1 < n) ? R[node + 1] : e;
    float sum = 1.0f;
    for (int j = start; j < end; ++j) sum += __uint_as_float(epair[j].y);
    dinv[node] = rsqrtf(sum);
}

// ================= x -> bf16 =================
__global__ void k_xcast(const float* __restrict__ x, unsigned int* __restrict__ xbf, int n8) {
    int t = blockIdx.x * blockDim.x + threadIdx.x;
    if (t < n8) {
        float2 v = ((const float2*)x)[t];
        xbf[t] = packbf(v.x, v.y);
    }
}

// ================= W1 -> MFMA B-fragment layout (bf16) =================
// W1p dword index: ((ct*4+kc)*64 + lane)*4 + dj ; lane holds B[k=kc*32+quad*8+2dj(+1)][n=ct*16+mrow]
__global__ void k_prepW1(const float* __restrict__ W1, unsigned int* __restrict__ W1p) {
    int t = blockIdx.x * blockDim.x + threadIdx.x;
    if (t >= 8192) return;
    int dj = t & 3;
    int lane = (t >> 2) & 63;
    int kc = (t >> 8) & 3;
    int ct = t >> 10;
    int quad = lane >> 4, mrow = lane & 15;
    int k0 = kc * 32 + quad * 8 + dj * 2;
    int col = ct * 16 + mrow;
    W1p[t] = packbf(W1[k0 * 128 + col], W1[(k0 + 1) * 128 + col]);
}

// ================= aggregations (CSR, no atomics) =================
__global__ void k_agg_x(const unsigned int* __restrict__ xbf, const uint2* __restrict__ epair,
                        const int* __restrict__ R, const float* __restrict__ dinv,
                        float* __restrict__ xagg, int n, int e) {
    int t = blockIdx.x * blockDim.x + threadIdx.x;
    int node = t >> 3, u = t & 7;
    if (node >= n) return;
    int start = R[node];
    int end = (node + 1 < n) ? R[node + 1] : e;
    float ax = 0.f, ay = 0.f;
    int j = start;
    for (; j + 1 < end; j += 2) {
        uint2 p0 = epair[j], p1 = epair[j + 1];
        float w0 = dinv[p0.x] * __uint_as_float(p0.y);
        float w1 = dinv[p1.x] * __uint_as_float(p1.y);
        unsigned int q0 = xbf[(size_t)p0.x * 8 + u];
        unsigned int q1 = xbf[(size_t)p1.x * 8 + u];
        ax += bflo(q0) * w0 + bflo(q1) * w1;
        ay += bfhi(q0) * w0 + bfhi(q1) * w1;
    }
    if (j < end) {
        uint2 p0 = epair[j];
        float w0 = dinv[p0.x] * __uint_as_float(p0.y);
        unsigned int q0 = xbf[(size_t)p0.x * 8 + u];
        ax += bflo(q0) * w0;
        ay += bfhi(q0) * w0;
    }
    float di = dinv[node];
    unsigned int ps = xbf[(size_t)node * 8 + u];
    ax = ax * di + bflo(ps) * di * di;
    ay = ay * di + bfhi(ps) * di * di;
    ((float2*)xagg)[(size_t)node * 8 + u] = make_float2(ax, ay);
}

// layer-1: 128-feature bf16 aggregation. wave/node, two 32-lane groups, uint2/lane.
__global__ void k_aggregate128(const uint2* __restrict__ Abf2, const uint2* __restrict__ epair,
                               const int* __restrict__ R, const float* __restrict__ dinv,
                               const float4* __restrict__ bias4, float4* __restrict__ B4,
                               int n, int e) {
    int gid = blockIdx.x * blockDim.x + threadIdx.x;
    int node = gid >> 6;
    if (node >= n) return;
    int lane = threadIdx.x & 63;
    int g = lane >> 5, sub = lane & 31;
    int start = R[node];
    int end = (node + 1 < n) ? R[node + 1] : e;
    float a0 = 0.f, a1 = 0.f, a2 = 0.f, a3 = 0.f;
    for (int base = start; base < end; base += 64) {
        int m = end - base; if (m > 64) m = 64;
        int myS = 0; float myW = 0.f;
        if (lane < m) {
            uint2 pr = epair[base + lane];
            myS = (int)pr.x;
            myW = dinv[pr.x] * __uint_as_float(pr.y);
        }
        for (int t = 0; t < m; t += 4) {
            int j0 = t + g;
            int j1 = t + 2 + g;
            int s0 = __shfl(myS, j0); float w0 = __shfl(myW, j0);
            int s1 = __shfl(myS, j1); float w1 = __shfl(myW, j1);
            if (j0 < m) {
                uint2 p = Abf2[(size_t)s0 * 32 + sub];
                a0 += bflo(p.x) * w0; a1 += bfhi(p.x) * w0;
                a2 += bflo(p.y) * w0; a3 += bfhi(p.y) * w0;
            }
            if (j1 < m) {
                uint2 p = Abf2[(size_t)s1 * 32 + sub];
                a0 += bflo(p.x) * w1; a1 += bfhi(p.x) * w1;
                a2 += bflo(p.y) * w1; a3 += bfhi(p.y) * w1;
            }
        }
    }
    a0 += __shfl_xor(a0, 32);
    a1 += __shfl_xor(a1, 32);
    a2 += __shfl_xor(a2, 32);
    a3 += __shfl_xor(a3, 32);
    if (g == 0) {
        float di = dinv[node];
        uint2 ps = Abf2[(size_t)node * 32 + sub];
        float4 bv = bias4[sub];
        float4 r;
        r.x = a0 * di + bflo(ps.x) * di * di + bv.x;
        r.y = a1 * di + bfhi(ps.x) * di * di + bv.y;
        r.z = a2 * di + bflo(ps.y) * di * di + bv.z;
        r.w = a3 * di + bfhi(ps.y) * di * di + bv.w;
        B4[(size_t)node * 32 + sub] = r;
    }
}

// layer-2: 12-feature aggregation over bf16 stride-16 rows.
__global__ void k_agg_out(const unsigned int* __restrict__ A16bf, const uint2* __restrict__ epair,
                          const int* __restrict__ R, const float* __restrict__ dinv,
                          const float* __restrict__ b2, float* __restrict__ out, int n, int e) {
    int t = blockIdx.x * blockDim.x + threadIdx.x;
    int node = t >> 3, u = t & 7;
    if (node >= n || u >= 6) return;
    int start = R[node];
    int end = (node + 1 < n) ? R[node + 1] : e;
    float ax = 0.f, ay = 0.f;
    int j = start;
    for (; j + 1 < end; j += 2) {
        uint2 p0 = epair[j], p1 = epair[j + 1];
        float w0 = dinv[p0.x] * __uint_as_float(p0.y);
        float w1 = dinv[p1.x] * __uint_as_float(p1.y);
        unsigned int q0 = A16bf[(size_t)p0.x * 8 + u];
        unsigned int q1 = A16bf[(size_t)p1.x * 8 + u];
        ax += bflo(q0) * w0 + bflo(q1) * w1;
        ay += bfhi(q0) * w0 + bfhi(q1) * w1;
    }
    if (j < end) {
        uint2 p0 = epair[j];
        float w0 = dinv[p0.x] * __uint_as_float(p0.y);
        unsigned int q0 = A16bf[(size_t)p0.x * 8 + u];
        ax += bflo(q0) * w0;
        ay += bfhi(q0) * w0;
    }
    float di = dinv[node];
    unsigned int ps = A16bf[(size_t)node * 8 + u];
    ax = ax * di + bflo(ps) * di * di + b2[2 * u];
    ay = ay * di + bfhi(ps) * di * di + b2[2 * u + 1];
    ((float2*)(out + (size_t)node * 12))[u] = make_float2(ax, ay);
}

// ================= GEMMs =================
__global__ void k_gemm_in(const float* __restrict__ x, const float* __restrict__ W,
                          const float* __restrict__ b, float* __restrict__ out, int n) {
    __shared__ float Ws[16 * 128];
    __shared__ float xs[8 * 16];
    int f = threadIdx.x;
    #pragma unroll
    for (int k = 0; k < 16; ++k) Ws[k * 128 + f] = W[k * 128 + f];
    int node0 = blockIdx.x * 8;
    int nrows = n - node0; if (nrows > 8) nrows = 8;
    if (f < nrows * 16) xs[f] = x[(size_t)node0 * 16 + f];
    __syncthreads();
    float bf = b[f];
    for (int nl = 0; nl < nrows; ++nl) {
        float acc = bf;
        #pragma unroll
        for (int k = 0; k < 16; ++k) acc += xs[nl * 16 + k] * Ws[k * 128 + f];
        out[(size_t)(node0 + nl) * 128 + f] = acc;
    }
}

// BN0+ReLU fused on load; MFMA bf16 (N,128)@(128,128) -> Abf bf16 packed.
// Block = 64 nodes, 4 waves x 16 nodes. 32 MFMAs (16x16x32) per wave.
__global__ __launch_bounds__(256) void k_gemm_hid_mfma(
        const float* __restrict__ Bin, const float* __restrict__ sums,
        const float* __restrict__ sumsq, const float* __restrict__ g,
        const float* __restrict__ be, const unsigned int* __restrict__ W1p,
        unsigned int* __restrict__ Abf, int n, float invn) {
    __shared__ unsigned int hsbf[64 * HSTRIDE];
    __shared__ float sc[128], sh[128];
    int tid = threadIdx.x;
    if (tid < 128) {
        float m = sums[tid] * invn;
        float v = sumsq[tid] * invn - m * m;
        float scale = rsqrtf(v + EPS_BN) * g[tid];
        sc[tid] = scale;
        sh[tid] = be[tid] - m * scale;
    }
    __syncthreads();
    int node0 = blockIdx.x * 64;
    // stage BN+ReLU'd rows as packed bf16 into LDS
    for (int i = tid; i < 64 * 32; i += 256) {
        int row = i >> 5, grp = i & 31;
        int gn = node0 + row;
        uint2 pk;
        if (gn < n) {
            float4 v = ((const float4*)Bin)[(size_t)gn * 32 + grp];
            int fb = grp * 4;
            v.x = fmaxf(v.x * sc[fb + 0] + sh[fb + 0], 0.f);
            v.y = fmaxf(v.y * sc[fb + 1] + sh[fb + 1], 0.f);
            v.z = fmaxf(v.z * sc[fb + 2] + sh[fb + 2], 0.f);
            v.w = fmaxf(v.w * sc[fb + 3] + sh[fb + 3], 0.f);
            pk = make_uint2(packbf(v.x, v.y), packbf(v.z, v.w));
        } else {
            pk = make_uint2(0u, 0u);
        }
        *((uint2*)&hsbf[row * HSTRIDE + grp * 2]) = pk;
    }
    __syncthreads();
    int wave = tid >> 6, lane = tid & 63;
    int quad = lane >> 4, mrow = lane & 15;
    int lrow = wave * 16 + mrow;
    // A fragments: A[m=lane&15][k=quad*8+j]
    s16x8 afrag[4];
    #pragma unroll
    for (int kc = 0; kc < 4; ++kc)
        afrag[kc] = *((const s16x8*)&hsbf[lrow * HSTRIDE + kc * 16 + quad * 4]);
    int gnode_base = node0 + wave * 16;
    const s16x8* Wf = (const s16x8*)W1p;
    for (int ct = 0; ct < 8; ++ct) {
        f32x4 acc = {0.f, 0.f, 0.f, 0.f};
        #pragma unroll
        for (int kc = 0; kc < 4; ++kc) {
            s16x8 bfrag = Wf[(ct * 4 + kc) * 64 + lane];
            acc = __builtin_amdgcn_mfma_f32_16x16x32_bf16(afrag[kc], bfrag, acc, 0, 0, 0);
        }
        // D: col = ct*16 + mrow, row = quad*4 + r. Pack col pairs via shfl partner.
        #pragma unroll
        for (int r = 0; r < 4; ++r) {
            float lo = acc[r];
            float hi = __shfl_xor(lo, 1);
            int grow = gnode_base + quad * 4 + r;
            if ((mrow & 1) == 0 && grow < n)
                Abf[(size_t)grow * 64 + ct * 8 + (mrow >> 1)] = packbf(lo, hi);
        }
    }
}

// BN1+ReLU fused on load; (N,128)@W2(128,12) -> A16bf bf16 stride-16
__global__ void k_gemm_out_bn(const float* __restrict__ Bin, const float* __restrict__ sums,
                              const float* __restrict__ sumsq, const float* __restrict__ g,
                              const float* __restrict__ be, const float* __restrict__ W,
                              unsigned int* __restrict__ A16bf, int n, float invn) {
    __shared__ float hs[16 * 129];
    __shared__ float Ws[128 * 12];
    __shared__ float sc[128], sh[128];
    __shared__ float outv[16 * 12];
    int tid = threadIdx.x;   // 192
    if (tid < 128) {
        float m = sums[tid] * invn;
        float v = sumsq[tid] * invn - m * m;
        float scale = rsqrtf(v + EPS_BN) * g[tid];
        sc[tid] = scale;
        sh[tid] = be[tid] - m * scale;
    }
    for (int i = tid; i < 128 * 12; i += 192) Ws[i] = W[i];
    int node0 = blockIdx.x * 16;
    int nrows = n - node0; if (nrows > 16) nrows = 16;
    __syncthreads();
    for (int i = tid; i < nrows * 128; i += 192) {
        int f = i & 127;
        float v = Bin[(size_t)node0 * 128 + i];
        hs[(i >> 7) * 129 + f] = fmaxf(v * sc[f] + sh[f], 0.f);
    }
    __syncthreads();
    int nl = tid / 12, f = tid - nl * 12;
    if (nl < 16 && nl < nrows) {
        float acc = 0.f;
        for (int k = 0; k < 128; ++k) acc += hs[nl * 129 + k] * Ws[k * 12 + f];
        outv[nl * 12 + f] = acc;
    }
    __syncthreads();
    for (int i = tid; i < nrows * 8; i += 192) {
        int nn = i >> 3, u = i & 7;
        float lo = (2 * u < 12)     ? outv[nn * 12 + 2 * u]     : 0.f;
        float hi = (2 * u + 1 < 12) ? outv[nn * 12 + 2 * u + 1] : 0.f;
        A16bf[(size_t)(node0 + nn) * 8 + u] = packbf(lo, hi);
    }
}

// ================= batch norm stats =================
__global__ void k_bn_stats(const float* __restrict__ h, float* __restrict__ sums,
                           float* __restrict__ sumsq, int n) {
    int f = threadIdx.x;             // 128
    int i0 = blockIdx.x * 256;
    int i1 = i0 + 256; if (i1 > n) i1 = n;
    float s = 0.f, ss = 0.f;
    for (int i = i0; i < i1; ++i) {
        float v = h[(size_t)i * 128 + f];
        s += v; ss += v * v;
    }
    atomicAdd(&sums[f], s);
    atomicAdd(&sumsq[f], ss);
}

// ================= launch =================
extern "C" void kernel_launch(void* const* d_in, const int* in_sizes, int n_in,
                              void* d_out, int out_size, void* d_ws, size_t ws_size,
                              hipStream_t stream) {
    const float* x   = (const float*)d_in[0];
    const int*   ei  = (const int*)d_in[1];
    const float* ew  = (const float*)d_in[2];
    const float* W0  = (const float*)d_in[3];
    const float* b0  = (const float*)d_in[4];
    const float* W1  = (const float*)d_in[5];
    const float* b1  = (const float*)d_in[6];
    const float* W2  = (const float*)d_in[7];
    const float* b2  = (const float*)d_in[8];
    const float* g0  = (const float*)d_in[9];
    const float* be0 = (const float*)d_in[10];
    const float* g1  = (const float*)d_in[11];
    const float* be1 = (const float*)d_in[12];
    float* out = (float*)d_out;

    const int n = in_sizes[0] / 16;   // 100000
    const int e = in_sizes[2];        // 1600000
    const int* src = ei;
    const int* dst = ei + e;

    // workspace layout (4B elems); rank[] aliases B (dead after k_place)
    float*        wsf   = (float*)d_ws;
    float*        dinv  = wsf;                                    // n
    int*          R     = (int*)(wsf + n);                        // n+4
    int*          bsum  = R + (n + 4);                            // 128
    uint2*        epair = (uint2*)(bsum + 128);                   // e pairs
    float*        B     = (float*)(bsum + 128 + 2 * (size_t)e);   // n*128 fp32
    int*          rank  = (int*)B;                                // e ints, aliases B
    unsigned int* Abf   = (unsigned int*)(B + (size_t)n * 128);   // n*64
    unsigned int* xbf   = Abf + (size_t)n * 64;                   // n*8
    float*        xagg  = (float*)(xbf + (size_t)n * 8);          // n*16
    unsigned int* A16bf = (unsigned int*)(xagg + (size_t)n * 16); // n*8
    float*        sums  = (float*)(A16bf + (size_t)n * 8);        // 128
    float*        sumsq = sums + 128;                             // 128
    unsigned int* W1p   = (unsigned int*)(sumsq + 128);           // 8192

    const float invn = 1.0f / (float)n;
    const int nb_scan = (n + 1023) / 1024;

    // ---- CSR build (single atomic pass; norm folded into aggregation) ----
    hipMemsetAsync(R, 0, (size_t)(n + 4) * sizeof(int), stream);
    k_xcast<<<(n * 8 + 255) / 256, 256, 0, stream>>>(x, xbf, n * 8);
    k_prepW1<<<32, 256, 0, stream>>>(W1, W1p);
    k_hist_rank<<<(e + 255) / 256, 256, 0, stream>>>(dst, R, rank, e);
    k_scan_local<<<nb_scan, 256, 0, stream>>>(R, bsum, n);
    k_scan_bsum<<<1, 128, 0, stream>>>(bsum, nb_scan);
    k_scan_add<<<nb_scan, 256, 0, stream>>>(R, bsum, n);
    k_place<<<(e + 255) / 256, 256, 0, stream>>>(src, dst, ew, rank, R, epair, e);
    k_deg_dinv<<<(n + 255) / 256, 256, 0, stream>>>(epair, R, dinv, n, e);

    // ---- layer 0 ----
    k_agg_x<<<(n * 8 + 255) / 256, 256, 0, stream>>>(xbf, epair, R, dinv, xagg, n, e);
    k_gemm_in<<<(n + 7) / 8, 128, 0, stream>>>(xagg, W0, b0, B, n);
    hipMemsetAsync(sums, 0, 256 * sizeof(float), stream);
    k_bn_stats<<<(n + 255) / 256, 128, 0, stream>>>(B, sums, sumsq, n);

    // ---- layer 1 (MFMA GEMM with fused BN0+ReLU) ----
    k_gemm_hid_mfma<<<(n + 63) / 64, 256, 0, stream>>>(B, sums, sumsq, g0, be0, W1p, Abf, n, invn);
    k_aggregate128<<<(n * 64 + 255) / 256, 256, 0, stream>>>((const uint2*)Abf, epair, R, dinv,
                                                             (const float4*)b1, (float4*)B, n, e);
    hipMemsetAsync(sums, 0, 256 * sizeof(float), stream);
    k_bn_stats<<<(n + 255) / 256, 128, 0, stream>>>(B, sums, sumsq, n);

    // ---- layer 2 ----
    k_gemm_out_bn<<<(n + 15) / 16, 192, 0, stream>>>(B, sums, sumsq, g1, be1, W2, A16bf, n, invn);
    k_agg_out<<<(n * 8 + 255) / 256, 256, 0, stream>>>(A16bf, epair, R, dinv, b2, out, n, e);
}

// Round 7
// 566.039 us; speedup vs baseline: 10.4928x; 1.0174x over previous
//
#include <hip/hip_runtime.h>

#define EPS_BN 1e-5f
#define HSTRIDE 68   // 64 dwords + 4 pad (272B rows, 16B-aligned)

typedef __attribute__((ext_vector_type(4))) float f32x4;
typedef __attribute__((ext_vector_type(8))) short s16x8;

__device__ inline unsigned short f2bf(float f) {
    unsigned int u = __float_as_uint(f);
    unsigned int r = (u + 0x7fffu + ((u >> 16) & 1u)) >> 16;
    return (unsigned short)r;
}
__device__ inline unsigned int packbf(float lo, float hi) {
    return (unsigned int)f2bf(lo) | ((unsigned int)f2bf(hi) << 16);
}
__device__ inline float bflo(unsigned int p) { return __uint_as_float(p << 16); }
__device__ inline float bfhi(unsigned int p) { return __uint_as_float(p & 0xffff0000u); }

// ================= CSR build: 1 atomic per edge =================
__global__ void k_hist_rank(const int* __restrict__ dst, int* __restrict__ R,
                            int* __restrict__ rank, int e) {
    int i = blockIdx.x * blockDim.x + threadIdx.x;
    if (i < e) rank[i] = atomicAdd(&R[dst[i]], 1);
}

// ================= exclusive scan (3-kernel) =================
__global__ void k_scan_local(int* __restrict__ R, int* __restrict__ bsum, int n) {
    __shared__ int s[256];
    int t = threadIdx.x;
    int base = blockIdx.x * 1024 + t * 4;
    int v0 = (base + 0 < n) ? R[base + 0] : 0;
    int v1 = (base + 1 < n) ? R[base + 1] : 0;
    int v2 = (base + 2 < n) ? R[base + 2] : 0;
    int v3 = (base + 3 < n) ? R[base + 3] : 0;
    int sum = v0 + v1 + v2 + v3;
    s[t] = sum;
    __syncthreads();
    for (int off = 1; off < 256; off <<= 1) {
        int u = (t >= off) ? s[t - off] : 0;
        __syncthreads();
        s[t] += u;
        __syncthreads();
    }
    if (t == 255) bsum[blockIdx.x] = s[255];
    int run = s[t] - sum;
    if (base + 0 < n) R[base + 0] = run;  run += v0;
    if (base + 1 < n) R[base + 1] = run;  run += v1;
    if (base + 2 < n) R[base + 2] = run;  run += v2;
    if (base + 3 < n) R[base + 3] = run;
}

__global__ void k_scan_bsum(int* __restrict__ bsum, int nb) {
    __shared__ int s[128];
    int t = threadIdx.x;
    int v = (t < nb) ? bsum[t] : 0;
    s[t] = v;
    __syncthreads();
    for (int off = 1; off < 128; off <<= 1) {
        int u = (t >= off) ? s[t - off] : 0;
        __syncthreads();
        s[t] += u;
        __syncthreads();
    }
    if (t < nb) bsum[t] = s[t] - v;
}

__global__ void k_scan_add(int* __restrict__ R, const int* __restrict__ bsum, int n) {
    int add = bsum[blockIdx.x];
    int base = blockIdx.x * 1024 + threadIdx.x * 4;
    for (int k = 0; k < 4; ++k)
        if (base + k < n) R[base + k] += add;
}

// atomic-free placement
__global__ void k_place(const int* __restrict__ src, const int* __restrict__ dst,
                        const float* __restrict__ w, const int* __restrict__ rank,
                        const int* __restrict__ R, uint2* __restrict__ epair, int e) {
    int i = blockIdx.x * blockDim.x + threadIdx.x;
    if (i < e) {
        int d = dst[i];
        int pos = R[d] + rank[i];
        epair[pos] = make_uint2((unsigned int)src[i], __float_as_uint(w[i]));
    }
}

// contiguous per-row sum of w -> dinv
__global__ void k_deg_dinv(const uint2* __restrict__ epair, const int* __restrict__ R,
                           float* __restrict__ dinv, int n, int e) {
    int node = blockIdx.x * blockDim.x + threadIdx.x;
    if (node >= n) return;
    int start = R[node];
    int end = (node + 1 < n) ? R[node + 1] : e;
    float sum = 1.0f;
    for (int j = start; j < end; ++j) sum += __uint_as_float(epair[j].y);
    dinv[node] = rsqrtf(sum);
}

// ================= x -> bf16 =================
__global__ void k_xcast(const float* __restrict__ x, unsigned int* __restrict__ xbf, int n8) {
    int t = blockIdx.x * blockDim.x + threadIdx.x;
    if (t < n8) {
        float2 v = ((const float2*)x)[t];
        xbf[t] = packbf(v.x, v.y);
    }
}

// ================= W1 -> MFMA B-fragment layout (bf16) =================
__global__ void k_prepW1(const float* __restrict__ W1, unsigned int* __restrict__ W1p) {
    int t = blockIdx.x * blockDim.x + threadIdx.x;
    if (t >= 8192) return;
    int dj = t & 3;
    int lane = (t >> 2) & 63;
    int kc = (t >> 8) & 3;
    int ct = t >> 10;
    int quad = lane >> 4, mrow = lane & 15;
    int k0 = kc * 32 + quad * 8 + dj * 2;
    int col = ct * 16 + mrow;
    W1p[t] = packbf(W1[k0 * 128 + col], W1[(k0 + 1) * 128 + col]);
}

// ================= aggregations (CSR, no atomics) =================
// layer-0: aggregate bf16 x, 8 lanes/node, unroll 4
__global__ void k_agg_x(const unsigned int* __restrict__ xbf, const uint2* __restrict__ epair,
                        const int* __restrict__ R, const float* __restrict__ dinv,
                        float* __restrict__ xagg, int n, int e) {
    int t = blockIdx.x * blockDim.x + threadIdx.x;
    int node = t >> 3, u = t & 7;
    if (node >= n) return;
    int start = R[node];
    int end = (node + 1 < n) ? R[node + 1] : e;
    float ax = 0.f, ay = 0.f;
    int j = start;
    for (; j + 3 < end; j += 4) {
        uint2 p0 = epair[j], p1 = epair[j + 1], p2 = epair[j + 2], p3 = epair[j + 3];
        float w0 = dinv[p0.x] * __uint_as_float(p0.y);
        float w1 = dinv[p1.x] * __uint_as_float(p1.y);
        float w2 = dinv[p2.x] * __uint_as_float(p2.y);
        float w3 = dinv[p3.x] * __uint_as_float(p3.y);
        unsigned int q0 = xbf[(size_t)p0.x * 8 + u];
        unsigned int q1 = xbf[(size_t)p1.x * 8 + u];
        unsigned int q2 = xbf[(size_t)p2.x * 8 + u];
        unsigned int q3 = xbf[(size_t)p3.x * 8 + u];
        ax += bflo(q0) * w0 + bflo(q1) * w1 + bflo(q2) * w2 + bflo(q3) * w3;
        ay += bfhi(q0) * w0 + bfhi(q1) * w1 + bfhi(q2) * w2 + bfhi(q3) * w3;
    }
    for (; j < end; ++j) {
        uint2 p0 = epair[j];
        float w0 = dinv[p0.x] * __uint_as_float(p0.y);
        unsigned int q0 = xbf[(size_t)p0.x * 8 + u];
        ax += bflo(q0) * w0;
        ay += bfhi(q0) * w0;
    }
    float di = dinv[node];
    unsigned int ps = xbf[(size_t)node * 8 + u];
    ax = ax * di + bflo(ps) * di * di;
    ay = ay * di + bfhi(ps) * di * di;
    ((float2*)xagg)[(size_t)node * 8 + u] = make_float2(ax, ay);
}

// layer-1: 128-feature bf16 aggregation. wave/node, FOUR 16-lane groups,
// uint4 (8 feats) per lane, 8 edges per trip, reduce via shfl_xor(16,32).
// Output packed bf16 (fused self-loop + bias).
__global__ void k_aggregate128(const uint4* __restrict__ Abf4, const uint2* __restrict__ epair,
                               const int* __restrict__ R, const float* __restrict__ dinv,
                               const float4* __restrict__ bias4, uint4* __restrict__ Bbf4,
                               int n, int e) {
    int gid = blockIdx.x * blockDim.x + threadIdx.x;
    int node = gid >> 6;
    if (node >= n) return;
    int lane = threadIdx.x & 63;
    int grp = lane >> 4, sub = lane & 15;
    int start = R[node];
    int end = (node + 1 < n) ? R[node + 1] : e;
    float a[8] = {0.f, 0.f, 0.f, 0.f, 0.f, 0.f, 0.f, 0.f};
    for (int base = start; base < end; base += 64) {
        int m = end - base; if (m > 64) m = 64;
        int myS = 0; float myW = 0.f;
        if (lane < m) {
            uint2 pr = epair[base + lane];
            myS = (int)pr.x;
            myW = dinv[pr.x] * __uint_as_float(pr.y);
        }
        for (int t = 0; t < m; t += 8) {
            int j0 = t + grp;
            int j1 = t + 4 + grp;
            int s0 = __shfl(myS, j0); float w0 = __shfl(myW, j0);
            int s1 = __shfl(myS, j1); float w1 = __shfl(myW, j1);
            if (j0 < m) {
                uint4 p = Abf4[(size_t)s0 * 16 + sub];
                a[0] += bflo(p.x) * w0; a[1] += bfhi(p.x) * w0;
                a[2] += bflo(p.y) * w0; a[3] += bfhi(p.y) * w0;
                a[4] += bflo(p.z) * w0; a[5] += bfhi(p.z) * w0;
                a[6] += bflo(p.w) * w0; a[7] += bfhi(p.w) * w0;
            }
            if (j1 < m) {
                uint4 p = Abf4[(size_t)s1 * 16 + sub];
                a[0] += bflo(p.x) * w1; a[1] += bfhi(p.x) * w1;
                a[2] += bflo(p.y) * w1; a[3] += bfhi(p.y) * w1;
                a[4] += bflo(p.z) * w1; a[5] += bfhi(p.z) * w1;
                a[6] += bflo(p.w) * w1; a[7] += bfhi(p.w) * w1;
            }
        }
    }
    #pragma unroll
    for (int k = 0; k < 8; ++k) {
        a[k] += __shfl_xor(a[k], 16);
        a[k] += __shfl_xor(a[k], 32);
    }
    if (grp == 0) {
        float di = dinv[node];
        uint4 ps = Abf4[(size_t)node * 16 + sub];
        float4 bl = bias4[2 * sub], bh = bias4[2 * sub + 1];
        float r0 = a[0] * di + bflo(ps.x) * di * di + bl.x;
        float r1 = a[1] * di + bfhi(ps.x) * di * di + bl.y;
        float r2 = a[2] * di + bflo(ps.y) * di * di + bl.z;
        float r3 = a[3] * di + bfhi(ps.y) * di * di + bl.w;
        float r4 = a[4] * di + bflo(ps.z) * di * di + bh.x;
        float r5 = a[5] * di + bfhi(ps.z) * di * di + bh.y;
        float r6 = a[6] * di + bflo(ps.w) * di * di + bh.z;
        float r7 = a[7] * di + bfhi(ps.w) * di * di + bh.w;
        Bbf4[(size_t)node * 16 + sub] = make_uint4(packbf(r0, r1), packbf(r2, r3),
                                                   packbf(r4, r5), packbf(r6, r7));
    }
}

// layer-2: 12-feature aggregation over bf16 stride-16 rows, unroll 4.
__global__ void k_agg_out(const unsigned int* __restrict__ A16bf, const uint2* __restrict__ epair,
                          const int* __restrict__ R, const float* __restrict__ dinv,
                          const float* __restrict__ b2, float* __restrict__ out, int n, int e) {
    int t = blockIdx.x * blockDim.x + threadIdx.x;
    int node = t >> 3, u = t & 7;
    if (node >= n || u >= 6) return;
    int start = R[node];
    int end = (node + 1 < n) ? R[node + 1] : e;
    float ax = 0.f, ay = 0.f;
    int j = start;
    for (; j + 3 < end; j += 4) {
        uint2 p0 = epair[j], p1 = epair[j + 1], p2 = epair[j + 2], p3 = epair[j + 3];
        float w0 = dinv[p0.x] * __uint_as_float(p0.y);
        float w1 = dinv[p1.x] * __uint_as_float(p1.y);
        float w2 = dinv[p2.x] * __uint_as_float(p2.y);
        float w3 = dinv[p3.x] * __uint_as_float(p3.y);
        unsigned int q0 = A16bf[(size_t)p0.x * 8 + u];
        unsigned int q1 = A16bf[(size_t)p1.x * 8 + u];
        unsigned int q2 = A16bf[(size_t)p2.x * 8 + u];
        unsigned int q3 = A16bf[(size_t)p3.x * 8 + u];
        ax += bflo(q0) * w0 + bflo(q1) * w1 + bflo(q2) * w2 + bflo(q3) * w3;
        ay += bfhi(q0) * w0 + bfhi(q1) * w1 + bfhi(q2) * w2 + bfhi(q3) * w3;
    }
    for (; j < end; ++j) {
        uint2 p0 = epair[j];
        float w0 = dinv[p0.x] * __uint_as_float(p0.y);
        unsigned int q0 = A16bf[(size_t)p0.x * 8 + u];
        ax += bflo(q0) * w0;
        ay += bfhi(q0) * w0;
    }
    float di = dinv[node];
    unsigned int ps = A16bf[(size_t)node * 8 + u];
    ax = ax * di + bflo(ps) * di * di + b2[2 * u];
    ay = ay * di + bfhi(ps) * di * di + b2[2 * u + 1];
    ((float2*)(out + (size_t)node * 12))[u] = make_float2(ax, ay);
}

// ================= GEMMs =================
// xagg(N,16)@W0 + b0 -> B0 packed bf16 (64 uints/row)
__global__ void k_gemm_in(const float* __restrict__ x, const float* __restrict__ W,
                          const float* __restrict__ b, unsigned int* __restrict__ Bbf, int n) {
    __shared__ float Ws[16 * 128];
    __shared__ float xs[8 * 16];
    int f = threadIdx.x;
    #pragma unroll
    for (int k = 0; k < 16; ++k) Ws[k * 128 + f] = W[k * 128 + f];
    int node0 = blockIdx.x * 8;
    int nrows = n - node0; if (nrows > 8) nrows = 8;
    if (f < nrows * 16) xs[f] = x[(size_t)node0 * 16 + f];
    __syncthreads();
    float bf = b[f];
    for (int nl = 0; nl < nrows; ++nl) {
        float acc = bf;
        #pragma unroll
        for (int k = 0; k < 16; ++k) acc += xs[nl * 16 + k] * Ws[k * 128 + f];
        float hi = __shfl_xor(acc, 1);
        if ((f & 1) == 0)
            Bbf[(size_t)(node0 + nl) * 64 + (f >> 1)] = packbf(acc, hi);
    }
}

// BN stats over packed bf16 rows
__global__ void k_bn_stats(const unsigned int* __restrict__ h, float* __restrict__ sums,
                           float* __restrict__ sumsq, int n) {
    int u = threadIdx.x & 63, half = threadIdx.x >> 6;   // blockDim 128
    int i0 = blockIdx.x * 256 + half;
    int i1 = blockIdx.x * 256 + 256; if (i1 > n) i1 = n;
    float sl = 0.f, shh = 0.f, ql = 0.f, qh = 0.f;
    for (int i = i0; i < i1; i += 2) {
        unsigned int p = h[(size_t)i * 64 + u];
        float lo = bflo(p), hi = bfhi(p);
        sl += lo; ql += lo * lo;
        shh += hi; qh += hi * hi;
    }
    atomicAdd(&sums[2 * u], sl);
    atomicAdd(&sums[2 * u + 1], shh);
    atomicAdd(&sumsq[2 * u], ql);
    atomicAdd(&sumsq[2 * u + 1], qh);
}

// BN0+ReLU fused on load (bf16 in); MFMA bf16 -> Abf bf16 packed.
__global__ __launch_bounds__(256) void k_gemm_hid_mfma(
        const uint4* __restrict__ Bbf4, const float* __restrict__ sums,
        const float* __restrict__ sumsq, const float* __restrict__ g,
        const float* __restrict__ be, const unsigned int* __restrict__ W1p,
        unsigned int* __restrict__ Abf, int n, float invn) {
    __shared__ __align__(16) unsigned int hsbf[64 * HSTRIDE];
    __shared__ float sc[128], sh[128];
    int tid = threadIdx.x;
    if (tid < 128) {
        float m = sums[tid] * invn;
        float v = sumsq[tid] * invn - m * m;
        float scale = rsqrtf(v + EPS_BN) * g[tid];
        sc[tid] = scale;
        sh[tid] = be[tid] - m * scale;
    }
    __syncthreads();
    int node0 = blockIdx.x * 64;
    for (int i = tid; i < 64 * 16; i += 256) {
        int row = i >> 4, q = i & 15;
        int gn = node0 + row;
        uint4 pk;
        if (gn < n) {
            uint4 p = Bbf4[(size_t)gn * 16 + q];
            int fb = q * 8;
            float v0 = fmaxf(bflo(p.x) * sc[fb + 0] + sh[fb + 0], 0.f);
            float v1 = fmaxf(bfhi(p.x) * sc[fb + 1] + sh[fb + 1], 0.f);
            float v2 = fmaxf(bflo(p.y) * sc[fb + 2] + sh[fb + 2], 0.f);
            float v3 = fmaxf(bfhi(p.y) * sc[fb + 3] + sh[fb + 3], 0.f);
            float v4 = fmaxf(bflo(p.z) * sc[fb + 4] + sh[fb + 4], 0.f);
            float v5 = fmaxf(bfhi(p.z) * sc[fb + 5] + sh[fb + 5], 0.f);
            float v6 = fmaxf(bflo(p.w) * sc[fb + 6] + sh[fb + 6], 0.f);
            float v7 = fmaxf(bfhi(p.w) * sc[fb + 7] + sh[fb + 7], 0.f);
            pk = make_uint4(packbf(v0, v1), packbf(v2, v3), packbf(v4, v5), packbf(v6, v7));
        } else {
            pk = make_uint4(0u, 0u, 0u, 0u);
        }
        *((uint4*)&hsbf[row * HSTRIDE + q * 4]) = pk;
    }
    __syncthreads();
    int wave = tid >> 6, lane = tid & 63;
    int quad = lane >> 4, mrow = lane & 15;
    int lrow = wave * 16 + mrow;
    s16x8 afrag[4];
    #pragma unroll
    for (int kc = 0; kc < 4; ++kc)
        afrag[kc] = *((const s16x8*)&hsbf[lrow * HSTRIDE + kc * 16 + quad * 4]);
    int gnode_base = node0 + wave * 16;
    const s16x8* Wf = (const s16x8*)W1p;
    for (int ct = 0; ct < 8; ++ct) {
        f32x4 acc = {0.f, 0.f, 0.f, 0.f};
        #pragma unroll
        for (int kc = 0; kc < 4; ++kc) {
            s16x8 bfrag = Wf[(ct * 4 + kc) * 64 + lane];
            acc = __builtin_amdgcn_mfma_f32_16x16x32_bf16(afrag[kc], bfrag, acc, 0, 0, 0);
        }
        #pragma unroll
        for (int r = 0; r < 4; ++r) {
            float lo = acc[r];
            float hi = __shfl_xor(lo, 1);
            int grow = gnode_base + quad * 4 + r;
            if ((mrow & 1) == 0 && grow < n)
                Abf[(size_t)grow * 64 + ct * 8 + (mrow >> 1)] = packbf(lo, hi);
        }
    }
}

// BN1+ReLU fused on load (bf16 in); (N,128)@W2(128,12) -> A16bf bf16 stride-16
__global__ void k_gemm_out_bn(const unsigned int* __restrict__ Bbf, const float* __restrict__ sums,
                              const float* __restrict__ sumsq, const float* __restrict__ g,
                              const float* __restrict__ be, const float* __restrict__ W,
                              unsigned int* __restrict__ A16bf, int n, float invn) {
    __shared__ float hs[16 * 129];
    __shared__ float Ws[128 * 12];
    __shared__ float sc[128], sh[128];
    __shared__ float outv[16 * 12];
    int tid = threadIdx.x;   // 192
    if (tid < 128) {
        float m = sums[tid] * invn;
        float v = sumsq[tid] * invn - m * m;
        float scale = rsqrtf(v + EPS_BN) * g[tid];
        sc[tid] = scale;
        sh[tid] = be[tid] - m * scale;
    }
    for (int i = tid; i < 128 * 12; i += 192) Ws[i] = W[i];
    int node0 = blockIdx.x * 16;
    int nrows = n - node0; if (nrows > 16) nrows = 16;
    __syncthreads();
    for (int i = tid; i < nrows * 64; i += 192) {
        int row = i >> 6, u = i & 63;
        unsigned int p = Bbf[(size_t)(node0 + row) * 64 + u];
        hs[row * 129 + 2 * u]     = fmaxf(bflo(p) * sc[2 * u] + sh[2 * u], 0.f);
        hs[row * 129 + 2 * u + 1] = fmaxf(bfhi(p) * sc[2 * u + 1] + sh[2 * u + 1], 0.f);
    }
    __syncthreads();
    int nl = tid / 12, f = tid - nl * 12;
    if (nl < 16 && nl < nrows) {
        float acc = 0.f;
        for (int k = 0; k < 128; ++k) acc += hs[nl * 129 + k] * Ws[k * 12 + f];
        outv[nl * 12 + f] = acc;
    }
    __syncthreads();
    for (int i = tid; i < nrows * 8; i += 192) {
        int nn = i >> 3, u = i & 7;
        float lo = (2 * u < 12)     ? outv[nn * 12 + 2 * u]     : 0.f;
        float hi = (2 * u + 1 < 12) ? outv[nn * 12 + 2 * u + 1] : 0.f;
        A16bf[(size_t)(node0 + nn) * 8 + u] = packbf(lo, hi);
    }
}

// ================= launch =================
extern "C" void kernel_launch(void* const* d_in, const int* in_sizes, int n_in,
                              void* d_out, int out_size, void* d_ws, size_t ws_size,
                              hipStream_t stream) {
    const float* x   = (const float*)d_in[0];
    const int*   ei  = (const int*)d_in[1];
    const float* ew  = (const float*)d_in[2];
    const float* W0  = (const float*)d_in[3];
    const float* b0  = (const float*)d_in[4];
    const float* W1  = (const float*)d_in[5];
    const float* b1  = (const float*)d_in[6];
    const float* W2  = (const float*)d_in[7];
    const float* b2  = (const float*)d_in[8];
    const float* g0  = (const float*)d_in[9];
    const float* be0 = (const float*)d_in[10];
    const float* g1  = (const float*)d_in[11];
    const float* be1 = (const float*)d_in[12];
    float* out = (float*)d_out;

    const int n = in_sizes[0] / 16;   // 100000
    const int e = in_sizes[2];        // 1600000
    const int* src = ei;
    const int* dst = ei + e;

    // workspace layout (4B elems); rank[] aliases B (dead after k_place)
    float*        wsf   = (float*)d_ws;
    float*        dinv  = wsf;                                    // n
    int*          R     = (int*)(wsf + n);                        // n+4
    int*          bsum  = R + (n + 4);                            // 128
    uint2*        epair = (uint2*)(bsum + 128);                   // e pairs
    float*        B     = (float*)(bsum + 128 + 2 * (size_t)e);   // region (bf16 rows use half)
    int*          rank  = (int*)B;                                // e ints, aliases B
    unsigned int* Bbf   = (unsigned int*)B;                       // n*64 (bf16 packed), aliases B
    unsigned int* Abf   = (unsigned int*)(B + (size_t)n * 128);   // n*64
    unsigned int* xbf   = Abf + (size_t)n * 64;                   // n*8
    float*        xagg  = (float*)(xbf + (size_t)n * 8);          // n*16
    unsigned int* A16bf = (unsigned int*)(xagg + (size_t)n * 16); // n*8
    float*        sums  = (float*)(A16bf + (size_t)n * 8);        // 128
    float*        sumsq = sums + 128;                             // 128
    unsigned int* W1p   = (unsigned int*)(sumsq + 128);           // 8192

    const float invn = 1.0f / (float)n;
    const int nb_scan = (n + 1023) / 1024;

    // ---- CSR build (single atomic pass; norm folded into aggregation) ----
    hipMemsetAsync(R, 0, (size_t)(n + 4) * sizeof(int), stream);
    k_xcast<<<(n * 8 + 255) / 256, 256, 0, stream>>>(x, xbf, n * 8);
    k_prepW1<<<32, 256, 0, stream>>>(W1, W1p);
    k_hist_rank<<<(e + 255) / 256, 256, 0, stream>>>(dst, R, rank, e);
    k_scan_local<<<nb_scan, 256, 0, stream>>>(R, bsum, n);
    k_scan_bsum<<<1, 128, 0, stream>>>(bsum, nb_scan);
    k_scan_add<<<nb_scan, 256, 0, stream>>>(R, bsum, n);
    k_place<<<(e + 255) / 256, 256, 0, stream>>>(src, dst, ew, rank, R, epair, e);
    k_deg_dinv<<<(n + 255) / 256, 256, 0, stream>>>(epair, R, dinv, n, e);

    // ---- layer 0 ----
    k_agg_x<<<(n * 8 + 255) / 256, 256, 0, stream>>>(xbf, epair, R, dinv, xagg, n, e);
    k_gemm_in<<<(n + 7) / 8, 128, 0, stream>>>(xagg, W0, b0, Bbf, n);
    hipMemsetAsync(sums, 0, 256 * sizeof(float), stream);
    k_bn_stats<<<(n + 255) / 256, 128, 0, stream>>>(Bbf, sums, sumsq, n);

    // ---- layer 1 (MFMA GEMM with fused BN0+ReLU) ----
    k_gemm_hid_mfma<<<(n + 63) / 64, 256, 0, stream>>>((const uint4*)Bbf, sums, sumsq, g0, be0,
                                                       W1p, Abf, n, invn);
    k_aggregate128<<<(n * 64 + 255) / 256, 256, 0, stream>>>((const uint4*)Abf, epair, R, dinv,
                                                             (const float4*)b1, (uint4*)Bbf, n, e);
    hipMemsetAsync(sums, 0, 256 * sizeof(float), stream);
    k_bn_stats<<<(n + 255) / 256, 128, 0, stream>>>(Bbf, sums, sumsq, n);

    // ---- layer 2 ----
    k_gemm_out_bn<<<(n + 15) / 16, 192, 0, stream>>>(Bbf, sums, sumsq, g1, be1, W2, A16bf, n, invn);
    k_agg_out<<<(n * 8 + 255) / 256, 256, 0, stream>>>(A16bf, epair, R, dinv, b2, out, n, e);
}

// Round 8
// 562.633 us; speedup vs baseline: 10.5564x; 1.0061x over previous
//
#include <hip/hip_runtime.h>

#define EPS_BN 1e-5f
#define HSTRIDE 68   // 64 dwords + 4 pad (272B rows, 16B-aligned)

typedef __attribute__((ext_vector_type(4))) float f32x4;
typedef __attribute__((ext_vector_type(8))) short s16x8;

__device__ inline unsigned short f2bf(float f) {
    unsigned int u = __float_as_uint(f);
    unsigned int r = (u + 0x7fffu + ((u >> 16) & 1u)) >> 16;
    return (unsigned short)r;
}
__device__ inline unsigned int packbf(float lo, float hi) {
    return (unsigned int)f2bf(lo) | ((unsigned int)f2bf(hi) << 16);
}
__device__ inline float bflo(unsigned int p) { return __uint_as_float(p << 16); }
__device__ inline float bfhi(unsigned int p) { return __uint_as_float(p & 0xffff0000u); }

// ================= CSR build: 1 atomic per edge =================
__global__ void k_hist_rank(const int* __restrict__ dst, int* __restrict__ R,
                            int* __restrict__ rank, int e) {
    int i = blockIdx.x * blockDim.x + threadIdx.x;
    if (i < e) rank[i] = atomicAdd(&R[dst[i]], 1);
}

// ================= exclusive scan (3-kernel) =================
__global__ void k_scan_local(int* __restrict__ R, int* __restrict__ bsum, int n) {
    __shared__ int s[256];
    int t = threadIdx.x;
    int base = blockIdx.x * 1024 + t * 4;
    int v0 = (base + 0 < n) ? R[base + 0] : 0;
    int v1 = (base + 1 < n) ? R[base + 1] : 0;
    int v2 = (base + 2 < n) ? R[base + 2] : 0;
    int v3 = (base + 3 < n) ? R[base + 3] : 0;
    int sum = v0 + v1 + v2 + v3;
    s[t] = sum;
    __syncthreads();
    for (int off = 1; off < 256; off <<= 1) {
        int u = (t >= off) ? s[t - off] : 0;
        __syncthreads();
        s[t] += u;
        __syncthreads();
    }
    if (t == 255) bsum[blockIdx.x] = s[255];
    int run = s[t] - sum;
    if (base + 0 < n) R[base + 0] = run;  run += v0;
    if (base + 1 < n) R[base + 1] = run;  run += v1;
    if (base + 2 < n) R[base + 2] = run;  run += v2;
    if (base + 3 < n) R[base + 3] = run;
}

__global__ void k_scan_bsum(int* __restrict__ bsum, int nb) {
    __shared__ int s[128];
    int t = threadIdx.x;
    int v = (t < nb) ? bsum[t] : 0;
    s[t] = v;
    __syncthreads();
    for (int off = 1; off < 128; off <<= 1) {
        int u = (t >= off) ? s[t - off] : 0;
        __syncthreads();
        s[t] += u;
        __syncthreads();
    }
    if (t < nb) bsum[t] = s[t] - v;
}

__global__ void k_scan_add(int* __restrict__ R, const int* __restrict__ bsum, int n) {
    int add = bsum[blockIdx.x];
    int base = blockIdx.x * 1024 + threadIdx.x * 4;
    for (int k = 0; k < 4; ++k)
        if (base + k < n) R[base + k] += add;
}

// atomic-free placement
__global__ void k_place(const int* __restrict__ src, const int* __restrict__ dst,
                        const float* __restrict__ w, const int* __restrict__ rank,
                        const int* __restrict__ R, uint2* __restrict__ epair, int e) {
    int i = blockIdx.x * blockDim.x + threadIdx.x;
    if (i < e) {
        int d = dst[i];
        int pos = R[d] + rank[i];
        epair[pos] = make_uint2((unsigned int)src[i], __float_as_uint(w[i]));
    }
}

// contiguous per-row sum of w -> dinv
__global__ void k_deg_dinv(const uint2* __restrict__ epair, const int* __restrict__ R,
                           float* __restrict__ dinv, int n, int e) {
    int node = blockIdx.x * blockDim.x + threadIdx.x;
    if (node >= n) return;
    int start = R[node];
    int end = (node + 1 < n) ? R[node + 1] : e;
    float sum = 1.0f;
    for (int j = start; j < end; ++j) sum += __uint_as_float(epair[j].y);
    dinv[node] = rsqrtf(sum);
}

// ================= x -> bf16 AND W1 -> MFMA B-fragment, single launch =========
__global__ void k_prep(const float* __restrict__ x, unsigned int* __restrict__ xbf, int n8,
                       const float* __restrict__ W1, unsigned int* __restrict__ W1p) {
    int t = blockIdx.x * blockDim.x + threadIdx.x;
    if (t < n8) {
        float2 v = ((const float2*)x)[t];
        xbf[t] = packbf(v.x, v.y);
    }
    if (t < 8192) {
        int dj = t & 3;
        int lane = (t >> 2) & 63;
        int kc = (t >> 8) & 3;
        int ct = t >> 10;
        int quad = lane >> 4, mrow = lane & 15;
        int k0 = kc * 32 + quad * 8 + dj * 2;
        int col = ct * 16 + mrow;
        W1p[t] = packbf(W1[k0 * 128 + col], W1[(k0 + 1) * 128 + col]);
    }
}

// ================= aggregations (CSR, no atomics) =================
// layer-0: aggregate bf16 x, 8 lanes/node, unroll 4
__global__ void k_agg_x(const unsigned int* __restrict__ xbf, const uint2* __restrict__ epair,
                        const int* __restrict__ R, const float* __restrict__ dinv,
                        float* __restrict__ xagg, int n, int e) {
    int t = blockIdx.x * blockDim.x + threadIdx.x;
    int node = t >> 3, u = t & 7;
    if (node >= n) return;
    int start = R[node];
    int end = (node + 1 < n) ? R[node + 1] : e;
    float ax = 0.f, ay = 0.f;
    int j = start;
    for (; j + 3 < end; j += 4) {
        uint2 p0 = epair[j], p1 = epair[j + 1], p2 = epair[j + 2], p3 = epair[j + 3];
        float w0 = dinv[p0.x] * __uint_as_float(p0.y);
        float w1 = dinv[p1.x] * __uint_as_float(p1.y);
        float w2 = dinv[p2.x] * __uint_as_float(p2.y);
        float w3 = dinv[p3.x] * __uint_as_float(p3.y);
        unsigned int q0 = xbf[(size_t)p0.x * 8 + u];
        unsigned int q1 = xbf[(size_t)p1.x * 8 + u];
        unsigned int q2 = xbf[(size_t)p2.x * 8 + u];
        unsigned int q3 = xbf[(size_t)p3.x * 8 + u];
        ax += bflo(q0) * w0 + bflo(q1) * w1 + bflo(q2) * w2 + bflo(q3) * w3;
        ay += bfhi(q0) * w0 + bfhi(q1) * w1 + bfhi(q2) * w2 + bfhi(q3) * w3;
    }
    for (; j < end; ++j) {
        uint2 p0 = epair[j];
        float w0 = dinv[p0.x] * __uint_as_float(p0.y);
        unsigned int q0 = xbf[(size_t)p0.x * 8 + u];
        ax += bflo(q0) * w0;
        ay += bfhi(q0) * w0;
    }
    float di = dinv[node];
    unsigned int ps = xbf[(size_t)node * 8 + u];
    ax = ax * di + bflo(ps) * di * di;
    ay = ay * di + bfhi(ps) * di * di;
    ((float2*)xagg)[(size_t)node * 8 + u] = make_float2(ax, ay);
}

// layer-1: 128-feature bf16 aggregation. wave/node, FOUR 16-lane groups,
// uint4 per lane, 16 edges per trip (4 independent gathers/lane in flight).
__global__ void k_aggregate128(const uint4* __restrict__ Abf4, const uint2* __restrict__ epair,
                               const int* __restrict__ R, const float* __restrict__ dinv,
                               const float4* __restrict__ bias4, uint4* __restrict__ Bbf4,
                               int n, int e) {
    int gid = blockIdx.x * blockDim.x + threadIdx.x;
    int node = gid >> 6;
    if (node >= n) return;
    int lane = threadIdx.x & 63;
    int grp = lane >> 4, sub = lane & 15;
    int start = R[node];
    int end = (node + 1 < n) ? R[node + 1] : e;
    float a[8] = {0.f, 0.f, 0.f, 0.f, 0.f, 0.f, 0.f, 0.f};
    for (int base = start; base < end; base += 64) {
        int m = end - base; if (m > 64) m = 64;
        int myS = 0; float myW = 0.f;
        if (lane < m) {
            uint2 pr = epair[base + lane];
            myS = (int)pr.x;
            myW = dinv[pr.x] * __uint_as_float(pr.y);
        }
        for (int t = 0; t < m; t += 16) {
            int j0 = t + grp, j1 = t + 4 + grp, j2 = t + 8 + grp, j3 = t + 12 + grp;
            int s0 = __shfl(myS, j0); float w0 = __shfl(myW, j0);
            int s1 = __shfl(myS, j1); float w1 = __shfl(myW, j1);
            int s2 = __shfl(myS, j2); float w2 = __shfl(myW, j2);
            int s3 = __shfl(myS, j3); float w3 = __shfl(myW, j3);
            if (j0 < m) {
                uint4 p = Abf4[(size_t)s0 * 16 + sub];
                a[0] += bflo(p.x) * w0; a[1] += bfhi(p.x) * w0;
                a[2] += bflo(p.y) * w0; a[3] += bfhi(p.y) * w0;
                a[4] += bflo(p.z) * w0; a[5] += bfhi(p.z) * w0;
                a[6] += bflo(p.w) * w0; a[7] += bfhi(p.w) * w0;
            }
            if (j1 < m) {
                uint4 p = Abf4[(size_t)s1 * 16 + sub];
                a[0] += bflo(p.x) * w1; a[1] += bfhi(p.x) * w1;
                a[2] += bflo(p.y) * w1; a[3] += bfhi(p.y) * w1;
                a[4] += bflo(p.z) * w1; a[5] += bfhi(p.z) * w1;
                a[6] += bflo(p.w) * w1; a[7] += bfhi(p.w) * w1;
            }
            if (j2 < m) {
                uint4 p = Abf4[(size_t)s2 * 16 + sub];
                a[0] += bflo(p.x) * w2; a[1] += bfhi(p.x) * w2;
                a[2] += bflo(p.y) * w2; a[3] += bfhi(p.y) * w2;
                a[4] += bflo(p.z) * w2; a[5] += bfhi(p.z) * w2;
                a[6] += bflo(p.w) * w2; a[7] += bfhi(p.w) * w2;
            }
            if (j3 < m) {
                uint4 p = Abf4[(size_t)s3 * 16 + sub];
                a[0] += bflo(p.x) * w3; a[1] += bfhi(p.x) * w3;
                a[2] += bflo(p.y) * w3; a[3] += bfhi(p.y) * w3;
                a[4] += bflo(p.z) * w3; a[5] += bfhi(p.z) * w3;
                a[6] += bflo(p.w) * w3; a[7] += bfhi(p.w) * w3;
            }
        }
    }
    #pragma unroll
    for (int k = 0; k < 8; ++k) {
        a[k] += __shfl_xor(a[k], 16);
        a[k] += __shfl_xor(a[k], 32);
    }
    if (grp == 0) {
        float di = dinv[node];
        uint4 ps = Abf4[(size_t)node * 16 + sub];
        float4 bl = bias4[2 * sub], bh = bias4[2 * sub + 1];
        float r0 = a[0] * di + bflo(ps.x) * di * di + bl.x;
        float r1 = a[1] * di + bfhi(ps.x) * di * di + bl.y;
        float r2 = a[2] * di + bflo(ps.y) * di * di + bl.z;
        float r3 = a[3] * di + bfhi(ps.y) * di * di + bl.w;
        float r4 = a[4] * di + bflo(ps.z) * di * di + bh.x;
        float r5 = a[5] * di + bfhi(ps.z) * di * di + bh.y;
        float r6 = a[6] * di + bflo(ps.w) * di * di + bh.z;
        float r7 = a[7] * di + bfhi(ps.w) * di * di + bh.w;
        Bbf4[(size_t)node * 16 + sub] = make_uint4(packbf(r0, r1), packbf(r2, r3),
                                                   packbf(r4, r5), packbf(r6, r7));
    }
}

// layer-2: 12-feature aggregation over bf16 stride-16 rows, unroll 4.
__global__ void k_agg_out(const unsigned int* __restrict__ A16bf, const uint2* __restrict__ epair,
                          const int* __restrict__ R, const float* __restrict__ dinv,
                          const float* __restrict__ b2, float* __restrict__ out, int n, int e) {
    int t = blockIdx.x * blockDim.x + threadIdx.x;
    int node = t >> 3, u = t & 7;
    if (node >= n || u >= 6) return;
    int start = R[node];
    int end = (node + 1 < n) ? R[node + 1] : e;
    float ax = 0.f, ay = 0.f;
    int j = start;
    for (; j + 3 < end; j += 4) {
        uint2 p0 = epair[j], p1 = epair[j + 1], p2 = epair[j + 2], p3 = epair[j + 3];
        float w0 = dinv[p0.x] * __uint_as_float(p0.y);
        float w1 = dinv[p1.x] * __uint_as_float(p1.y);
        float w2 = dinv[p2.x] * __uint_as_float(p2.y);
        float w3 = dinv[p3.x] * __uint_as_float(p3.y);
        unsigned int q0 = A16bf[(size_t)p0.x * 8 + u];
        unsigned int q1 = A16bf[(size_t)p1.x * 8 + u];
        unsigned int q2 = A16bf[(size_t)p2.x * 8 + u];
        unsigned int q3 = A16bf[(size_t)p3.x * 8 + u];
        ax += bflo(q0) * w0 + bflo(q1) * w1 + bflo(q2) * w2 + bflo(q3) * w3;
        ay += bfhi(q0) * w0 + bfhi(q1) * w1 + bfhi(q2) * w2 + bfhi(q3) * w3;
    }
    for (; j < end; ++j) {
        uint2 p0 = epair[j];
        float w0 = dinv[p0.x] * __uint_as_float(p0.y);
        unsigned int q0 = A16bf[(size_t)p0.x * 8 + u];
        ax += bflo(q0) * w0;
        ay += bfhi(q0) * w0;
    }
    float di = dinv[node];
    unsigned int ps = A16bf[(size_t)node * 8 + u];
    ax = ax * di + bflo(ps) * di * di + b2[2 * u];
    ay = ay * di + bfhi(ps) * di * di + b2[2 * u + 1];
    ((float2*)(out + (size_t)node * 12))[u] = make_float2(ax, ay);
}

// ================= GEMMs =================
// xagg(N,16)@W0 + b0 -> B0 packed bf16 (64 uints/row)
__global__ void k_gemm_in(const float* __restrict__ x, const float* __restrict__ W,
                          const float* __restrict__ b, unsigned int* __restrict__ Bbf, int n) {
    __shared__ float Ws[16 * 128];
    __shared__ float xs[8 * 16];
    int f = threadIdx.x;
    #pragma unroll
    for (int k = 0; k < 16; ++k) Ws[k * 128 + f] = W[k * 128 + f];
    int node0 = blockIdx.x * 8;
    int nrows = n - node0; if (nrows > 8) nrows = 8;
    if (f < nrows * 16) xs[f] = x[(size_t)node0 * 16 + f];
    __syncthreads();
    float bf = b[f];
    for (int nl = 0; nl < nrows; ++nl) {
        float acc = bf;
        #pragma unroll
        for (int k = 0; k < 16; ++k) acc += xs[nl * 16 + k] * Ws[k * 128 + f];
        float hi = __shfl_xor(acc, 1);
        if ((f & 1) == 0)
            Bbf[(size_t)(node0 + nl) * 64 + (f >> 1)] = packbf(acc, hi);
    }
}

// BN stats over packed bf16 rows
__global__ void k_bn_stats(const unsigned int* __restrict__ h, float* __restrict__ sums,
                           float* __restrict__ sumsq, int n) {
    int u = threadIdx.x & 63, half = threadIdx.x >> 6;   // blockDim 128
    int i0 = blockIdx.x * 256 + half;
    int i1 = blockIdx.x * 256 + 256; if (i1 > n) i1 = n;
    float sl = 0.f, shh = 0.f, ql = 0.f, qh = 0.f;
    for (int i = i0; i < i1; i += 2) {
        unsigned int p = h[(size_t)i * 64 + u];
        float lo = bflo(p), hi = bfhi(p);
        sl += lo; ql += lo * lo;
        shh += hi; qh += hi * hi;
    }
    atomicAdd(&sums[2 * u], sl);
    atomicAdd(&sums[2 * u + 1], shh);
    atomicAdd(&sumsq[2 * u], ql);
    atomicAdd(&sumsq[2 * u + 1], qh);
}

// BN0+ReLU fused on load (bf16 in); MFMA bf16 -> Abf bf16 packed.
__global__ __launch_bounds__(256) void k_gemm_hid_mfma(
        const uint4* __restrict__ Bbf4, const float* __restrict__ sums,
        const float* __restrict__ sumsq, const float* __restrict__ g,
        const float* __restrict__ be, const unsigned int* __restrict__ W1p,
        unsigned int* __restrict__ Abf, int n, float invn) {
    __shared__ __align__(16) unsigned int hsbf[64 * HSTRIDE];
    __shared__ float sc[128], sh[128];
    int tid = threadIdx.x;
    if (tid < 128) {
        float m = sums[tid] * invn;
        float v = sumsq[tid] * invn - m * m;
        float scale = rsqrtf(v + EPS_BN) * g[tid];
        sc[tid] = scale;
        sh[tid] = be[tid] - m * scale;
    }
    __syncthreads();
    int node0 = blockIdx.x * 64;
    for (int i = tid; i < 64 * 16; i += 256) {
        int row = i >> 4, q = i & 15;
        int gn = node0 + row;
        uint4 pk;
        if (gn < n) {
            uint4 p = Bbf4[(size_t)gn * 16 + q];
            int fb = q * 8;
            float v0 = fmaxf(bflo(p.x) * sc[fb + 0] + sh[fb + 0], 0.f);
            float v1 = fmaxf(bfhi(p.x) * sc[fb + 1] + sh[fb + 1], 0.f);
            float v2 = fmaxf(bflo(p.y) * sc[fb + 2] + sh[fb + 2], 0.f);
            float v3 = fmaxf(bfhi(p.y) * sc[fb + 3] + sh[fb + 3], 0.f);
            float v4 = fmaxf(bflo(p.z) * sc[fb + 4] + sh[fb + 4], 0.f);
            float v5 = fmaxf(bfhi(p.z) * sc[fb + 5] + sh[fb + 5], 0.f);
            float v6 = fmaxf(bflo(p.w) * sc[fb + 6] + sh[fb + 6], 0.f);
            float v7 = fmaxf(bfhi(p.w) * sc[fb + 7] + sh[fb + 7], 0.f);
            pk = make_uint4(packbf(v0, v1), packbf(v2, v3), packbf(v4, v5), packbf(v6, v7));
        } else {
            pk = make_uint4(0u, 0u, 0u, 0u);
        }
        *((uint4*)&hsbf[row * HSTRIDE + q * 4]) = pk;
    }
    __syncthreads();
    int wave = tid >> 6, lane = tid & 63;
    int quad = lane >> 4, mrow = lane & 15;
    int lrow = wave * 16 + mrow;
    s16x8 afrag[4];
    #pragma unroll
    for (int kc = 0; kc < 4; ++kc)
        afrag[kc] = *((const s16x8*)&hsbf[lrow * HSTRIDE + kc * 16 + quad * 4]);
    int gnode_base = node0 + wave * 16;
    const s16x8* Wf = (const s16x8*)W1p;
    for (int ct = 0; ct < 8; ++ct) {
        f32x4 acc = {0.f, 0.f, 0.f, 0.f};
        #pragma unroll
        for (int kc = 0; kc < 4; ++kc) {
            s16x8 bfrag = Wf[(ct * 4 + kc) * 64 + lane];
            acc = __builtin_amdgcn_mfma_f32_16x16x32_bf16(afrag[kc], bfrag, acc, 0, 0, 0);
        }
        #pragma unroll
        for (int r = 0; r < 4; ++r) {
            float lo = acc[r];
            float hi = __shfl_xor(lo, 1);
            int grow = gnode_base + quad * 4 + r;
            if ((mrow & 1) == 0 && grow < n)
                Abf[(size_t)grow * 64 + ct * 8 + (mrow >> 1)] = packbf(lo, hi);
        }
    }
}

// BN1+ReLU fused on load (bf16 in); (N,128)@W2(128,12) -> A16bf bf16 stride-16
__global__ void k_gemm_out_bn(const unsigned int* __restrict__ Bbf, const float* __restrict__ sums,
                              const float* __restrict__ sumsq, const float* __restrict__ g,
                              const float* __restrict__ be, const float* __restrict__ W,
                              unsigned int* __restrict__ A16bf, int n, float invn) {
    __shared__ float hs[16 * 129];
    __shared__ float Ws[128 * 12];
    __shared__ float sc[128], sh[128];
    __shared__ float outv[16 * 12];
    int tid = threadIdx.x;   // 192
    if (tid < 128) {
        float m = sums[tid] * invn;
        float v = sumsq[tid] * invn - m * m;
        float scale = rsqrtf(v + EPS_BN) * g[tid];
        sc[tid] = scale;
        sh[tid] = be[tid] - m * scale;
    }
    for (int i = tid; i < 128 * 12; i += 192) Ws[i] = W[i];
    int node0 = blockIdx.x * 16;
    int nrows = n - node0; if (nrows > 16) nrows = 16;
    __syncthreads();
    for (int i = tid; i < nrows * 64; i += 192) {
        int row = i >> 6, u = i & 63;
        unsigned int p = Bbf[(size_t)(node0 + row) * 64 + u];
        hs[row * 129 + 2 * u]     = fmaxf(bflo(p) * sc[2 * u] + sh[2 * u], 0.f);
        hs[row * 129 + 2 * u + 1] = fmaxf(bfhi(p) * sc[2 * u + 1] + sh[2 * u + 1], 0.f);
    }
    __syncthreads();
    int nl = tid / 12, f = tid - nl * 12;
    if (nl < 16 && nl < nrows) {
        float acc = 0.f;
        for (int k = 0; k < 128; ++k) acc += hs[nl * 129 + k] * Ws[k * 12 + f];
        outv[nl * 12 + f] = acc;
    }
    __syncthreads();
    for (int i = tid; i < nrows * 8; i += 192) {
        int nn = i >> 3, u = i & 7;
        float lo = (2 * u < 12)     ? outv[nn * 12 + 2 * u]     : 0.f;
        float hi = (2 * u + 1 < 12) ? outv[nn * 12 + 2 * u + 1] : 0.f;
        A16bf[(size_t)(node0 + nn) * 8 + u] = packbf(lo, hi);
    }
}

// ================= launch =================
extern "C" void kernel_launch(void* const* d_in, const int* in_sizes, int n_in,
                              void* d_out, int out_size, void* d_ws, size_t ws_size,
                              hipStream_t stream) {
    const float* x   = (const float*)d_in[0];
    const int*   ei  = (const int*)d_in[1];
    const float* ew  = (const float*)d_in[2];
    const float* W0  = (const float*)d_in[3];
    const float* b0  = (const float*)d_in[4];
    const float* W1  = (const float*)d_in[5];
    const float* b1  = (const float*)d_in[6];
    const float* W2  = (const float*)d_in[7];
    const float* b2  = (const float*)d_in[8];
    const float* g0  = (const float*)d_in[9];
    const float* be0 = (const float*)d_in[10];
    const float* g1  = (const float*)d_in[11];
    const float* be1 = (const float*)d_in[12];
    float* out = (float*)d_out;

    const int n = in_sizes[0] / 16;   // 100000
    const int e = in_sizes[2];        // 1600000
    const int* src = ei;
    const int* dst = ei + e;

    // workspace layout (4B elems); rank[] aliases B region (dead after k_place)
    float*        wsf   = (float*)d_ws;
    float*        dinv  = wsf;                                    // n
    int*          R     = (int*)(wsf + n);                        // n+4
    int*          bsum  = R + (n + 4);                            // 128
    uint2*        epair = (uint2*)(bsum + 128);                   // e pairs
    float*        B     = (float*)(bsum + 128 + 2 * (size_t)e);   // region
    int*          rank  = (int*)B;                                // e ints, aliases B
    unsigned int* Bbf   = (unsigned int*)B;                       // n*64 (bf16 packed)
    unsigned int* Abf   = (unsigned int*)(B + (size_t)n * 128);   // n*64
    unsigned int* xbf   = Abf + (size_t)n * 64;                   // n*8
    float*        xagg  = (float*)(xbf + (size_t)n * 8);          // n*16
    unsigned int* A16bf = (unsigned int*)(xagg + (size_t)n * 16); // n*8
    float*        sums  = (float*)(A16bf + (size_t)n * 8);        // 128
    float*        sumsq = sums + 128;                             // 128
    unsigned int* W1p   = (unsigned int*)(sumsq + 128);           // 8192

    const float invn = 1.0f / (float)n;
    const int nb_scan = (n + 1023) / 1024;

    // ---- CSR build (single atomic pass; norm folded into aggregation) ----
    hipMemsetAsync(R, 0, (size_t)(n + 4) * sizeof(int), stream);
    k_prep<<<(n * 8 + 255) / 256, 256, 0, stream>>>(x, xbf, n * 8, W1, W1p);
    k_hist_rank<<<(e + 255) / 256, 256, 0, stream>>>(dst, R, rank, e);
    k_scan_local<<<nb_scan, 256, 0, stream>>>(R, bsum, n);
    k_scan_bsum<<<1, 128, 0, stream>>>(bsum, nb_scan);
    k_scan_add<<<nb_scan, 256, 0, stream>>>(R, bsum, n);
    k_place<<<(e + 255) / 256, 256, 0, stream>>>(src, dst, ew, rank, R, epair, e);
    k_deg_dinv<<<(n + 255) / 256, 256, 0, stream>>>(epair, R, dinv, n, e);

    // ---- layer 0 ----
    k_agg_x<<<(n * 8 + 255) / 256, 256, 0, stream>>>(xbf, epair, R, dinv, xagg, n, e);
    k_gemm_in<<<(n + 7) / 8, 128, 0, stream>>>(xagg, W0, b0, Bbf, n);
    hipMemsetAsync(sums, 0, 256 * sizeof(float), stream);
    k_bn_stats<<<(n + 255) / 256, 128, 0, stream>>>(Bbf, sums, sumsq, n);

    // ---- layer 1 (MFMA GEMM with fused BN0+ReLU) ----
    k_gemm_hid_mfma<<<(n + 63) / 64, 256, 0, stream>>>((const uint4*)Bbf, sums, sumsq, g0, be0,
                                                       W1p, Abf, n, invn);
    k_aggregate128<<<(n * 64 + 255) / 256, 256, 0, stream>>>((const uint4*)Abf, epair, R, dinv,
                                                             (const float4*)b1, (uint4*)Bbf, n, e);
    hipMemsetAsync(sums, 0, 256 * sizeof(float), stream);
    k_bn_stats<<<(n + 255) / 256, 128, 0, stream>>>(Bbf, sums, sumsq, n);

    // ---- layer 2 ----
    k_gemm_out_bn<<<(n + 15) / 16, 192, 0, stream>>>(Bbf, sums, sumsq, g1, be1, W2, A16bf, n, invn);
    k_agg_out<<<(n * 8 + 255) / 256, 256, 0, stream>>>(A16bf, epair, R, dinv, b2, out, n, e);
}

// Round 9
// 536.187 us; speedup vs baseline: 11.0770x; 1.0493x over previous
//
#include <hip/hip_runtime.h>

#define EPS_BN 1e-5f
#define HSTRIDE 68   // 64 dwords + 4 pad (272B rows, 16B-aligned)
#define BSH 9        // bucket = 512 consecutive nodes

typedef __attribute__((ext_vector_type(4))) float f32x4;
typedef __attribute__((ext_vector_type(8))) short s16x8;

__device__ inline unsigned short f2bf(float f) {
    unsigned int u = __float_as_uint(f);
    unsigned int r = (u + 0x7fffu + ((u >> 16) & 1u)) >> 16;
    return (unsigned short)r;
}
__device__ inline unsigned int packbf(float lo, float hi) {
    return (unsigned int)f2bf(lo) | ((unsigned int)f2bf(hi) << 16);
}
__device__ inline float bflo(unsigned int p) { return __uint_as_float(p << 16); }
__device__ inline float bfhi(unsigned int p) { return __uint_as_float(p & 0xffff0000u); }

// ================= bucketed CSR build (no per-edge global atomics) =========
// pass 1: per-bucket edge counts. 4096 edges/block, LDS histogram, flush once.
__global__ void k_pass1(const int* __restrict__ dst, int* __restrict__ bucketCnt, int e) {
    __shared__ int cnt[256];
    int t = threadIdx.x;
    cnt[t] = 0;
    __syncthreads();
    int base = blockIdx.x * 4096 + t * 16;
    #pragma unroll
    for (int k = 0; k < 16; ++k) {
        int i = base + k;
        if (i < e) atomicAdd(&cnt[dst[i] >> BSH], 1);
    }
    __syncthreads();
    int c = cnt[t];
    if (c) atomicAdd(&bucketCnt[t], c);
}

// exclusive scan of bucket counts -> bucketBase, init bucketCursor
__global__ void k_scan_buckets(const int* __restrict__ bucketCnt, int* __restrict__ bucketBase,
                               int* __restrict__ bucketCursor, int nb, int e) {
    __shared__ int s[256];
    int t = threadIdx.x;
    int v = (t < nb) ? bucketCnt[t] : 0;
    s[t] = v;
    __syncthreads();
    for (int off = 1; off < 256; off <<= 1) {
        int u = (t >= off) ? s[t - off] : 0;
        __syncthreads();
        s[t] += u;
        __syncthreads();
    }
    int excl = s[t] - v;
    if (t < nb) { bucketBase[t] = excl; bucketCursor[t] = excl; }
    if (t == 0) bucketBase[nb] = e;
}

// pass 2: scatter edges into bucket-partitioned etmp, coalesced via LDS staging.
// 2048 edges/block. record: {src | dstLocal<<17, w-bits}
__global__ void k_pass2(const int* __restrict__ src, const int* __restrict__ dst,
                        const float* __restrict__ w, int* __restrict__ bucketCursor,
                        uint2* __restrict__ etmp, int e) {
    __shared__ int cnt[256];
    __shared__ int s[256];
    __shared__ int gbase[256];
    __shared__ int lscan[256];
    __shared__ uint2 rec[2048];
    __shared__ unsigned short bof[2048];
    int t = threadIdx.x;
    cnt[t] = 0;
    __syncthreads();
    int base = blockIdx.x * 2048;
    int myB[8], myR[8];
    unsigned int mySrc[8], myW[8];
    int myDl[8];
    #pragma unroll
    for (int k = 0; k < 8; ++k) {
        int i = base + t * 8 + k;
        if (i < e) {
            int d = dst[i];
            myB[k] = d >> BSH;
            myDl[k] = d & 511;
            mySrc[k] = (unsigned int)src[i];
            myW[k] = __float_as_uint(w[i]);
            myR[k] = atomicAdd(&cnt[myB[k]], 1);
        } else {
            myB[k] = -1;
        }
    }
    __syncthreads();
    int c = cnt[t];
    s[t] = c;
    __syncthreads();
    for (int off = 1; off < 256; off <<= 1) {
        int u = (t >= off) ? s[t - off] : 0;
        __syncthreads();
        s[t] += u;
        __syncthreads();
    }
    lscan[t] = s[t] - c;
    if (c > 0) gbase[t] = atomicAdd(&bucketCursor[t], c);
    __syncthreads();
    #pragma unroll
    for (int k = 0; k < 8; ++k) {
        if (myB[k] >= 0) {
            int lpos = lscan[myB[k]] + myR[k];
            rec[lpos] = make_uint2(mySrc[k] | ((unsigned int)myDl[k] << 17), myW[k]);
            bof[lpos] = (unsigned short)myB[k];
        }
    }
    __syncthreads();
    int m = e - base; if (m > 2048) m = 2048;
    for (int i = t; i < m; i += 256) {
        int b = bof[i];
        etmp[gbase[b] + (i - lscan[b])] = rec[i];
    }
}

// pass 3: per-bucket local CSR + degree. One block per bucket (512 nodes).
__global__ void k_pass3(const uint2* __restrict__ etmp, const int* __restrict__ bucketBase,
                        int* __restrict__ R, uint2* __restrict__ epair,
                        float* __restrict__ dinv, int n) {
    __shared__ int hist[512];
    __shared__ float degs[512];
    __shared__ int s[256];
    int b = blockIdx.x, t = threadIdx.x;
    int lo = bucketBase[b], hi = bucketBase[b + 1];
    hist[t] = 0; hist[t + 256] = 0;
    degs[t] = 0.f; degs[t + 256] = 0.f;
    __syncthreads();
    for (int i = lo + t; i < hi; i += 256)
        atomicAdd(&hist[etmp[i].x >> 17], 1);
    __syncthreads();
    int c0 = hist[2 * t], c1 = hist[2 * t + 1];
    int p = c0 + c1;
    s[t] = p;
    __syncthreads();
    for (int off = 1; off < 256; off <<= 1) {
        int u = (t >= off) ? s[t - off] : 0;
        __syncthreads();
        s[t] += u;
        __syncthreads();
    }
    int excl = s[t] - p;
    int node0 = b << BSH;
    int e0 = excl, e1 = excl + c0;
    if (node0 + 2 * t < n)     R[node0 + 2 * t]     = lo + e0;
    if (node0 + 2 * t + 1 < n) R[node0 + 2 * t + 1] = lo + e1;
    __syncthreads();
    hist[2 * t] = e0; hist[2 * t + 1] = e1;   // cursors
    __syncthreads();
    for (int i = lo + t; i < hi; i += 256) {
        uint2 r = etmp[i];
        int dl = r.x >> 17;
        int slot = lo + atomicAdd(&hist[dl], 1);
        epair[slot] = make_uint2(r.x & 0x1FFFFu, r.y);
        atomicAdd(&degs[dl], __uint_as_float(r.y));
    }
    __syncthreads();
    for (int l = t; l < 512; l += 256) {
        int node = node0 + l;
        if (node < n) dinv[node] = rsqrtf(1.f + degs[l]);
    }
}

// ================= x -> bf16 AND W1 -> MFMA B-fragment, single launch =========
__global__ void k_prep(const float* __restrict__ x, unsigned int* __restrict__ xbf, int n8,
                       const float* __restrict__ W1, unsigned int* __restrict__ W1p) {
    int t = blockIdx.x * blockDim.x + threadIdx.x;
    if (t < n8) {
        float2 v = ((const float2*)x)[t];
        xbf[t] = packbf(v.x, v.y);
    }
    if (t < 8192) {
        int dj = t & 3;
        int lane = (t >> 2) & 63;
        int kc = (t >> 8) & 3;
        int ct = t >> 10;
        int quad = lane >> 4, mrow = lane & 15;
        int k0 = kc * 32 + quad * 8 + dj * 2;
        int col = ct * 16 + mrow;
        W1p[t] = packbf(W1[k0 * 128 + col], W1[(k0 + 1) * 128 + col]);
    }
}

// ================= aggregations (CSR, no atomics) =================
// layer-0: aggregate bf16 x, 8 lanes/node, unroll 4
__global__ void k_agg_x(const unsigned int* __restrict__ xbf, const uint2* __restrict__ epair,
                        const int* __restrict__ R, const float* __restrict__ dinv,
                        float* __restrict__ xagg, int n, int e) {
    int t = blockIdx.x * blockDim.x + threadIdx.x;
    int node = t >> 3, u = t & 7;
    if (node >= n) return;
    int start = R[node];
    int end = (node + 1 < n) ? R[node + 1] : e;
    float ax = 0.f, ay = 0.f;
    int j = start;
    for (; j + 3 < end; j += 4) {
        uint2 p0 = epair[j], p1 = epair[j + 1], p2 = epair[j + 2], p3 = epair[j + 3];
        float w0 = dinv[p0.x] * __uint_as_float(p0.y);
        float w1 = dinv[p1.x] * __uint_as_float(p1.y);
        float w2 = dinv[p2.x] * __uint_as_float(p2.y);
        float w3 = dinv[p3.x] * __uint_as_float(p3.y);
        unsigned int q0 = xbf[(size_t)p0.x * 8 + u];
        unsigned int q1 = xbf[(size_t)p1.x * 8 + u];
        unsigned int q2 = xbf[(size_t)p2.x * 8 + u];
        unsigned int q3 = xbf[(size_t)p3.x * 8 + u];
        ax += bflo(q0) * w0 + bflo(q1) * w1 + bflo(q2) * w2 + bflo(q3) * w3;
        ay += bfhi(q0) * w0 + bfhi(q1) * w1 + bfhi(q2) * w2 + bfhi(q3) * w3;
    }
    for (; j < end; ++j) {
        uint2 p0 = epair[j];
        float w0 = dinv[p0.x] * __uint_as_float(p0.y);
        unsigned int q0 = xbf[(size_t)p0.x * 8 + u];
        ax += bflo(q0) * w0;
        ay += bfhi(q0) * w0;
    }
    float di = dinv[node];
    unsigned int ps = xbf[(size_t)node * 8 + u];
    ax = ax * di + bflo(ps) * di * di;
    ay = ay * di + bfhi(ps) * di * di;
    ((float2*)xagg)[(size_t)node * 8 + u] = make_float2(ax, ay);
}

// layer-1: 128-feature bf16 aggregation. wave/node, four 16-lane groups.
__global__ void k_aggregate128(const uint4* __restrict__ Abf4, const uint2* __restrict__ epair,
                               const int* __restrict__ R, const float* __restrict__ dinv,
                               const float4* __restrict__ bias4, uint4* __restrict__ Bbf4,
                               int n, int e) {
    int gid = blockIdx.x * blockDim.x + threadIdx.x;
    int node = gid >> 6;
    if (node >= n) return;
    int lane = threadIdx.x & 63;
    int grp = lane >> 4, sub = lane & 15;
    int start = R[node];
    int end = (node + 1 < n) ? R[node + 1] : e;
    float a[8] = {0.f, 0.f, 0.f, 0.f, 0.f, 0.f, 0.f, 0.f};
    for (int base = start; base < end; base += 64) {
        int m = end - base; if (m > 64) m = 64;
        int myS = 0; float myW = 0.f;
        if (lane < m) {
            uint2 pr = epair[base + lane];
            myS = (int)pr.x;
            myW = dinv[pr.x] * __uint_as_float(pr.y);
        }
        for (int t = 0; t < m; t += 16) {
            int j0 = t + grp, j1 = t + 4 + grp, j2 = t + 8 + grp, j3 = t + 12 + grp;
            int s0 = __shfl(myS, j0); float w0 = __shfl(myW, j0);
            int s1 = __shfl(myS, j1); float w1 = __shfl(myW, j1);
            int s2 = __shfl(myS, j2); float w2 = __shfl(myW, j2);
            int s3 = __shfl(myS, j3); float w3 = __shfl(myW, j3);
            if (j0 < m) {
                uint4 p = Abf4[(size_t)s0 * 16 + sub];
                a[0] += bflo(p.x) * w0; a[1] += bfhi(p.x) * w0;
                a[2] += bflo(p.y) * w0; a[3] += bfhi(p.y) * w0;
                a[4] += bflo(p.z) * w0; a[5] += bfhi(p.z) * w0;
                a[6] += bflo(p.w) * w0; a[7] += bfhi(p.w) * w0;
            }
            if (j1 < m) {
                uint4 p = Abf4[(size_t)s1 * 16 + sub];
                a[0] += bflo(p.x) * w1; a[1] += bfhi(p.x) * w1;
                a[2] += bflo(p.y) * w1; a[3] += bfhi(p.y) * w1;
                a[4] += bflo(p.z) * w1; a[5] += bfhi(p.z) * w1;
                a[6] += bflo(p.w) * w1; a[7] += bfhi(p.w) * w1;
            }
            if (j2 < m) {
                uint4 p = Abf4[(size_t)s2 * 16 + sub];
                a[0] += bflo(p.x) * w2; a[1] += bfhi(p.x) * w2;
                a[2] += bflo(p.y) * w2; a[3] += bfhi(p.y) * w2;
                a[4] += bflo(p.z) * w2; a[5] += bfhi(p.z) * w2;
                a[6] += bflo(p.w) * w2; a[7] += bfhi(p.w) * w2;
            }
            if (j3 < m) {
                uint4 p = Abf4[(size_t)s3 * 16 + sub];
                a[0] += bflo(p.x) * w3; a[1] += bfhi(p.x) * w3;
                a[2] += bflo(p.y) * w3; a[3] += bfhi(p.y) * w3;
                a[4] += bflo(p.z) * w3; a[5] += bfhi(p.z) * w3;
                a[6] += bflo(p.w) * w3; a[7] += bfhi(p.w) * w3;
            }
        }
    }
    #pragma unroll
    for (int k = 0; k < 8; ++k) {
        a[k] += __shfl_xor(a[k], 16);
        a[k] += __shfl_xor(a[k], 32);
    }
    if (grp == 0) {
        float di = dinv[node];
        uint4 ps = Abf4[(size_t)node * 16 + sub];
        float4 bl = bias4[2 * sub], bh = bias4[2 * sub + 1];
        float r0 = a[0] * di + bflo(ps.x) * di * di + bl.x;
        float r1 = a[1] * di + bfhi(ps.x) * di * di + bl.y;
        float r2 = a[2] * di + bflo(ps.y) * di * di + bl.z;
        float r3 = a[3] * di + bfhi(ps.y) * di * di + bl.w;
        float r4 = a[4] * di + bflo(ps.z) * di * di + bh.x;
        float r5 = a[5] * di + bfhi(ps.z) * di * di + bh.y;
        float r6 = a[6] * di + bflo(ps.w) * di * di + bh.z;
        float r7 = a[7] * di + bfhi(ps.w) * di * di + bh.w;
        Bbf4[(size_t)node * 16 + sub] = make_uint4(packbf(r0, r1), packbf(r2, r3),
                                                   packbf(r4, r5), packbf(r6, r7));
    }
}

// layer-2: 12-feature aggregation over bf16 stride-16 rows, unroll 4.
__global__ void k_agg_out(const unsigned int* __restrict__ A16bf, const uint2* __restrict__ epair,
                          const int* __restrict__ R, const float* __restrict__ dinv,
                          const float* __restrict__ b2, float* __restrict__ out, int n, int e) {
    int t = blockIdx.x * blockDim.x + threadIdx.x;
    int node = t >> 3, u = t & 7;
    if (node >= n || u >= 6) return;
    int start = R[node];
    int end = (node + 1 < n) ? R[node + 1] : e;
    float ax = 0.f, ay = 0.f;
    int j = start;
    for (; j + 3 < end; j += 4) {
        uint2 p0 = epair[j], p1 = epair[j + 1], p2 = epair[j + 2], p3 = epair[j + 3];
        float w0 = dinv[p0.x] * __uint_as_float(p0.y);
        float w1 = dinv[p1.x] * __uint_as_float(p1.y);
        float w2 = dinv[p2.x] * __uint_as_float(p2.y);
        float w3 = dinv[p3.x] * __uint_as_float(p3.y);
        unsigned int q0 = A16bf[(size_t)p0.x * 8 + u];
        unsigned int q1 = A16bf[(size_t)p1.x * 8 + u];
        unsigned int q2 = A16bf[(size_t)p2.x * 8 + u];
        unsigned int q3 = A16bf[(size_t)p3.x * 8 + u];
        ax += bflo(q0) * w0 + bflo(q1) * w1 + bflo(q2) * w2 + bflo(q3) * w3;
        ay += bfhi(q0) * w0 + bfhi(q1) * w1 + bfhi(q2) * w2 + bfhi(q3) * w3;
    }
    for (; j < end; ++j) {
        uint2 p0 = epair[j];
        float w0 = dinv[p0.x] * __uint_as_float(p0.y);
        unsigned int q0 = A16bf[(size_t)p0.x * 8 + u];
        ax += bflo(q0) * w0;
        ay += bfhi(q0) * w0;
    }
    float di = dinv[node];
    unsigned int ps = A16bf[(size_t)node * 8 + u];
    ax = ax * di + bflo(ps) * di * di + b2[2 * u];
    ay = ay * di + bfhi(ps) * di * di + b2[2 * u + 1];
    ((float2*)(out + (size_t)node * 12))[u] = make_float2(ax, ay);
}

// ================= GEMMs =================
__global__ void k_gemm_in(const float* __restrict__ x, const float* __restrict__ W,
                          const float* __restrict__ b, unsigned int* __restrict__ Bbf, int n) {
    __shared__ float Ws[16 * 128];
    __shared__ float xs[8 * 16];
    int f = threadIdx.x;
    #pragma unroll
    for (int k = 0; k < 16; ++k) Ws[k * 128 + f] = W[k * 128 + f];
    int node0 = blockIdx.x * 8;
    int nrows = n - node0; if (nrows > 8) nrows = 8;
    if (f < nrows * 16) xs[f] = x[(size_t)node0 * 16 + f];
    __syncthreads();
    float bf = b[f];
    for (int nl = 0; nl < nrows; ++nl) {
        float acc = bf;
        #pragma unroll
        for (int k = 0; k < 16; ++k) acc += xs[nl * 16 + k] * Ws[k * 128 + f];
        float hi = __shfl_xor(acc, 1);
        if ((f & 1) == 0)
            Bbf[(size_t)(node0 + nl) * 64 + (f >> 1)] = packbf(acc, hi);
    }
}

// BN stats over packed bf16 rows
__global__ void k_bn_stats(const unsigned int* __restrict__ h, float* __restrict__ sums,
                           float* __restrict__ sumsq, int n) {
    int u = threadIdx.x & 63, half = threadIdx.x >> 6;   // blockDim 128
    int i0 = blockIdx.x * 256 + half;
    int i1 = blockIdx.x * 256 + 256; if (i1 > n) i1 = n;
    float sl = 0.f, shh = 0.f, ql = 0.f, qh = 0.f;
    for (int i = i0; i < i1; i += 2) {
        unsigned int p = h[(size_t)i * 64 + u];
        float lo = bflo(p), hi = bfhi(p);
        sl += lo; ql += lo * lo;
        shh += hi; qh += hi * hi;
    }
    atomicAdd(&sums[2 * u], sl);
    atomicAdd(&sums[2 * u + 1], shh);
    atomicAdd(&sumsq[2 * u], ql);
    atomicAdd(&sumsq[2 * u + 1], qh);
}

// BN0+ReLU fused on load (bf16 in); MFMA bf16 -> Abf bf16 packed.
__global__ __launch_bounds__(256) void k_gemm_hid_mfma(
        const uint4* __restrict__ Bbf4, const float* __restrict__ sums,
        const float* __restrict__ sumsq, const float* __restrict__ g,
        const float* __restrict__ be, const unsigned int* __restrict__ W1p,
        unsigned int* __restrict__ Abf, int n, float invn) {
    __shared__ __align__(16) unsigned int hsbf[64 * HSTRIDE];
    __shared__ float sc[128], sh[128];
    int tid = threadIdx.x;
    if (tid < 128) {
        float m = sums[tid] * invn;
        float v = sumsq[tid] * invn - m * m;
        float scale = rsqrtf(v + EPS_BN) * g[tid];
        sc[tid] = scale;
        sh[tid] = be[tid] - m * scale;
    }
    __syncthreads();
    int node0 = blockIdx.x * 64;
    for (int i = tid; i < 64 * 16; i += 256) {
        int row = i >> 4, q = i & 15;
        int gn = node0 + row;
        uint4 pk;
        if (gn < n) {
            uint4 p = Bbf4[(size_t)gn * 16 + q];
            int fb = q * 8;
            float v0 = fmaxf(bflo(p.x) * sc[fb + 0] + sh[fb + 0], 0.f);
            float v1 = fmaxf(bfhi(p.x) * sc[fb + 1] + sh[fb + 1], 0.f);
            float v2 = fmaxf(bflo(p.y) * sc[fb + 2] + sh[fb + 2], 0.f);
            float v3 = fmaxf(bfhi(p.y) * sc[fb + 3] + sh[fb + 3], 0.f);
            float v4 = fmaxf(bflo(p.z) * sc[fb + 4] + sh[fb + 4], 0.f);
            float v5 = fmaxf(bfhi(p.z) * sc[fb + 5] + sh[fb + 5], 0.f);
            float v6 = fmaxf(bflo(p.w) * sc[fb + 6] + sh[fb + 6], 0.f);
            float v7 = fmaxf(bfhi(p.w) * sc[fb + 7] + sh[fb + 7], 0.f);
            pk = make_uint4(packbf(v0, v1), packbf(v2, v3), packbf(v4, v5), packbf(v6, v7));
        } else {
            pk = make_uint4(0u, 0u, 0u, 0u);
        }
        *((uint4*)&hsbf[row * HSTRIDE + q * 4]) = pk;
    }
    __syncthreads();
    int wave = tid >> 6, lane = tid & 63;
    int quad = lane >> 4, mrow = lane & 15;
    int lrow = wave * 16 + mrow;
    s16x8 afrag[4];
    #pragma unroll
    for (int kc = 0; kc < 4; ++kc)
        afrag[kc] = *((const s16x8*)&hsbf[lrow * HSTRIDE + kc * 16 + quad * 4]);
    int gnode_base = node0 + wave * 16;
    const s16x8* Wf = (const s16x8*)W1p;
    for (int ct = 0; ct < 8; ++ct) {
        f32x4 acc = {0.f, 0.f, 0.f, 0.f};
        #pragma unroll
        for (int kc = 0; kc < 4; ++kc) {
            s16x8 bfrag = Wf[(ct * 4 + kc) * 64 + lane];
            acc = __builtin_amdgcn_mfma_f32_16x16x32_bf16(afrag[kc], bfrag, acc, 0, 0, 0);
        }
        #pragma unroll
        for (int r = 0; r < 4; ++r) {
            float lo = acc[r];
            float hi = __shfl_xor(lo, 1);
            int grow = gnode_base + quad * 4 + r;
            if ((mrow & 1) == 0 && grow < n)
                Abf[(size_t)grow * 64 + ct * 8 + (mrow >> 1)] = packbf(lo, hi);
        }
    }
}

// BN1+ReLU fused on load (bf16 in); (N,128)@W2(128,12) -> A16bf bf16 stride-16
__global__ void k_gemm_out_bn(const unsigned int* __restrict__ Bbf, const float* __restrict__ sums,
                              const float* __restrict__ sumsq, const float* __restrict__ g,
                              const float* __restrict__ be, const float* __restrict__ W,
                              unsigned int* __restrict__ A16bf, int n, float invn) {
    __shared__ float hs[16 * 129];
    __shared__ float Ws[128 * 12];
    __shared__ float sc[128], sh[128];
    __shared__ float outv[16 * 12];
    int tid = threadIdx.x;   // 192
    if (tid < 128) {
        float m = sums[tid] * invn;
        float v = sumsq[tid] * invn - m * m;
        float scale = rsqrtf(v + EPS_BN) * g[tid];
        sc[tid] = scale;
        sh[tid] = be[tid] - m * scale;
    }
    for (int i = tid; i < 128 * 12; i += 192) Ws[i] = W[i];
    int node0 = blockIdx.x * 16;
    int nrows = n - node0; if (nrows > 16) nrows = 16;
    __syncthreads();
    for (int i = tid; i < nrows * 64; i += 192) {
        int row = i >> 6, u = i & 63;
        unsigned int p = Bbf[(size_t)(node0 + row) * 64 + u];
        hs[row * 129 + 2 * u]     = fmaxf(bflo(p) * sc[2 * u] + sh[2 * u], 0.f);
        hs[row * 129 + 2 * u + 1] = fmaxf(bfhi(p) * sc[2 * u + 1] + sh[2 * u + 1], 0.f);
    }
    __syncthreads();
    int nl = tid / 12, f = tid - nl * 12;
    if (nl < 16 && nl < nrows) {
        float acc = 0.f;
        for (int k = 0; k < 128; ++k) acc += hs[nl * 129 + k] * Ws[k * 12 + f];
        outv[nl * 12 + f] = acc;
    }
    __syncthreads();
    for (int i = tid; i < nrows * 8; i += 192) {
        int nn = i >> 3, u = i & 7;
        float lo = (2 * u < 12)     ? outv[nn * 12 + 2 * u]     : 0.f;
        float hi = (2 * u + 1 < 12) ? outv[nn * 12 + 2 * u + 1] : 0.f;
        A16bf[(size_t)(node0 + nn) * 8 + u] = packbf(lo, hi);
    }
}

// ================= launch =================
extern "C" void kernel_launch(void* const* d_in, const int* in_sizes, int n_in,
                              void* d_out, int out_size, void* d_ws, size_t ws_size,
                              hipStream_t stream) {
    const float* x   = (const float*)d_in[0];
    const int*   ei  = (const int*)d_in[1];
    const float* ew  = (const float*)d_in[2];
    const float* W0  = (const float*)d_in[3];
    const float* b0  = (const float*)d_in[4];
    const float* W1  = (const float*)d_in[5];
    const float* b1  = (const float*)d_in[6];
    const float* W2  = (const float*)d_in[7];
    const float* b2  = (const float*)d_in[8];
    const float* g0  = (const float*)d_in[9];
    const float* be0 = (const float*)d_in[10];
    const float* g1  = (const float*)d_in[11];
    const float* be1 = (const float*)d_in[12];
    float* out = (float*)d_out;

    const int n = in_sizes[0] / 16;   // 100000
    const int e = in_sizes[2];        // 1600000
    const int* src = ei;
    const int* dst = ei + e;
    const int NB = (n + 511) >> 9;    // 196 buckets of 512 nodes

    // workspace layout (4B elems); etmp aliases B region (dead before Bbf written)
    float*        wsf   = (float*)d_ws;
    float*        dinv  = wsf;                                    // n
    int*          R     = (int*)(wsf + n);                        // n+4
    int*          bCnt  = R + (n + 4);                            // 512
    int*          bBase = bCnt + 512;                             // 520
    int*          bCur  = bBase + 520;                            // 512
    uint2*        epair = (uint2*)(bCur + 512);                   // e pairs
    float*        B     = (float*)(bCur + 512 + 2 * (size_t)e);   // region (n*128 dwords)
    uint2*        etmp  = (uint2*)B;                              // e pairs, aliases B
    unsigned int* Bbf   = (unsigned int*)B;                       // n*64 (bf16 packed)
    unsigned int* Abf   = (unsigned int*)(B + (size_t)n * 128);   // n*64
    unsigned int* xbf   = Abf + (size_t)n * 64;                   // n*8
    float*        xagg  = (float*)(xbf + (size_t)n * 8);          // n*16
    unsigned int* A16bf = (unsigned int*)(xagg + (size_t)n * 16); // n*8
    float*        sums  = (float*)(A16bf + (size_t)n * 8);        // 128
    float*        sumsq = sums + 128;                             // 128
    unsigned int* W1p   = (unsigned int*)(sumsq + 128);           // 8192

    const float invn = 1.0f / (float)n;

    // ---- bucketed CSR build (LDS histograms; ~150K global atomics total) ----
    hipMemsetAsync(bCnt, 0, 512 * sizeof(int), stream);
    k_prep<<<(n * 8 + 255) / 256, 256, 0, stream>>>(x, xbf, n * 8, W1, W1p);
    k_pass1<<<(e + 4095) / 4096, 256, 0, stream>>>(dst, bCnt, e);
    k_scan_buckets<<<1, 256, 0, stream>>>(bCnt, bBase, bCur, NB, e);
    k_pass2<<<(e + 2047) / 2048, 256, 0, stream>>>(src, dst, ew, bCur, etmp, e);
    k_pass3<<<NB, 256, 0, stream>>>(etmp, bBase, R, epair, dinv, n);

    // ---- layer 0 ----
    k_agg_x<<<(n * 8 + 255) / 256, 256, 0, stream>>>(xbf, epair, R, dinv, xagg, n, e);
    k_gemm_in<<<(n + 7) / 8, 128, 0, stream>>>(xagg, W0, b0, Bbf, n);
    hipMemsetAsync(sums, 0, 256 * sizeof(float), stream);
    k_bn_stats<<<(n + 255) / 256, 128, 0, stream>>>(Bbf, sums, sumsq, n);

    // ---- layer 1 (MFMA GEMM with fused BN0+ReLU) ----
    k_gemm_hid_mfma<<<(n + 63) / 64, 256, 0, stream>>>((const uint4*)Bbf, sums, sumsq, g0, be0,
                                                       W1p, Abf, n, invn);
    k_aggregate128<<<(n * 64 + 255) / 256, 256, 0, stream>>>((const uint4*)Abf, epair, R, dinv,
                                                             (const float4*)b1, (uint4*)Bbf, n, e);
    hipMemsetAsync(sums, 0, 256 * sizeof(float), stream);
    k_bn_stats<<<(n + 255) / 256, 128, 0, stream>>>(Bbf, sums, sumsq, n);

    // ---- layer 2 ----
    k_gemm_out_bn<<<(n + 15) / 16, 192, 0, stream>>>(Bbf, sums, sumsq, g1, be1, W2, A16bf, n, invn);
    k_agg_out<<<(n * 8 + 255) / 256, 256, 0, stream>>>(A16bf, epair, R, dinv, b2, out, n, e);
}

// Round 10
// 502.535 us; speedup vs baseline: 11.8188x; 1.0670x over previous
//
#include <hip/hip_runtime.h>

#define EPS_BN 1e-5f
#define HSTRIDE 68   // 64 dwords + 4 pad (272B rows, 16B-aligned)
#define BSH 9        // bucket = 512 consecutive nodes

typedef __attribute__((ext_vector_type(4))) float f32x4;
typedef __attribute__((ext_vector_type(8))) short s16x8;

__device__ inline unsigned short f2bf(float f) {
    unsigned int u = __float_as_uint(f);
    unsigned int r = (u + 0x7fffu + ((u >> 16) & 1u)) >> 16;
    return (unsigned short)r;
}
__device__ inline unsigned int packbf(float lo, float hi) {
    return (unsigned int)f2bf(lo) | ((unsigned int)f2bf(hi) << 16);
}
__device__ inline float bflo(unsigned int p) { return __uint_as_float(p << 16); }
__device__ inline float bfhi(unsigned int p) { return __uint_as_float(p & 0xffff0000u); }

// ====== combined prep: x->bf16, W1/W2 -> MFMA B-frags, bucket histogram ======
__global__ void k_prep_all(const float* __restrict__ x, unsigned int* __restrict__ xbf, int n8,
                           const float* __restrict__ W1, unsigned int* __restrict__ W1p,
                           const float* __restrict__ W2, unsigned int* __restrict__ W2p,
                           const int* __restrict__ dst, int* __restrict__ bCnt,
                           int e, int nhist) {
    __shared__ int cnt[256];
    int tid = threadIdx.x;
    bool hb = ((int)blockIdx.x < nhist);
    if (hb) cnt[tid] = 0;
    __syncthreads();
    int t = blockIdx.x * 256 + tid;
    if (t < n8) {
        float2 v = ((const float2*)x)[t];
        xbf[t] = packbf(v.x, v.y);
    }
    if (t < 8192) {
        int dj = t & 3;
        int lane = (t >> 2) & 63;
        int kc = (t >> 8) & 3;
        int ct = t >> 10;
        int quad = lane >> 4, mrow = lane & 15;
        int k0 = kc * 32 + quad * 8 + dj * 2;
        int col = ct * 16 + mrow;
        W1p[t] = packbf(W1[k0 * 128 + col], W1[(k0 + 1) * 128 + col]);
    }
    if (t < 1024) {
        int dj = t & 3;
        int lane = (t >> 2) & 63;
        int kc = t >> 8;                   // 0..3
        int quad = lane >> 4, mrow = lane & 15;
        int k0 = kc * 32 + quad * 8 + dj * 2;
        float lo = (mrow < 12) ? W2[k0 * 12 + mrow] : 0.f;
        float hi = (mrow < 12) ? W2[(k0 + 1) * 12 + mrow] : 0.f;
        W2p[t] = packbf(lo, hi);
    }
    if (hb) {
        int base = blockIdx.x * 4096 + tid * 16;
        #pragma unroll
        for (int k = 0; k < 16; ++k) {
            int i = base + k;
            if (i < e) atomicAdd(&cnt[dst[i] >> BSH], 1);
        }
    }
    __syncthreads();
    if (hb) {
        int c = cnt[tid];
        if (c) atomicAdd(&bCnt[tid], c);
    }
}

// exclusive scan of bucket counts -> bucketBase, init cursors; zero BN stat buffers
__global__ void k_scan_buckets(const int* __restrict__ bucketCnt, int* __restrict__ bucketBase,
                               int* __restrict__ bucketCursor, int nb, int e,
                               float* __restrict__ stat0, float* __restrict__ stat1) {
    __shared__ int s[256];
    int t = threadIdx.x;
    stat0[t] = 0.f;
    stat1[t] = 0.f;
    int v = (t < nb) ? bucketCnt[t] : 0;
    s[t] = v;
    __syncthreads();
    for (int off = 1; off < 256; off <<= 1) {
        int u = (t >= off) ? s[t - off] : 0;
        __syncthreads();
        s[t] += u;
        __syncthreads();
    }
    int excl = s[t] - v;
    if (t < nb) { bucketBase[t] = excl; bucketCursor[t] = excl; }
    if (t == 0) bucketBase[nb] = e;
}

// pass 2: scatter edges into bucket-partitioned etmp, coalesced via LDS staging.
__global__ void k_pass2(const int* __restrict__ src, const int* __restrict__ dst,
                        const float* __restrict__ w, int* __restrict__ bucketCursor,
                        uint2* __restrict__ etmp, int e) {
    __shared__ int cnt[256];
    __shared__ int s[256];
    __shared__ int gbase[256];
    __shared__ int lscan[256];
    __shared__ uint2 rec[2048];
    __shared__ unsigned short bof[2048];
    int t = threadIdx.x;
    cnt[t] = 0;
    __syncthreads();
    int base = blockIdx.x * 2048;
    int myB[8], myR[8];
    unsigned int mySrc[8], myW[8];
    int myDl[8];
    #pragma unroll
    for (int k = 0; k < 8; ++k) {
        int i = base + t * 8 + k;
        if (i < e) {
            int d = dst[i];
            myB[k] = d >> BSH;
            myDl[k] = d & 511;
            mySrc[k] = (unsigned int)src[i];
            myW[k] = __float_as_uint(w[i]);
            myR[k] = atomicAdd(&cnt[myB[k]], 1);
        } else {
            myB[k] = -1;
        }
    }
    __syncthreads();
    int c = cnt[t];
    s[t] = c;
    __syncthreads();
    for (int off = 1; off < 256; off <<= 1) {
        int u = (t >= off) ? s[t - off] : 0;
        __syncthreads();
        s[t] += u;
        __syncthreads();
    }
    lscan[t] = s[t] - c;
    if (c > 0) gbase[t] = atomicAdd(&bucketCursor[t], c);
    __syncthreads();
    #pragma unroll
    for (int k = 0; k < 8; ++k) {
        if (myB[k] >= 0) {
            int lpos = lscan[myB[k]] + myR[k];
            rec[lpos] = make_uint2(mySrc[k] | ((unsigned int)myDl[k] << 17), myW[k]);
            bof[lpos] = (unsigned short)myB[k];
        }
    }
    __syncthreads();
    int m = e - base; if (m > 2048) m = 2048;
    for (int i = t; i < m; i += 256) {
        int b = bof[i];
        etmp[gbase[b] + (i - lscan[b])] = rec[i];
    }
}

// pass 3: per-bucket local CSR + degree -> dinv. One block per bucket (512 nodes).
__global__ void k_pass3(const uint2* __restrict__ etmp, const int* __restrict__ bucketBase,
                        int* __restrict__ R, uint2* __restrict__ epair,
                        float* __restrict__ dinv, int n) {
    __shared__ int hist[512];
    __shared__ float degs[512];
    __shared__ int s[256];
    int b = blockIdx.x, t = threadIdx.x;
    int lo = bucketBase[b], hi = bucketBase[b + 1];
    hist[t] = 0; hist[t + 256] = 0;
    degs[t] = 0.f; degs[t + 256] = 0.f;
    __syncthreads();
    for (int i = lo + t; i < hi; i += 256)
        atomicAdd(&hist[etmp[i].x >> 17], 1);
    __syncthreads();
    int c0 = hist[2 * t], c1 = hist[2 * t + 1];
    int p = c0 + c1;
    s[t] = p;
    __syncthreads();
    for (int off = 1; off < 256; off <<= 1) {
        int u = (t >= off) ? s[t - off] : 0;
        __syncthreads();
        s[t] += u;
        __syncthreads();
    }
    int excl = s[t] - p;
    int node0 = b << BSH;
    int e0 = excl, e1 = excl + c0;
    if (node0 + 2 * t < n)     R[node0 + 2 * t]     = lo + e0;
    if (node0 + 2 * t + 1 < n) R[node0 + 2 * t + 1] = lo + e1;
    __syncthreads();
    hist[2 * t] = e0; hist[2 * t + 1] = e1;   // cursors
    __syncthreads();
    for (int i = lo + t; i < hi; i += 256) {
        uint2 r = etmp[i];
        int dl = r.x >> 17;
        int slot = lo + atomicAdd(&hist[dl], 1);
        epair[slot] = make_uint2(r.x & 0x1FFFFu, r.y);
        atomicAdd(&degs[dl], __uint_as_float(r.y));
    }
    __syncthreads();
    for (int l = t; l < 512; l += 256) {
        int node = node0 + l;
        if (node < n) dinv[node] = rsqrtf(1.f + degs[l]);
    }
}

// ====== layer 0 fused: aggregate x (bf16, 16 feats) -> GEMM 16->128 + b0 -> Bbf ======
__global__ void k_layer0(const unsigned int* __restrict__ xbf, const uint2* __restrict__ epair,
                         const int* __restrict__ R, const float* __restrict__ dinv,
                         const float* __restrict__ W0, const float* __restrict__ b0,
                         unsigned int* __restrict__ Bbf, int n, int e) {
    __shared__ float Ws[16 * 128];
    __shared__ float xs[16 * 16];
    int tid = threadIdx.x;   // 128
    #pragma unroll
    for (int k = 0; k < 16; ++k) Ws[k * 128 + tid] = W0[k * 128 + tid];
    int node0 = blockIdx.x * 16;
    int node_l = tid >> 3, u = tid & 7;
    int node = node0 + node_l;
    if (node < n) {
        int start = R[node];
        int end = (node + 1 < n) ? R[node + 1] : e;
        float ax = 0.f, ay = 0.f;
        int j = start;
        for (; j + 3 < end; j += 4) {
            uint2 p0 = epair[j], p1 = epair[j + 1], p2 = epair[j + 2], p3 = epair[j + 3];
            float w0 = dinv[p0.x] * __uint_as_float(p0.y);
            float w1 = dinv[p1.x] * __uint_as_float(p1.y);
            float w2 = dinv[p2.x] * __uint_as_float(p2.y);
            float w3 = dinv[p3.x] * __uint_as_float(p3.y);
            unsigned int q0 = xbf[(size_t)p0.x * 8 + u];
            unsigned int q1 = xbf[(size_t)p1.x * 8 + u];
            unsigned int q2 = xbf[(size_t)p2.x * 8 + u];
            unsigned int q3 = xbf[(size_t)p3.x * 8 + u];
            ax += bflo(q0) * w0 + bflo(q1) * w1 + bflo(q2) * w2 + bflo(q3) * w3;
            ay += bfhi(q0) * w0 + bfhi(q1) * w1 + bfhi(q2) * w2 + bfhi(q3) * w3;
        }
        for (; j < end; ++j) {
            uint2 p0 = epair[j];
            float w0 = dinv[p0.x] * __uint_as_float(p0.y);
            unsigned int q0 = xbf[(size_t)p0.x * 8 + u];
            ax += bflo(q0) * w0;
            ay += bfhi(q0) * w0;
        }
        float di = dinv[node];
        unsigned int ps = xbf[(size_t)node * 8 + u];
        xs[node_l * 16 + 2 * u]     = ax * di + bflo(ps) * di * di;
        xs[node_l * 16 + 2 * u + 1] = ay * di + bfhi(ps) * di * di;
    }
    __syncthreads();
    int nrows = n - node0; if (nrows > 16) nrows = 16;
    float bf = b0[tid];
    for (int nl = 0; nl < nrows; ++nl) {
        float acc = bf;
        #pragma unroll
        for (int k = 0; k < 16; ++k) acc += xs[nl * 16 + k] * Ws[k * 128 + tid];
        float hi = __shfl_xor(acc, 1);
        if ((tid & 1) == 0)
            Bbf[(size_t)(node0 + nl) * 64 + (tid >> 1)] = packbf(acc, hi);
    }
}

// BN stats over packed bf16 rows
__global__ void k_bn_stats(const unsigned int* __restrict__ h, float* __restrict__ sums,
                           float* __restrict__ sumsq, int n) {
    int u = threadIdx.x & 63, half = threadIdx.x >> 6;   // blockDim 128
    int i0 = blockIdx.x * 256 + half;
    int i1 = blockIdx.x * 256 + 256; if (i1 > n) i1 = n;
    float sl = 0.f, shh = 0.f, ql = 0.f, qh = 0.f;
    for (int i = i0; i < i1; i += 2) {
        unsigned int p = h[(size_t)i * 64 + u];
        float lo = bflo(p), hi = bfhi(p);
        sl += lo; ql += lo * lo;
        shh += hi; qh += hi * hi;
    }
    atomicAdd(&sums[2 * u], sl);
    atomicAdd(&sums[2 * u + 1], shh);
    atomicAdd(&sumsq[2 * u], ql);
    atomicAdd(&sumsq[2 * u + 1], qh);
}

// BN0+ReLU fused on load (bf16 in); MFMA bf16 -> Abf bf16 packed (8 col-tiles).
__global__ __launch_bounds__(256) void k_gemm_hid_mfma(
        const uint4* __restrict__ Bbf4, const float* __restrict__ sums,
        const float* __restrict__ sumsq, const float* __restrict__ g,
        const float* __restrict__ be, const unsigned int* __restrict__ W1p,
        unsigned int* __restrict__ Abf, int n, float invn) {
    __shared__ __align__(16) unsigned int hsbf[64 * HSTRIDE];
    __shared__ float sc[128], sh[128];
    int tid = threadIdx.x;
    if (tid < 128) {
        float m = sums[tid] * invn;
        float v = sumsq[tid] * invn - m * m;
        float scale = rsqrtf(v + EPS_BN) * g[tid];
        sc[tid] = scale;
        sh[tid] = be[tid] - m * scale;
    }
    __syncthreads();
    int node0 = blockIdx.x * 64;
    for (int i = tid; i < 64 * 16; i += 256) {
        int row = i >> 4, q = i & 15;
        int gn = node0 + row;
        uint4 pk;
        if (gn < n) {
            uint4 p = Bbf4[(size_t)gn * 16 + q];
            int fb = q * 8;
            float v0 = fmaxf(bflo(p.x) * sc[fb + 0] + sh[fb + 0], 0.f);
            float v1 = fmaxf(bfhi(p.x) * sc[fb + 1] + sh[fb + 1], 0.f);
            float v2 = fmaxf(bflo(p.y) * sc[fb + 2] + sh[fb + 2], 0.f);
            float v3 = fmaxf(bfhi(p.y) * sc[fb + 3] + sh[fb + 3], 0.f);
            float v4 = fmaxf(bflo(p.z) * sc[fb + 4] + sh[fb + 4], 0.f);
            float v5 = fmaxf(bfhi(p.z) * sc[fb + 5] + sh[fb + 5], 0.f);
            float v6 = fmaxf(bflo(p.w) * sc[fb + 6] + sh[fb + 6], 0.f);
            float v7 = fmaxf(bfhi(p.w) * sc[fb + 7] + sh[fb + 7], 0.f);
            pk = make_uint4(packbf(v0, v1), packbf(v2, v3), packbf(v4, v5), packbf(v6, v7));
        } else {
            pk = make_uint4(0u, 0u, 0u, 0u);
        }
        *((uint4*)&hsbf[row * HSTRIDE + q * 4]) = pk;
    }
    __syncthreads();
    int wave = tid >> 6, lane = tid & 63;
    int quad = lane >> 4, mrow = lane & 15;
    int lrow = wave * 16 + mrow;
    s16x8 afrag[4];
    #pragma unroll
    for (int kc = 0; kc < 4; ++kc)
        afrag[kc] = *((const s16x8*)&hsbf[lrow * HSTRIDE + kc * 16 + quad * 4]);
    int gnode_base = node0 + wave * 16;
    const s16x8* Wf = (const s16x8*)W1p;
    for (int ct = 0; ct < 8; ++ct) {
        f32x4 acc = {0.f, 0.f, 0.f, 0.f};
        #pragma unroll
        for (int kc = 0; kc < 4; ++kc) {
            s16x8 bfrag = Wf[(ct * 4 + kc) * 64 + lane];
            acc = __builtin_amdgcn_mfma_f32_16x16x32_bf16(afrag[kc], bfrag, acc, 0, 0, 0);
        }
        #pragma unroll
        for (int r = 0; r < 4; ++r) {
            float lo = acc[r];
            float hi = __shfl_xor(lo, 1);
            int grow = gnode_base + quad * 4 + r;
            if ((mrow & 1) == 0 && grow < n)
                Abf[(size_t)grow * 64 + ct * 8 + (mrow >> 1)] = packbf(lo, hi);
        }
    }
}

// BN1+ReLU fused on load (bf16 in); MFMA (N,128)@W2(128,16-padded) -> A16bf stride-16 bf16
__global__ __launch_bounds__(256) void k_gemm_out_mfma(
        const uint4* __restrict__ Bbf4, const float* __restrict__ sums,
        const float* __restrict__ sumsq, const float* __restrict__ g,
        const float* __restrict__ be, const unsigned int* __restrict__ W2p,
        unsigned int* __restrict__ A16bf, int n, float invn) {
    __shared__ __align__(16) unsigned int hsbf[64 * HSTRIDE];
    __shared__ float sc[128], sh[128];
    int tid = threadIdx.x;
    if (tid < 128) {
        float m = sums[tid] * invn;
        float v = sumsq[tid] * invn - m * m;
        float scale = rsqrtf(v + EPS_BN) * g[tid];
        sc[tid] = scale;
        sh[tid] = be[tid] - m * scale;
    }
    __syncthreads();
    int node0 = blockIdx.x * 64;
    for (int i = tid; i < 64 * 16; i += 256) {
        int row = i >> 4, q = i & 15;
        int gn = node0 + row;
        uint4 pk;
        if (gn < n) {
            uint4 p = Bbf4[(size_t)gn * 16 + q];
            int fb = q * 8;
            float v0 = fmaxf(bflo(p.x) * sc[fb + 0] + sh[fb + 0], 0.f);
            float v1 = fmaxf(bfhi(p.x) * sc[fb + 1] + sh[fb + 1], 0.f);
            float v2 = fmaxf(bflo(p.y) * sc[fb + 2] + sh[fb + 2], 0.f);
            float v3 = fmaxf(bfhi(p.y) * sc[fb + 3] + sh[fb + 3], 0.f);
            float v4 = fmaxf(bflo(p.z) * sc[fb + 4] + sh[fb + 4], 0.f);
            float v5 = fmaxf(bfhi(p.z) * sc[fb + 5] + sh[fb + 5], 0.f);
            float v6 = fmaxf(bflo(p.w) * sc[fb + 6] + sh[fb + 6], 0.f);
            float v7 = fmaxf(bfhi(p.w) * sc[fb + 7] + sh[fb + 7], 0.f);
            pk = make_uint4(packbf(v0, v1), packbf(v2, v3), packbf(v4, v5), packbf(v6, v7));
        } else {
            pk = make_uint4(0u, 0u, 0u, 0u);
        }
        *((uint4*)&hsbf[row * HSTRIDE + q * 4]) = pk;
    }
    __syncthreads();
    int wave = tid >> 6, lane = tid & 63;
    int quad = lane >> 4, mrow = lane & 15;
    int lrow = wave * 16 + mrow;
    s16x8 afrag[4];
    #pragma unroll
    for (int kc = 0; kc < 4; ++kc)
        afrag[kc] = *((const s16x8*)&hsbf[lrow * HSTRIDE + kc * 16 + quad * 4]);
    int gnode_base = node0 + wave * 16;
    const s16x8* Wf = (const s16x8*)W2p;
    f32x4 acc = {0.f, 0.f, 0.f, 0.f};
    #pragma unroll
    for (int kc = 0; kc < 4; ++kc) {
        s16x8 bfrag = Wf[kc * 64 + lane];
        acc = __builtin_amdgcn_mfma_f32_16x16x32_bf16(afrag[kc], bfrag, acc, 0, 0, 0);
    }
    #pragma unroll
    for (int r = 0; r < 4; ++r) {
        float lo = acc[r];
        float hi = __shfl_xor(lo, 1);
        int grow = gnode_base + quad * 4 + r;
        if ((mrow & 1) == 0 && grow < n)
            A16bf[(size_t)grow * 8 + (mrow >> 1)] = packbf(lo, hi);
    }
}

// layer-1: 128-feature bf16 aggregation. wave/node, four 16-lane groups.
__global__ void k_aggregate128(const uint4* __restrict__ Abf4, const uint2* __restrict__ epair,
                               const int* __restrict__ R, const float* __restrict__ dinv,
                               const float4* __restrict__ bias4, uint4* __restrict__ Bbf4,
                               int n, int e) {
    int gid = blockIdx.x * blockDim.x + threadIdx.x;
    int node = gid >> 6;
    if (node >= n) return;
    int lane = threadIdx.x & 63;
    int grp = lane >> 4, sub = lane & 15;
    int start = R[node];
    int end = (node + 1 < n) ? R[node + 1] : e;
    float a[8] = {0.f, 0.f, 0.f, 0.f, 0.f, 0.f, 0.f, 0.f};
    for (int base = start; base < end; base += 64) {
        int m = end - base; if (m > 64) m = 64;
        int myS = 0; float myW = 0.f;
        if (lane < m) {
            uint2 pr = epair[base + lane];
            myS = (int)pr.x;
            myW = dinv[pr.x] * __uint_as_float(pr.y);
        }
        for (int t = 0; t < m; t += 16) {
            int j0 = t + grp, j1 = t + 4 + grp, j2 = t + 8 + grp, j3 = t + 12 + grp;
            int s0 = __shfl(myS, j0); float w0 = __shfl(myW, j0);
            int s1 = __shfl(myS, j1); float w1 = __shfl(myW, j1);
            int s2 = __shfl(myS, j2); float w2 = __shfl(myW, j2);
            int s3 = __shfl(myS, j3); float w3 = __shfl(myW, j3);
            if (j0 < m) {
                uint4 p = Abf4[(size_t)s0 * 16 + sub];
                a[0] += bflo(p.x) * w0; a[1] += bfhi(p.x) * w0;
                a[2] += bflo(p.y) * w0; a[3] += bfhi(p.y) * w0;
                a[4] += bflo(p.z) * w0; a[5] += bfhi(p.z) * w0;
                a[6] += bflo(p.w) * w0; a[7] += bfhi(p.w) * w0;
            }
            if (j1 < m) {
                uint4 p = Abf4[(size_t)s1 * 16 + sub];
                a[0] += bflo(p.x) * w1; a[1] += bfhi(p.x) * w1;
                a[2] += bflo(p.y) * w1; a[3] += bfhi(p.y) * w1;
                a[4] += bflo(p.z) * w1; a[5] += bfhi(p.z) * w1;
                a[6] += bflo(p.w) * w1; a[7] += bfhi(p.w) * w1;
            }
            if (j2 < m) {
                uint4 p = Abf4[(size_t)s2 * 16 + sub];
                a[0] += bflo(p.x) * w2; a[1] += bfhi(p.x) * w2;
                a[2] += bflo(p.y) * w2; a[3] += bfhi(p.y) * w2;
                a[4] += bflo(p.z) * w2; a[5] += bfhi(p.z) * w2;
                a[6] += bflo(p.w) * w2; a[7] += bfhi(p.w) * w2;
            }
            if (j3 < m) {
                uint4 p = Abf4[(size_t)s3 * 16 + sub];
                a[0] += bflo(p.x) * w3; a[1] += bfhi(p.x) * w3;
                a[2] += bflo(p.y) * w3; a[3] += bfhi(p.y) * w3;
                a[4] += bflo(p.z) * w3; a[5] += bfhi(p.z) * w3;
                a[6] += bflo(p.w) * w3; a[7] += bfhi(p.w) * w3;
            }
        }
    }
    #pragma unroll
    for (int k = 0; k < 8; ++k) {
        a[k] += __shfl_xor(a[k], 16);
        a[k] += __shfl_xor(a[k], 32);
    }
    if (grp == 0) {
        float di = dinv[node];
        uint4 ps = Abf4[(size_t)node * 16 + sub];
        float4 bl = bias4[2 * sub], bh = bias4[2 * sub + 1];
        float r0 = a[0] * di + bflo(ps.x) * di * di + bl.x;
        float r1 = a[1] * di + bfhi(ps.x) * di * di + bl.y;
        float r2 = a[2] * di + bflo(ps.y) * di * di + bl.z;
        float r3 = a[3] * di + bfhi(ps.y) * di * di + bl.w;
        float r4 = a[4] * di + bflo(ps.z) * di * di + bh.x;
        float r5 = a[5] * di + bfhi(ps.z) * di * di + bh.y;
        float r6 = a[6] * di + bflo(ps.w) * di * di + bh.z;
        float r7 = a[7] * di + bfhi(ps.w) * di * di + bh.w;
        Bbf4[(size_t)node * 16 + sub] = make_uint4(packbf(r0, r1), packbf(r2, r3),
                                                   packbf(r4, r5), packbf(r6, r7));
    }
}

// layer-2: 12-feature aggregation over bf16 stride-16 rows, unroll 4.
__global__ void k_agg_out(const unsigned int* __restrict__ A16bf, const uint2* __restrict__ epair,
                          const int* __restrict__ R, const float* __restrict__ dinv,
                          const float* __restrict__ b2, float* __restrict__ out, int n, int e) {
    int t = blockIdx.x * blockDim.x + threadIdx.x;
    int node = t >> 3, u = t & 7;
    if (node >= n || u >= 6) return;
    int start = R[node];
    int end = (node + 1 < n) ? R[node + 1] : e;
    float ax = 0.f, ay = 0.f;
    int j = start;
    for (; j + 3 < end; j += 4) {
        uint2 p0 = epair[j], p1 = epair[j + 1], p2 = epair[j + 2], p3 = epair[j + 3];
        float w0 = dinv[p0.x] * __uint_as_float(p0.y);
        float w1 = dinv[p1.x] * __uint_as_float(p1.y);
        float w2 = dinv[p2.x] * __uint_as_float(p2.y);
        float w3 = dinv[p3.x] * __uint_as_float(p3.y);
        unsigned int q0 = A16bf[(size_t)p0.x * 8 + u];
        unsigned int q1 = A16bf[(size_t)p1.x * 8 + u];
        unsigned int q2 = A16bf[(size_t)p2.x * 8 + u];
        unsigned int q3 = A16bf[(size_t)p3.x * 8 + u];
        ax += bflo(q0) * w0 + bflo(q1) * w1 + bflo(q2) * w2 + bflo(q3) * w3;
        ay += bfhi(q0) * w0 + bfhi(q1) * w1 + bfhi(q2) * w2 + bfhi(q3) * w3;
    }
    for (; j < end; ++j) {
        uint2 p0 = epair[j];
        float w0 = dinv[p0.x] * __uint_as_float(p0.y);
        unsigned int q0 = A16bf[(size_t)p0.x * 8 + u];
        ax += bflo(q0) * w0;
        ay += bfhi(q0) * w0;
    }
    float di = dinv[node];
    unsigned int ps = A16bf[(size_t)node * 8 + u];
    ax = ax * di + bflo(ps) * di * di + b2[2 * u];
    ay = ay * di + bfhi(ps) * di * di + b2[2 * u + 1];
    ((float2*)(out + (size_t)node * 12))[u] = make_float2(ax, ay);
}

// ================= launch =================
extern "C" void kernel_launch(void* const* d_in, const int* in_sizes, int n_in,
                              void* d_out, int out_size, void* d_ws, size_t ws_size,
                              hipStream_t stream) {
    const float* x   = (const float*)d_in[0];
    const int*   ei  = (const int*)d_in[1];
    const float* ew  = (const float*)d_in[2];
    const float* W0  = (const float*)d_in[3];
    const float* b0  = (const float*)d_in[4];
    const float* W1  = (const float*)d_in[5];
    const float* b1  = (const float*)d_in[6];
    const float* W2  = (const float*)d_in[7];
    const float* b2  = (const float*)d_in[8];
    const float* g0  = (const float*)d_in[9];
    const float* be0 = (const float*)d_in[10];
    const float* g1  = (const float*)d_in[11];
    const float* be1 = (const float*)d_in[12];
    float* out = (float*)d_out;

    const int n = in_sizes[0] / 16;   // 100000
    const int e = in_sizes[2];        // 1600000
    const int* src = ei;
    const int* dst = ei + e;
    const int NB = (n + 511) >> 9;                 // 196 buckets
    const int NHIST = (e + 4095) / 4096;           // 391 histogram blocks

    // workspace layout (4B elems); etmp aliases B region (dead before Bbf written)
    float*        wsf   = (float*)d_ws;
    float*        dinv  = wsf;                                    // n
    int*          R     = (int*)(wsf + n);                        // n+4
    int*          bCnt  = R + (n + 4);                            // 512
    int*          bBase = bCnt + 512;                             // 520
    int*          bCur  = bBase + 520;                            // 512
    uint2*        epair = (uint2*)(bCur + 512);                   // e pairs
    float*        B     = (float*)(bCur + 512 + 2 * (size_t)e);   // region (n*128 dwords)
    uint2*        etmp  = (uint2*)B;                              // e pairs, aliases B
    unsigned int* Bbf   = (unsigned int*)B;                       // n*64 (bf16 packed)
    unsigned int* Abf   = (unsigned int*)(B + (size_t)n * 128);   // n*64
    unsigned int* xbf   = Abf + (size_t)n * 64;                   // n*8
    unsigned int* A16bf = xbf + (size_t)n * 8;                    // n*8
    float*        stat0 = (float*)(A16bf + (size_t)n * 8);        // 256 (sums|sumsq)
    float*        stat1 = stat0 + 256;                            // 256
    unsigned int* W1p   = (unsigned int*)(stat1 + 256);           // 8192
    unsigned int* W2p   = W1p + 8192;                             // 1024

    const float invn = 1.0f / (float)n;

    // ---- build + prep (12 dispatches total this launch) ----
    hipMemsetAsync(bCnt, 0, 512 * sizeof(int), stream);
    k_prep_all<<<(n * 8 + 255) / 256, 256, 0, stream>>>(x, xbf, n * 8, W1, W1p, W2, W2p,
                                                        dst, bCnt, e, NHIST);
    k_scan_buckets<<<1, 256, 0, stream>>>(bCnt, bBase, bCur, NB, e, stat0, stat1);
    k_pass2<<<(e + 2047) / 2048, 256, 0, stream>>>(src, dst, ew, bCur, etmp, e);
    k_pass3<<<NB, 256, 0, stream>>>(etmp, bBase, R, epair, dinv, n);

    // ---- layer 0 (fused aggregate + 16->128 GEMM + bias) ----
    k_layer0<<<(n + 15) / 16, 128, 0, stream>>>(xbf, epair, R, dinv, W0, b0, Bbf, n, e);
    k_bn_stats<<<(n + 255) / 256, 128, 0, stream>>>(Bbf, stat0, stat0 + 128, n);

    // ---- layer 1 (MFMA GEMM with fused BN0+ReLU, then aggregation) ----
    k_gemm_hid_mfma<<<(n + 63) / 64, 256, 0, stream>>>((const uint4*)Bbf, stat0, stat0 + 128,
                                                       g0, be0, W1p, Abf, n, invn);
    k_aggregate128<<<(n * 64 + 255) / 256, 256, 0, stream>>>((const uint4*)Abf, epair, R, dinv,
                                                             (const float4*)b1, (uint4*)Bbf, n, e);
    k_bn_stats<<<(n + 255) / 256, 128, 0, stream>>>(Bbf, stat1, stat1 + 128, n);

    // ---- layer 2 (MFMA GEMM with fused BN1+ReLU, then aggregation to out) ----
    k_gemm_out_mfma<<<(n + 63) / 64, 256, 0, stream>>>((const uint4*)Bbf, stat1, stat1 + 128,
                                                       g1, be1, W2p, A16bf, n, invn);
    k_agg_out<<<(n * 8 + 255) / 256, 256, 0, stream>>>(A16bf, epair, R, dinv, b2, out, n, e);
}